// Round 14
// baseline (123.747 us; speedup 1.0000x reference)
//
#include <hip/hip_runtime.h>
#include <hip/hip_bf16.h>

typedef __attribute__((ext_vector_type(4))) float f32x4;
typedef __attribute__((ext_vector_type(3))) float f32x3;
typedef __attribute__((ext_vector_type(8))) short bf16x8;

static constexpr int B   = 2;
static constexpr int N   = 2048;
static constexpr int F   = 64;
static constexpr int H   = 4;
static constexpr int HID = 128;
static constexpr int BN  = B * N;
static constexpr size_t LOG_SZ = (size_t)B * N * N * 3;

__device__ __forceinline__ float sigmoidf_(float x) { return 1.0f / (1.0f + __expf(-x)); }
__device__ __forceinline__ float tanhf_(float x) {
  float e = __expf(2.0f * x);
  return 1.0f - 2.0f / (e + 1.0f);      // inf-safe
}
// RNE bf16 split: v = hi + lo with ~2^-17 relative error
__device__ __forceinline__ void split_bf16(float v, short& hi, short& lo) {
  unsigned u = __float_as_uint(v);
  unsigned hr = (u + 0x7FFFu + ((u >> 16) & 1u)) >> 16;
  hi = (short)hr;
  float hv = __uint_as_float(hr << 16);
  float res = v - hv;
  unsigned u2 = __float_as_uint(res);
  lo = (short)((u2 + 0x7FFFu + ((u2 >> 16) & 1u)) >> 16);
}
__device__ __forceinline__ void stage16(const short* gp, short* lp) {
  __builtin_amdgcn_global_load_lds(
      (const __attribute__((address_space(1))) void*)gp,
      (__attribute__((address_space(3))) void*)lp, 16, 0, 0);
}

// ------------- K1: merged prep (weights->frag-order bf16x2) + feat + h-split ---
struct PreArgs {
  const float* x; const float* gk; const float* asel; const float* anei;
  float* hfeat; float* sself; float* sneigh;
  const float* h[3];
  short* hh[3]; short* hl[3];
  const float* src[12];
  short* whi[12]; short* wlo[12];
  int nks[12];
};
__global__ __launch_bounds__(256) void k_pre(PreArgs pa) {
  const int bid = blockIdx.x;
  if (bid < BN / 2) {
    const int t = threadIdx.x;
    const int r = t >> 7, tt = t & 127;
    const int bn = bid * 2 + r;
    __shared__ float xs[2][F];
    if (tt < F) xs[r][tt] = pa.x[(size_t)bn * F + tt];
    const size_t o = (size_t)bn * HID + tt;
    { short hi, lo; split_bf16(pa.h[0][o], hi, lo); pa.hh[0][o] = hi; pa.hl[0][o] = lo; }
    { short hi, lo; split_bf16(pa.h[1][o], hi, lo); pa.hh[1][o] = hi; pa.hl[1][o] = lo; }
    { short hi, lo; split_bf16(pa.h[2][o], hi, lo); pa.hh[2][o] = hi; pa.hl[2][o] = lo; }
    __syncthreads();
    float acc = 0.f;
    #pragma unroll 8
    for (int f = 0; f < F; ++f) acc += xs[r][f] * pa.gk[f * HID + tt];
    pa.hfeat[o] = acc;
    float ps = acc * pa.asel[tt];
    float pn = acc * pa.anei[tt];
    #pragma unroll
    for (int d = 16; d >= 1; d >>= 1) {
      ps += __shfl_xor(ps, d, 32);
      pn += __shfl_xor(pn, d, 32);
    }
    if ((tt & 31) == 0) {
      pa.sself [bn * H + (tt >> 5)] = ps;
      pa.sneigh[bn * H + (tt >> 5)] = pn;
    }
  } else {
    const int pb = bid - BN / 2;
    const int m = pb >> 3, cf = pb & 7;
    const int nksv = pa.nks[m];
    const int wv = threadIdx.x >> 6, lane = threadIdx.x & 63;
    const float* src = pa.src[m];
    short* ph = pa.whi[m];
    short* pl = pa.wlo[m];
    const int col = cf * 16 + (lane & 15);
    const int krow = (lane >> 4) * 8;
    for (int ks = wv; ks < nksv; ks += 4) {
      bf16x8 vh, vl;
      #pragma unroll
      for (int e = 0; e < 8; ++e) {
        const int k = ks * 32 + krow + e;
        short hi, lo; split_bf16(src[(size_t)k * HID + col], hi, lo);
        vh[e] = hi; vl[e] = lo;
      }
      const size_t o = (((size_t)cf * nksv + ks) * 64 + lane) * 8;
      *(bf16x8*)&ph[o] = vh;
      *(bf16x8*)&pl[o] = vl;
    }
  }
}

// ------------- K2: sparse GAT attention — one wave per row -------------
__global__ __launch_bounds__(256) void k_attn(
    const float* __restrict__ a, const float* __restrict__ hfeat,
    const float* __restrict__ sself, const float* __restrict__ sneigh,
    const float* __restrict__ bias,
    short* __restrict__ conv_hi, short* __restrict__ conv_lo) {
  const int wv   = threadIdx.x >> 6;
  const int lane = threadIdx.x & 63;
  const int bi   = blockIdx.x * 4 + wv;
  const int bbase = bi & ~(N - 1);
  __shared__ int   nbr[4][256];
  __shared__ float wts[4][256][4];
  int*   nb       = nbr[wv];
  float (*wt)[4]  = wts[wv];
  const float si0 = sself[bi * H + 0];
  const float si1 = sself[bi * H + 1];
  const float si2 = sself[bi * H + 2];
  const float si3 = sself[bi * H + 3];
  float den0 = 0.f, den1 = 0.f, den2 = 0.f, den3 = 0.f;
  float acc0 = 0.f, acc1 = 0.f;
  const unsigned long long lmlt = ((unsigned long long)1 << lane) - 1ull;
  const float* arow = a + (size_t)bi * N;
  const float* hb   = hfeat + (size_t)bbase * HID;
  const float* snb  = sneigh + (size_t)bbase * H;
  const int h0 = lane >> 5;
  int num = 0;
  auto flush = [&]() {
    asm volatile("s_waitcnt lgkmcnt(0)" ::: "memory");
    for (int n = lane; n < num; n += 64) {
      const int j = nb[n];
      f32x4 sn = *(const f32x4*)&snb[(size_t)j * H];
      float s0 = si0 + sn[0]; s0 = (s0 > 0.f) ? s0 : 0.2f * s0;
      float s1 = si1 + sn[1]; s1 = (s1 > 0.f) ? s1 : 0.2f * s1;
      float s2 = si2 + sn[2]; s2 = (s2 > 0.f) ? s2 : 0.2f * s2;
      float s3 = si3 + sn[3]; s3 = (s3 > 0.f) ? s3 : 0.2f * s3;
      float w0 = __expf(s0), w1 = __expf(s1), w2 = __expf(s2), w3 = __expf(s3);
      wt[n][0] = w0; wt[n][1] = w1; wt[n][2] = w2; wt[n][3] = w3;
      den0 += w0; den1 += w1; den2 += w2; den3 += w3;
    }
    asm volatile("s_waitcnt lgkmcnt(0)" ::: "memory");
    #pragma unroll 4
    for (int n = 0; n < num; ++n) {
      const int j  = nb[n];
      const float wA = wt[n][h0];
      const float wB = wt[n][h0 + 2];
      const float* hr = hb + (size_t)j * HID;
      acc0 += wA * hr[lane];
      acc1 += wB * hr[lane + 64];
    }
    asm volatile("s_waitcnt lgkmcnt(0)" ::: "memory");
    num = 0;
  };
  for (int jb = 0; jb < N; jb += 256) {
    f32x4 av = *(const f32x4*)&arow[jb + lane * 4];
    #pragma unroll
    for (int e = 0; e < 4; ++e) {
      const unsigned long long m = __ballot(av[e] > 0.5f);
      if (av[e] > 0.5f) {
        const int pos = num + __popcll(m & lmlt);
        nb[pos] = jb + lane * 4 + e;
      }
      num += __popcll(m);
      if (num > 192) flush();
    }
  }
  if (num > 0) flush();
  #pragma unroll
  for (int d = 32; d >= 1; d >>= 1) {
    den0 += __shfl_xor(den0, d, 64);
    den1 += __shfl_xor(den1, d, 64);
    den2 += __shfl_xor(den2, d, 64);
    den3 += __shfl_xor(den3, d, 64);
  }
  const float dA = h0 ? den1 : den0;
  const float dB = h0 ? den3 : den2;
  const float v0 = acc0 / dA + bias[lane];
  const float v1 = acc1 / dB + bias[64 + lane];
  { short hi, lo; split_bf16(v0, hi, lo);
    conv_hi[(size_t)bi * HID + lane] = hi; conv_lo[(size_t)bi * HID + lane] = lo; }
  { short hi, lo; split_bf16(v1, hi, lo);
    conv_hi[(size_t)bi * HID + 64 + lane] = hi; conv_lo[(size_t)bi * HID + 64 + lane] = lo; }
}

// ------------- shared arg pack -------------
struct GArgs {
  const short* chi; const short* clo;
  const float* h[3];
  const short* hhi[3]; const short* hlo[3];
  const float* bu[3]; const float* br[3]; const float* bc[3];
  const short* WuH[3]; const short* WuL[3];
  const short* WrH[3]; const short* WrL[3];
  const short* WcH[3]; const short* WcL[3];
  const short* RtH[3]; const short* RtL[3];
  float* u_ws[3];
  short* rhh[3]; short* rhl[3];
  short* hph[3]; short* hpl[3];
  float* hout[3]; short* gb[3];
};

// ------------- K3: u+r gates combined -------------
__global__ __launch_bounds__(256) void k_ur(GArgs ga) {
  const int wv = threadIdx.x >> 6, lane = threadIdx.x & 63;
  const int bx = blockIdx.x, cg2 = blockIdx.y, cell = blockIdx.z;
  const int lr = lane & 15, lg = lane >> 4, kb = lg * 8;
  const int R0 = bx * 64 + wv * 16;
  __shared__ short wlds[4][16][64][8];
  bf16x8 a_h[8], a_l[8];
  {
    const size_t ab = (size_t)(R0 + lr) * HID + kb;
    const short* hhi = ga.hhi[cell]; const short* hlo = ga.hlo[cell];
    #pragma unroll
    for (int ks = 0; ks < 4; ++ks) {
      a_h[ks]     = *(const bf16x8*)&ga.chi[ab + ks * 32];
      a_l[ks]     = *(const bf16x8*)&ga.clo[ab + ks * 32];
      a_h[4 + ks] = *(const bf16x8*)&hhi[ab + ks * 32];
      a_l[4 + ks] = *(const bf16x8*)&hlo[ab + ks * 32];
    }
  }
  {
    const short* srcs[4] = { ga.WuH[cell], ga.WuL[cell], ga.WrH[cell], ga.WrL[cell] };
    const short* sp = srcs[wv];
    #pragma unroll
    for (int f = 0; f < 16; ++f) {
      const short* gp = sp + (((size_t)((cg2 * 2 + (f >> 3)) * 8 + (f & 7))) * 64 + lane) * 8;
      stage16(gp, &wlds[wv][f][0][0]);
    }
  }
  asm volatile("s_waitcnt vmcnt(0)" ::: "memory");
  __syncthreads();
  f32x4 au[2] = {}, ar[2] = {};
  #pragma unroll
  for (int ks = 0; ks < 8; ++ks) {
    const bf16x8 ah = a_h[ks], al = a_l[ks];
    #pragma unroll
    for (int cfl = 0; cfl < 2; ++cfl) {
      const int f = cfl * 8 + ks;
      bf16x8 buh = *(const bf16x8*)&wlds[0][f][lane][0];
      bf16x8 bul = *(const bf16x8*)&wlds[1][f][lane][0];
      bf16x8 brh = *(const bf16x8*)&wlds[2][f][lane][0];
      bf16x8 brl = *(const bf16x8*)&wlds[3][f][lane][0];
      au[cfl] = __builtin_amdgcn_mfma_f32_16x16x32_bf16(ah, buh, au[cfl], 0, 0, 0);
      au[cfl] = __builtin_amdgcn_mfma_f32_16x16x32_bf16(ah, bul, au[cfl], 0, 0, 0);
      au[cfl] = __builtin_amdgcn_mfma_f32_16x16x32_bf16(al, buh, au[cfl], 0, 0, 0);
      ar[cfl] = __builtin_amdgcn_mfma_f32_16x16x32_bf16(ah, brh, ar[cfl], 0, 0, 0);
      ar[cfl] = __builtin_amdgcn_mfma_f32_16x16x32_bf16(ah, brl, ar[cfl], 0, 0, 0);
      ar[cfl] = __builtin_amdgcn_mfma_f32_16x16x32_bf16(al, brh, ar[cfl], 0, 0, 0);
    }
  }
  const float* bu = ga.bu[cell];
  const float* br = ga.br[cell];
  const float* hsrc = ga.h[cell];
  float* uws = ga.u_ws[cell];
  short* rhh = ga.rhh[cell]; short* rhl = ga.rhl[cell];
  #pragma unroll
  for (int cfl = 0; cfl < 2; ++cfl) {
    const int col = cg2 * 32 + cfl * 16 + lr;
    #pragma unroll
    for (int q = 0; q < 4; ++q) {
      const int row = R0 + lg * 4 + q;
      const int n = row & (N - 1);
      uws[(size_t)row * HID + col] = sigmoidf_(au[cfl][q] + bu[n]);
      const float rv = sigmoidf_(ar[cfl][q] + br[n]);
      const float rhv = rv * hsrc[(size_t)row * HID + col];
      short hi, lo; split_bf16(rhv, hi, lo);
      rhh[(size_t)row * HID + col] = hi;
      rhl[(size_t)row * HID + col] = lo;
    }
  }
}

// ------------- K4: c gate + h' -------------
__global__ __launch_bounds__(256) void k_c(GArgs ga) {
  const int wv = threadIdx.x >> 6, lane = threadIdx.x & 63;
  const int bx = blockIdx.x, cg2 = blockIdx.y, cell = blockIdx.z;
  const int lr = lane & 15, lg = lane >> 4, kb = lg * 8;
  const int R0 = bx * 64 + wv * 16;
  __shared__ short wlds[2][16][64][8];
  bf16x8 a_h[8], a_l[8];
  {
    const size_t ab = (size_t)(R0 + lr) * HID + kb;
    const short* rhh = ga.rhh[cell]; const short* rhl = ga.rhl[cell];
    #pragma unroll
    for (int ks = 0; ks < 4; ++ks) {
      a_h[ks]     = *(const bf16x8*)&ga.chi[ab + ks * 32];
      a_l[ks]     = *(const bf16x8*)&ga.clo[ab + ks * 32];
      a_h[4 + ks] = *(const bf16x8*)&rhh[ab + ks * 32];
      a_l[4 + ks] = *(const bf16x8*)&rhl[ab + ks * 32];
    }
  }
  {
    const short* WH = ga.WcH[cell];
    const short* WL = ga.WcL[cell];
    #pragma unroll
    for (int i = 0; i < 8; ++i) {
      const int fid = wv * 8 + i;
      const int combo = fid >> 4, f = fid & 15;
      const short* src = combo ? WL : WH;
      const short* gp = src + (((size_t)((cg2 * 2 + (f >> 3)) * 8 + (f & 7))) * 64 + lane) * 8;
      stage16(gp, &wlds[combo][f][0][0]);
    }
  }
  asm volatile("s_waitcnt vmcnt(0)" ::: "memory");
  __syncthreads();
  f32x4 acc[2] = {};
  #pragma unroll
  for (int ks = 0; ks < 8; ++ks) {
    const bf16x8 ah = a_h[ks], al = a_l[ks];
    #pragma unroll
    for (int cfl = 0; cfl < 2; ++cfl) {
      const int f = cfl * 8 + ks;
      bf16x8 bh = *(const bf16x8*)&wlds[0][f][lane][0];
      bf16x8 bl = *(const bf16x8*)&wlds[1][f][lane][0];
      acc[cfl] = __builtin_amdgcn_mfma_f32_16x16x32_bf16(ah, bh, acc[cfl], 0, 0, 0);
      acc[cfl] = __builtin_amdgcn_mfma_f32_16x16x32_bf16(ah, bl, acc[cfl], 0, 0, 0);
      acc[cfl] = __builtin_amdgcn_mfma_f32_16x16x32_bf16(al, bh, acc[cfl], 0, 0, 0);
    }
  }
  const float* bc = ga.bc[cell];
  const float* uw = ga.u_ws[cell];
  const float* hsrc = ga.h[cell];
  float* hout = ga.hout[cell];
  short* hph = ga.hph[cell]; short* hpl = ga.hpl[cell];
  #pragma unroll
  for (int cfl = 0; cfl < 2; ++cfl) {
    const int col = cg2 * 32 + cfl * 16 + lr;
    #pragma unroll
    for (int q = 0; q < 4; ++q) {
      const int row = R0 + lg * 4 + q;
      const float cv = tanhf_(acc[cfl][q] + bc[row & (N - 1)]);
      const float uv = uw[(size_t)row * HID + col];
      const float hv = hsrc[(size_t)row * HID + col];
      const float o = uv * hv + (1.f - uv) * cv;
      __builtin_nontemporal_store(o, &hout[(size_t)row * HID + col]);
      short hi, lo; split_bf16(o, hi, lo);
      hph[(size_t)row * HID + col] = hi;
      hpl[(size_t)row * HID + col] = lo;
    }
  }
}

// ------------- K5: g = h' @ R -------------
__global__ __launch_bounds__(256) void k_g(GArgs ga) {
  const int wv = threadIdx.x >> 6, lane = threadIdx.x & 63;
  const int bx = blockIdx.x, cg2 = blockIdx.y, cell = blockIdx.z;
  const int lr = lane & 15, lg = lane >> 4, kb = lg * 8;
  const int R0 = bx * 64 + wv * 16;
  __shared__ short wlds[2][8][64][8];
  bf16x8 a_h[4], a_l[4];
  {
    const size_t ab = (size_t)(R0 + lr) * HID + kb;
    const short* hph = ga.hph[cell]; const short* hpl = ga.hpl[cell];
    #pragma unroll
    for (int ks = 0; ks < 4; ++ks) {
      a_h[ks] = *(const bf16x8*)&hph[ab + ks * 32];
      a_l[ks] = *(const bf16x8*)&hpl[ab + ks * 32];
    }
  }
  {
    #pragma unroll
    for (int i = 0; i < 4; ++i) {
      const int fid = wv * 4 + i;
      const int combo = fid >> 3, f = fid & 7;
      const short* src = combo ? ga.RtL[cell] : ga.RtH[cell];
      const short* gp = src + (((size_t)((cg2 * 2 + (f >> 2)) * 4 + (f & 3))) * 64 + lane) * 8;
      stage16(gp, &wlds[combo][f][0][0]);
    }
  }
  asm volatile("s_waitcnt vmcnt(0)" ::: "memory");
  __syncthreads();
  f32x4 acc[2] = {};
  #pragma unroll
  for (int ks = 0; ks < 4; ++ks) {
    const bf16x8 ah = a_h[ks], al = a_l[ks];
    #pragma unroll
    for (int cfl = 0; cfl < 2; ++cfl) {
      const int f = cfl * 4 + ks;
      bf16x8 bh = *(const bf16x8*)&wlds[0][f][lane][0];
      bf16x8 bl = *(const bf16x8*)&wlds[1][f][lane][0];
      acc[cfl] = __builtin_amdgcn_mfma_f32_16x16x32_bf16(ah, bh, acc[cfl], 0, 0, 0);
      acc[cfl] = __builtin_amdgcn_mfma_f32_16x16x32_bf16(ah, bl, acc[cfl], 0, 0, 0);
      acc[cfl] = __builtin_amdgcn_mfma_f32_16x16x32_bf16(al, bh, acc[cfl], 0, 0, 0);
    }
  }
  short* gbo = ga.gb[cell];
  #pragma unroll
  for (int cfl = 0; cfl < 2; ++cfl) {
    const int col = cg2 * 32 + cfl * 16 + lr;
    #pragma unroll
    for (int q = 0; q < 4; ++q) {
      const int row = R0 + lg * 4 + q;
      short hi, lo; split_bf16(acc[cfl][q], hi, lo);
      gbo[(size_t)row * HID + col] = hi;
    }
  }
}

// ------------- K6: logits — FLAT 16x512 tiles for contiguous row writes --------
// grid (N/16, N/512, B), 512 thr = 8 waves, each wave 16 rows x 64 cols.
__global__ __launch_bounds__(512) void k_bilinear(
    const short* __restrict__ g0, const short* __restrict__ g1,
    const short* __restrict__ g2, const short* __restrict__ h0,
    const short* __restrict__ h1, const short* __restrict__ h2,
    float* __restrict__ out) {
  const int ti = blockIdx.x;           // 16-row block
  const int tj = blockIdx.y;           // 512-col block
  const int b  = blockIdx.z;
  const int t = threadIdx.x;
  const int w = t >> 6, l = t & 63;
  const int rb = ti * 16;
  const int cb = tj * 512 + w * 64;
  const short* gbs[3] = {g0, g1, g2};
  const short* hbs[3] = {h0, h1, h2};
  const int lr = l & 15;
  const int kb = (l >> 4) * 8;
  f32x4 acc[3][4] = {};
  for (int k0 = 0; k0 < HID; k0 += 32) {
    #pragma unroll
    for (int d = 0; d < 3; ++d) {
      bf16x8 af = *(const bf16x8*)&gbs[d][(size_t)(b * N + rb + lr) * HID + k0 + kb];
      #pragma unroll
      for (int mj = 0; mj < 4; ++mj) {
        bf16x8 bf = *(const bf16x8*)&hbs[d][(size_t)(b * N + cb + mj * 16 + lr) * HID + k0 + kb];
        acc[d][mj] = __builtin_amdgcn_mfma_f32_16x16x32_bf16(af, bf, acc[d][mj], 0, 0, 0);
      }
    }
  }
  const int orow = (l >> 4) * 4;
  const int col  = l & 15;
  #pragma unroll
  for (int mj = 0; mj < 4; ++mj)
    #pragma unroll
    for (int r = 0; r < 4; ++r) {
      const int row = rb + orow + r;
      const int cc  = cb + mj * 16 + col;
      float* p = &out[(((size_t)(b * N + row)) * N + cc) * 3];
      f32x3 v;
      v[0] = acc[0][mj][r];
      v[1] = acc[1][mj][r];
      v[2] = acc[2][mj][r];
      *(f32x3*)p = v;
    }
}

extern "C" void kernel_launch(void* const* d_in, const int* in_sizes, int n_in,
                              void* d_out, int out_size, void* d_ws, size_t ws_size,
                              hipStream_t stream) {
  (void)in_sizes; (void)n_in; (void)out_size; (void)ws_size;
  const float* a    = (const float*)d_in[1];
  const float* bias = (const float*)d_in[8];

  float* ws      = (float*)d_ws;
  float* hfeat   = ws;
  float* sself   = hfeat + (size_t)BN * HID;
  float* sneigh  = sself + (size_t)BN * H;
  float* u_ws0   = sneigh + (size_t)BN * H;
  short* sp      = (short*)(u_ws0 + 3 * (size_t)BN * HID);
  auto alloc_s = [&](size_t n) { short* p = sp; sp += n; return p; };

  short* conv_hi = alloc_s((size_t)BN * HID);
  short* conv_lo = alloc_s((size_t)BN * HID);
  short* h_hi[3]; short* h_lo[3];
  for (int c = 0; c < 3; ++c) { h_hi[c] = alloc_s((size_t)BN * HID); h_lo[c] = alloc_s((size_t)BN * HID); }
  short* rh_hi[3]; short* rh_lo[3];
  for (int c = 0; c < 3; ++c) { rh_hi[c] = alloc_s((size_t)BN * HID); rh_lo[c] = alloc_s((size_t)BN * HID); }
  short* hp_hi[3]; short* hp_lo[3];
  for (int c = 0; c < 3; ++c) { hp_hi[c] = alloc_s((size_t)BN * HID); hp_lo[c] = alloc_s((size_t)BN * HID); }
  short* gbb[3];
  for (int c = 0; c < 3; ++c) gbb[c] = alloc_s((size_t)BN * HID);

  float* out = (float*)d_out;

  PreArgs pa;
  pa.x = (const float*)d_in[0];
  pa.gk = (const float*)d_in[5];
  pa.asel = (const float*)d_in[6];
  pa.anei = (const float*)d_in[7];
  pa.hfeat = hfeat; pa.sself = sself; pa.sneigh = sneigh;

  GArgs ga;
  ga.chi = conv_hi; ga.clo = conv_lo;
  ga.h[0] = (const float*)d_in[2];
  ga.h[1] = (const float*)d_in[3];
  ga.h[2] = (const float*)d_in[4];
  for (int c = 0; c < 3; ++c) {
    pa.h[c] = ga.h[c];
    pa.hh[c] = h_hi[c]; pa.hl[c] = h_lo[c];
    const int base = 9 + c * 6;
    ga.hhi[c] = h_hi[c]; ga.hlo[c] = h_lo[c];
    ga.bu[c] = (const float*)d_in[base + 1];
    ga.br[c] = (const float*)d_in[base + 3];
    ga.bc[c] = (const float*)d_in[base + 5];
    short* wu_h = alloc_s(256 * 128); short* wu_l = alloc_s(256 * 128);
    short* wr_h = alloc_s(256 * 128); short* wr_l = alloc_s(256 * 128);
    short* wc_h = alloc_s(256 * 128); short* wc_l = alloc_s(256 * 128);
    short* rt_h = alloc_s(128 * 128); short* rt_l = alloc_s(128 * 128);
    const int pb = c * 4;
    pa.src[pb + 0] = (const float*)d_in[base + 0]; pa.whi[pb + 0] = wu_h; pa.wlo[pb + 0] = wu_l; pa.nks[pb + 0] = 8;
    pa.src[pb + 1] = (const float*)d_in[base + 2]; pa.whi[pb + 1] = wr_h; pa.wlo[pb + 1] = wr_l; pa.nks[pb + 1] = 8;
    pa.src[pb + 2] = (const float*)d_in[base + 4]; pa.whi[pb + 2] = wc_h; pa.wlo[pb + 2] = wc_l; pa.nks[pb + 2] = 8;
    pa.src[pb + 3] = (const float*)d_in[27 + c];   pa.whi[pb + 3] = rt_h; pa.wlo[pb + 3] = rt_l; pa.nks[pb + 3] = 4;
    ga.WuH[c] = wu_h; ga.WuL[c] = wu_l;
    ga.WrH[c] = wr_h; ga.WrL[c] = wr_l;
    ga.WcH[c] = wc_h; ga.WcL[c] = wc_l;
    ga.RtH[c] = rt_h; ga.RtL[c] = rt_l;
    ga.u_ws[c] = u_ws0 + (size_t)c * BN * HID;
    ga.rhh[c] = rh_hi[c]; ga.rhl[c] = rh_lo[c];
    ga.hph[c] = hp_hi[c]; ga.hpl[c] = hp_lo[c];
    ga.hout[c] = out + LOG_SZ + (size_t)c * BN * HID;
    ga.gb[c] = gbb[c];
  }

  k_pre<<<BN / 2 + 96, 256, 0, stream>>>(pa);
  k_attn<<<BN / 4, 256, 0, stream>>>(a, hfeat, sself, sneigh, bias, conv_hi, conv_lo);
  k_ur<<<dim3(BN / 64, 4, 3), 256, 0, stream>>>(ga);
  k_c<<<dim3(BN / 64, 4, 3), 256, 0, stream>>>(ga);
  k_g<<<dim3(BN / 64, 4, 3), 256, 0, stream>>>(ga);
  dim3 g2(N / 16, N / 512, B);
  k_bilinear<<<g2, 512, 0, stream>>>(gbb[0], gbb[1], gbb[2],
                                     hp_hi[0], hp_hi[1], hp_hi[2], out);
}

// Round 15
// 113.480 us; speedup vs baseline: 1.0905x; 1.0905x over previous
//
#include <hip/hip_runtime.h>
#include <hip/hip_bf16.h>

typedef __attribute__((ext_vector_type(4))) float f32x4;
typedef __attribute__((ext_vector_type(8))) short bf16x8;

static constexpr int B   = 2;
static constexpr int N   = 2048;
static constexpr int F   = 64;
static constexpr int H   = 4;
static constexpr int HID = 128;
static constexpr int BN  = B * N;
static constexpr size_t LOG_SZ = (size_t)B * N * N * 3;

__device__ __forceinline__ float sigmoidf_(float x) { return 1.0f / (1.0f + __expf(-x)); }
__device__ __forceinline__ float tanhf_(float x) {
  float e = __expf(2.0f * x);
  return 1.0f - 2.0f / (e + 1.0f);      // inf-safe
}
// RNE bf16 split: v = hi + lo with ~2^-17 relative error
__device__ __forceinline__ void split_bf16(float v, short& hi, short& lo) {
  unsigned u = __float_as_uint(v);
  unsigned hr = (u + 0x7FFFu + ((u >> 16) & 1u)) >> 16;
  hi = (short)hr;
  float hv = __uint_as_float(hr << 16);
  float res = v - hv;
  unsigned u2 = __float_as_uint(res);
  lo = (short)((u2 + 0x7FFFu + ((u2 >> 16) & 1u)) >> 16);
}
__device__ __forceinline__ void stage16(const short* gp, short* lp) {
  __builtin_amdgcn_global_load_lds(
      (const __attribute__((address_space(1))) void*)gp,
      (__attribute__((address_space(3))) void*)lp, 16, 0, 0);
}

// ------------- K1: merged prep (weights->frag-order bf16x2) + feat + h-split ---
struct PreArgs {
  const float* x; const float* gk; const float* asel; const float* anei;
  float* hfeat; float* sself; float* sneigh;
  const float* h[3];
  short* hh[3]; short* hl[3];
  const float* src[12];
  short* whi[12]; short* wlo[12];
  int nks[12];
};
__global__ __launch_bounds__(256) void k_pre(PreArgs pa) {
  const int bid = blockIdx.x;
  if (bid < BN / 2) {
    const int t = threadIdx.x;
    const int r = t >> 7, tt = t & 127;
    const int bn = bid * 2 + r;
    __shared__ float xs[2][F];
    if (tt < F) xs[r][tt] = pa.x[(size_t)bn * F + tt];
    const size_t o = (size_t)bn * HID + tt;
    { short hi, lo; split_bf16(pa.h[0][o], hi, lo); pa.hh[0][o] = hi; pa.hl[0][o] = lo; }
    { short hi, lo; split_bf16(pa.h[1][o], hi, lo); pa.hh[1][o] = hi; pa.hl[1][o] = lo; }
    { short hi, lo; split_bf16(pa.h[2][o], hi, lo); pa.hh[2][o] = hi; pa.hl[2][o] = lo; }
    __syncthreads();
    float acc = 0.f;
    #pragma unroll 8
    for (int f = 0; f < F; ++f) acc += xs[r][f] * pa.gk[f * HID + tt];
    pa.hfeat[o] = acc;
    float ps = acc * pa.asel[tt];
    float pn = acc * pa.anei[tt];
    #pragma unroll
    for (int d = 16; d >= 1; d >>= 1) {
      ps += __shfl_xor(ps, d, 32);
      pn += __shfl_xor(pn, d, 32);
    }
    if ((tt & 31) == 0) {
      pa.sself [bn * H + (tt >> 5)] = ps;
      pa.sneigh[bn * H + (tt >> 5)] = pn;
    }
  } else {
    const int pb = bid - BN / 2;
    const int m = pb >> 3, cf = pb & 7;
    const int nksv = pa.nks[m];
    const int wv = threadIdx.x >> 6, lane = threadIdx.x & 63;
    const float* src = pa.src[m];
    short* ph = pa.whi[m];
    short* pl = pa.wlo[m];
    const int col = cf * 16 + (lane & 15);
    const int krow = (lane >> 4) * 8;
    for (int ks = wv; ks < nksv; ks += 4) {
      bf16x8 vh, vl;
      #pragma unroll
      for (int e = 0; e < 8; ++e) {
        const int k = ks * 32 + krow + e;
        short hi, lo; split_bf16(src[(size_t)k * HID + col], hi, lo);
        vh[e] = hi; vl[e] = lo;
      }
      const size_t o = (((size_t)cf * nksv + ks) * 64 + lane) * 8;
      *(bf16x8*)&ph[o] = vh;
      *(bf16x8*)&pl[o] = vl;
    }
  }
}

// ------------- K2: sparse GAT attention — one wave per row -------------
__global__ __launch_bounds__(256) void k_attn(
    const float* __restrict__ a, const float* __restrict__ hfeat,
    const float* __restrict__ sself, const float* __restrict__ sneigh,
    const float* __restrict__ bias,
    short* __restrict__ conv_hi, short* __restrict__ conv_lo) {
  const int wv   = threadIdx.x >> 6;
  const int lane = threadIdx.x & 63;
  const int bi   = blockIdx.x * 4 + wv;
  const int bbase = bi & ~(N - 1);
  __shared__ int   nbr[4][256];
  __shared__ float wts[4][256][4];
  int*   nb       = nbr[wv];
  float (*wt)[4]  = wts[wv];
  const float si0 = sself[bi * H + 0];
  const float si1 = sself[bi * H + 1];
  const float si2 = sself[bi * H + 2];
  const float si3 = sself[bi * H + 3];
  float den0 = 0.f, den1 = 0.f, den2 = 0.f, den3 = 0.f;
  float acc0 = 0.f, acc1 = 0.f;
  const unsigned long long lmlt = ((unsigned long long)1 << lane) - 1ull;
  const float* arow = a + (size_t)bi * N;
  const float* hb   = hfeat + (size_t)bbase * HID;
  const float* snb  = sneigh + (size_t)bbase * H;
  const int h0 = lane >> 5;
  int num = 0;
  auto flush = [&]() {
    asm volatile("s_waitcnt lgkmcnt(0)" ::: "memory");
    for (int n = lane; n < num; n += 64) {
      const int j = nb[n];
      f32x4 sn = *(const f32x4*)&snb[(size_t)j * H];
      float s0 = si0 + sn[0]; s0 = (s0 > 0.f) ? s0 : 0.2f * s0;
      float s1 = si1 + sn[1]; s1 = (s1 > 0.f) ? s1 : 0.2f * s1;
      float s2 = si2 + sn[2]; s2 = (s2 > 0.f) ? s2 : 0.2f * s2;
      float s3 = si3 + sn[3]; s3 = (s3 > 0.f) ? s3 : 0.2f * s3;
      float w0 = __expf(s0), w1 = __expf(s1), w2 = __expf(s2), w3 = __expf(s3);
      wt[n][0] = w0; wt[n][1] = w1; wt[n][2] = w2; wt[n][3] = w3;
      den0 += w0; den1 += w1; den2 += w2; den3 += w3;
    }
    asm volatile("s_waitcnt lgkmcnt(0)" ::: "memory");
    #pragma unroll 4
    for (int n = 0; n < num; ++n) {
      const int j  = nb[n];
      const float wA = wt[n][h0];
      const float wB = wt[n][h0 + 2];
      const float* hr = hb + (size_t)j * HID;
      acc0 += wA * hr[lane];
      acc1 += wB * hr[lane + 64];
    }
    asm volatile("s_waitcnt lgkmcnt(0)" ::: "memory");
    num = 0;
  };
  for (int jb = 0; jb < N; jb += 256) {
    f32x4 av = *(const f32x4*)&arow[jb + lane * 4];
    #pragma unroll
    for (int e = 0; e < 4; ++e) {
      const unsigned long long m = __ballot(av[e] > 0.5f);
      if (av[e] > 0.5f) {
        const int pos = num + __popcll(m & lmlt);
        nb[pos] = jb + lane * 4 + e;
      }
      num += __popcll(m);
      if (num > 192) flush();
    }
  }
  if (num > 0) flush();
  #pragma unroll
  for (int d = 32; d >= 1; d >>= 1) {
    den0 += __shfl_xor(den0, d, 64);
    den1 += __shfl_xor(den1, d, 64);
    den2 += __shfl_xor(den2, d, 64);
    den3 += __shfl_xor(den3, d, 64);
  }
  const float dA = h0 ? den1 : den0;
  const float dB = h0 ? den3 : den2;
  const float v0 = acc0 / dA + bias[lane];
  const float v1 = acc1 / dB + bias[64 + lane];
  { short hi, lo; split_bf16(v0, hi, lo);
    conv_hi[(size_t)bi * HID + lane] = hi; conv_lo[(size_t)bi * HID + lane] = lo; }
  { short hi, lo; split_bf16(v1, hi, lo);
    conv_hi[(size_t)bi * HID + 64 + lane] = hi; conv_lo[(size_t)bi * HID + 64 + lane] = lo; }
}

// ------------- shared arg pack -------------
struct GArgs {
  const short* chi; const short* clo;
  const float* h[3];
  const short* hhi[3]; const short* hlo[3];
  const float* bu[3]; const float* br[3]; const float* bc[3];
  const short* WuH[3]; const short* WuL[3];
  const short* WrH[3]; const short* WrL[3];
  const short* WcH[3]; const short* WcL[3];
  const short* RtH[3]; const short* RtL[3];
  float* u_ws[3];
  short* rhh[3]; short* rhl[3];
  short* hph[3]; short* hpl[3];
  float* hout[3]; short* gb[3];
};

// ------------- K3: u+r gates combined -------------
__global__ __launch_bounds__(256) void k_ur(GArgs ga) {
  const int wv = threadIdx.x >> 6, lane = threadIdx.x & 63;
  const int bx = blockIdx.x, cg2 = blockIdx.y, cell = blockIdx.z;
  const int lr = lane & 15, lg = lane >> 4, kb = lg * 8;
  const int R0 = bx * 64 + wv * 16;
  __shared__ short wlds[4][16][64][8];
  bf16x8 a_h[8], a_l[8];
  {
    const size_t ab = (size_t)(R0 + lr) * HID + kb;
    const short* hhi = ga.hhi[cell]; const short* hlo = ga.hlo[cell];
    #pragma unroll
    for (int ks = 0; ks < 4; ++ks) {
      a_h[ks]     = *(const bf16x8*)&ga.chi[ab + ks * 32];
      a_l[ks]     = *(const bf16x8*)&ga.clo[ab + ks * 32];
      a_h[4 + ks] = *(const bf16x8*)&hhi[ab + ks * 32];
      a_l[4 + ks] = *(const bf16x8*)&hlo[ab + ks * 32];
    }
  }
  {
    const short* srcs[4] = { ga.WuH[cell], ga.WuL[cell], ga.WrH[cell], ga.WrL[cell] };
    const short* sp = srcs[wv];
    #pragma unroll
    for (int f = 0; f < 16; ++f) {
      const short* gp = sp + (((size_t)((cg2 * 2 + (f >> 3)) * 8 + (f & 7))) * 64 + lane) * 8;
      stage16(gp, &wlds[wv][f][0][0]);
    }
  }
  asm volatile("s_waitcnt vmcnt(0)" ::: "memory");
  __syncthreads();
  f32x4 au[2] = {}, ar[2] = {};
  #pragma unroll
  for (int ks = 0; ks < 8; ++ks) {
    const bf16x8 ah = a_h[ks], al = a_l[ks];
    #pragma unroll
    for (int cfl = 0; cfl < 2; ++cfl) {
      const int f = cfl * 8 + ks;
      bf16x8 buh = *(const bf16x8*)&wlds[0][f][lane][0];
      bf16x8 bul = *(const bf16x8*)&wlds[1][f][lane][0];
      bf16x8 brh = *(const bf16x8*)&wlds[2][f][lane][0];
      bf16x8 brl = *(const bf16x8*)&wlds[3][f][lane][0];
      au[cfl] = __builtin_amdgcn_mfma_f32_16x16x32_bf16(ah, buh, au[cfl], 0, 0, 0);
      au[cfl] = __builtin_amdgcn_mfma_f32_16x16x32_bf16(ah, bul, au[cfl], 0, 0, 0);
      au[cfl] = __builtin_amdgcn_mfma_f32_16x16x32_bf16(al, buh, au[cfl], 0, 0, 0);
      ar[cfl] = __builtin_amdgcn_mfma_f32_16x16x32_bf16(ah, brh, ar[cfl], 0, 0, 0);
      ar[cfl] = __builtin_amdgcn_mfma_f32_16x16x32_bf16(ah, brl, ar[cfl], 0, 0, 0);
      ar[cfl] = __builtin_amdgcn_mfma_f32_16x16x32_bf16(al, brh, ar[cfl], 0, 0, 0);
    }
  }
  const float* bu = ga.bu[cell];
  const float* br = ga.br[cell];
  const float* hsrc = ga.h[cell];
  float* uws = ga.u_ws[cell];
  short* rhh = ga.rhh[cell]; short* rhl = ga.rhl[cell];
  #pragma unroll
  for (int cfl = 0; cfl < 2; ++cfl) {
    const int col = cg2 * 32 + cfl * 16 + lr;
    #pragma unroll
    for (int q = 0; q < 4; ++q) {
      const int row = R0 + lg * 4 + q;
      const int n = row & (N - 1);
      uws[(size_t)row * HID + col] = sigmoidf_(au[cfl][q] + bu[n]);
      const float rv = sigmoidf_(ar[cfl][q] + br[n]);
      const float rhv = rv * hsrc[(size_t)row * HID + col];
      short hi, lo; split_bf16(rhv, hi, lo);
      rhh[(size_t)row * HID + col] = hi;
      rhl[(size_t)row * HID + col] = lo;
    }
  }
}

// ------------- K4: c gate + h' -------------
__global__ __launch_bounds__(256) void k_c(GArgs ga) {
  const int wv = threadIdx.x >> 6, lane = threadIdx.x & 63;
  const int bx = blockIdx.x, cg2 = blockIdx.y, cell = blockIdx.z;
  const int lr = lane & 15, lg = lane >> 4, kb = lg * 8;
  const int R0 = bx * 64 + wv * 16;
  __shared__ short wlds[2][16][64][8];
  bf16x8 a_h[8], a_l[8];
  {
    const size_t ab = (size_t)(R0 + lr) * HID + kb;
    const short* rhh = ga.rhh[cell]; const short* rhl = ga.rhl[cell];
    #pragma unroll
    for (int ks = 0; ks < 4; ++ks) {
      a_h[ks]     = *(const bf16x8*)&ga.chi[ab + ks * 32];
      a_l[ks]     = *(const bf16x8*)&ga.clo[ab + ks * 32];
      a_h[4 + ks] = *(const bf16x8*)&rhh[ab + ks * 32];
      a_l[4 + ks] = *(const bf16x8*)&rhl[ab + ks * 32];
    }
  }
  {
    const short* WH = ga.WcH[cell];
    const short* WL = ga.WcL[cell];
    #pragma unroll
    for (int i = 0; i < 8; ++i) {
      const int fid = wv * 8 + i;
      const int combo = fid >> 4, f = fid & 15;
      const short* src = combo ? WL : WH;
      const short* gp = src + (((size_t)((cg2 * 2 + (f >> 3)) * 8 + (f & 7))) * 64 + lane) * 8;
      stage16(gp, &wlds[combo][f][0][0]);
    }
  }
  asm volatile("s_waitcnt vmcnt(0)" ::: "memory");
  __syncthreads();
  f32x4 acc[2] = {};
  #pragma unroll
  for (int ks = 0; ks < 8; ++ks) {
    const bf16x8 ah = a_h[ks], al = a_l[ks];
    #pragma unroll
    for (int cfl = 0; cfl < 2; ++cfl) {
      const int f = cfl * 8 + ks;
      bf16x8 bh = *(const bf16x8*)&wlds[0][f][lane][0];
      bf16x8 bl = *(const bf16x8*)&wlds[1][f][lane][0];
      acc[cfl] = __builtin_amdgcn_mfma_f32_16x16x32_bf16(ah, bh, acc[cfl], 0, 0, 0);
      acc[cfl] = __builtin_amdgcn_mfma_f32_16x16x32_bf16(ah, bl, acc[cfl], 0, 0, 0);
      acc[cfl] = __builtin_amdgcn_mfma_f32_16x16x32_bf16(al, bh, acc[cfl], 0, 0, 0);
    }
  }
  const float* bc = ga.bc[cell];
  const float* uw = ga.u_ws[cell];
  const float* hsrc = ga.h[cell];
  float* hout = ga.hout[cell];
  short* hph = ga.hph[cell]; short* hpl = ga.hpl[cell];
  #pragma unroll
  for (int cfl = 0; cfl < 2; ++cfl) {
    const int col = cg2 * 32 + cfl * 16 + lr;
    #pragma unroll
    for (int q = 0; q < 4; ++q) {
      const int row = R0 + lg * 4 + q;
      const float cv = tanhf_(acc[cfl][q] + bc[row & (N - 1)]);
      const float uv = uw[(size_t)row * HID + col];
      const float hv = hsrc[(size_t)row * HID + col];
      const float o = uv * hv + (1.f - uv) * cv;
      __builtin_nontemporal_store(o, &hout[(size_t)row * HID + col]);
      short hi, lo; split_bf16(o, hi, lo);
      hph[(size_t)row * HID + col] = hi;
      hpl[(size_t)row * HID + col] = lo;
    }
  }
}

// ------------- K5: g = h' @ R -------------
__global__ __launch_bounds__(256) void k_g(GArgs ga) {
  const int wv = threadIdx.x >> 6, lane = threadIdx.x & 63;
  const int bx = blockIdx.x, cg2 = blockIdx.y, cell = blockIdx.z;
  const int lr = lane & 15, lg = lane >> 4, kb = lg * 8;
  const int R0 = bx * 64 + wv * 16;
  __shared__ short wlds[2][8][64][8];
  bf16x8 a_h[4], a_l[4];
  {
    const size_t ab = (size_t)(R0 + lr) * HID + kb;
    const short* hph = ga.hph[cell]; const short* hpl = ga.hpl[cell];
    #pragma unroll
    for (int ks = 0; ks < 4; ++ks) {
      a_h[ks] = *(const bf16x8*)&hph[ab + ks * 32];
      a_l[ks] = *(const bf16x8*)&hpl[ab + ks * 32];
    }
  }
  {
    #pragma unroll
    for (int i = 0; i < 4; ++i) {
      const int fid = wv * 4 + i;
      const int combo = fid >> 3, f = fid & 7;
      const short* src = combo ? ga.RtL[cell] : ga.RtH[cell];
      const short* gp = src + (((size_t)((cg2 * 2 + (f >> 2)) * 4 + (f & 3))) * 64 + lane) * 8;
      stage16(gp, &wlds[combo][f][0][0]);
    }
  }
  asm volatile("s_waitcnt vmcnt(0)" ::: "memory");
  __syncthreads();
  f32x4 acc[2] = {};
  #pragma unroll
  for (int ks = 0; ks < 4; ++ks) {
    const bf16x8 ah = a_h[ks], al = a_l[ks];
    #pragma unroll
    for (int cfl = 0; cfl < 2; ++cfl) {
      const int f = cfl * 4 + ks;
      bf16x8 bh = *(const bf16x8*)&wlds[0][f][lane][0];
      bf16x8 bl = *(const bf16x8*)&wlds[1][f][lane][0];
      acc[cfl] = __builtin_amdgcn_mfma_f32_16x16x32_bf16(ah, bh, acc[cfl], 0, 0, 0);
      acc[cfl] = __builtin_amdgcn_mfma_f32_16x16x32_bf16(ah, bl, acc[cfl], 0, 0, 0);
      acc[cfl] = __builtin_amdgcn_mfma_f32_16x16x32_bf16(al, bh, acc[cfl], 0, 0, 0);
    }
  }
  short* gbo = ga.gb[cell];
  #pragma unroll
  for (int cfl = 0; cfl < 2; ++cfl) {
    const int col = cg2 * 32 + cfl * 16 + lr;
    #pragma unroll
    for (int q = 0; q < 4; ++q) {
      const int row = R0 + lg * 4 + q;
      short hi, lo; split_bf16(acc[cfl][q], hi, lo);
      gbo[(size_t)row * HID + col] = hi;
    }
  }
}

// ------------- K6: logits — 64x64 tiles, LDS-repacked dwordx4-dense stores -----
// grid (N/64, N/64, B), 256 thr = 4 waves; wave owns 32x32; XCD swizzle kept.
__global__ __launch_bounds__(256) void k_bilinear(
    const short* __restrict__ g0, const short* __restrict__ g1,
    const short* __restrict__ g2, const short* __restrict__ h0,
    const short* __restrict__ h1, const short* __restrict__ h2,
    float* __restrict__ out) {
  const int id  = blockIdx.y * 32 + blockIdx.x;      // 0..1023
  const int id2 = (id & 7) * 128 + (id >> 3);        // bijective XCD swizzle
  const int ti = id2 & 31, tj = id2 >> 5;
  const int b = blockIdx.z;
  const int t = threadIdx.x;
  const int w = t >> 6, l = t & 63;
  const int wi = w >> 1, wj = w & 1;
  const int i_base = ti * 64 + wi * 32;
  const int j_base = tj * 64 + wj * 32;
  const short* gbs[3] = {g0, g1, g2};
  const short* hbs[3] = {h0, h1, h2};
  const int lr = l & 15;
  const int kb = (l >> 4) * 8;
  f32x4 acc[3][2][2] = {};
  for (int k0 = 0; k0 < HID; k0 += 32) {
    #pragma unroll
    for (int d = 0; d < 3; ++d) {
      bf16x8 af0 = *(const bf16x8*)&gbs[d][(size_t)(b * N + i_base + lr) * HID + k0 + kb];
      bf16x8 af1 = *(const bf16x8*)&gbs[d][(size_t)(b * N + i_base + 16 + lr) * HID + k0 + kb];
      bf16x8 bf0 = *(const bf16x8*)&hbs[d][(size_t)(b * N + j_base + lr) * HID + k0 + kb];
      bf16x8 bf1 = *(const bf16x8*)&hbs[d][(size_t)(b * N + j_base + 16 + lr) * HID + k0 + kb];
      acc[d][0][0] = __builtin_amdgcn_mfma_f32_16x16x32_bf16(af0, bf0, acc[d][0][0], 0, 0, 0);
      acc[d][0][1] = __builtin_amdgcn_mfma_f32_16x16x32_bf16(af0, bf1, acc[d][0][1], 0, 0, 0);
      acc[d][1][0] = __builtin_amdgcn_mfma_f32_16x16x32_bf16(af1, bf0, acc[d][1][0], 0, 0, 0);
      acc[d][1][1] = __builtin_amdgcn_mfma_f32_16x16x32_bf16(af1, bf1, acc[d][1][1], 0, 0, 0);
    }
  }
  // repack through LDS: wave-private 32x32x3 tile (row stride 100 dw = 400B, 16B-aligned)
  __shared__ float tile[4][32][100];
  const int orow = (l >> 4) * 4;
  const int col  = l & 15;
  #pragma unroll
  for (int mi = 0; mi < 2; ++mi)
    #pragma unroll
    for (int mj = 0; mj < 2; ++mj)
      #pragma unroll
      for (int r = 0; r < 4; ++r) {
        float* tp = &tile[w][mi * 16 + orow + r][(mj * 16 + col) * 3];
        tp[0] = acc[0][mi][mj][r];
        tp[1] = acc[1][mi][mj][r];
        tp[2] = acc[2][mi][mj][r];
      }
  __syncthreads();
  // dense store phase: 12 x (ds_read_b128 + aligned global_store_dwordx4) per lane
  const size_t obase = (((size_t)(b * N + i_base)) * N + j_base) * 3;
  #pragma unroll
  for (int pass = 0; pass < 12; ++pass) {
    const int ci  = pass * 64 + l;      // 0..767 chunk index (4 dwords each)
    const int row = ci / 24;            // local row 0..31 (24 chunks = 96 dw/row)
    const int c4  = (ci % 24) * 4;      // dword offset within row
    f32x4 v = *(const f32x4*)&tile[w][row][c4];
    *(f32x4*)&out[obase + (size_t)row * N * 3 + c4] = v;
  }
}

extern "C" void kernel_launch(void* const* d_in, const int* in_sizes, int n_in,
                              void* d_out, int out_size, void* d_ws, size_t ws_size,
                              hipStream_t stream) {
  (void)in_sizes; (void)n_in; (void)out_size; (void)ws_size;
  const float* a    = (const float*)d_in[1];
  const float* bias = (const float*)d_in[8];

  float* ws      = (float*)d_ws;
  float* hfeat   = ws;
  float* sself   = hfeat + (size_t)BN * HID;
  float* sneigh  = sself + (size_t)BN * H;
  float* u_ws0   = sneigh + (size_t)BN * H;
  short* sp      = (short*)(u_ws0 + 3 * (size_t)BN * HID);
  auto alloc_s = [&](size_t n) { short* p = sp; sp += n; return p; };

  short* conv_hi = alloc_s((size_t)BN * HID);
  short* conv_lo = alloc_s((size_t)BN * HID);
  short* h_hi[3]; short* h_lo[3];
  for (int c = 0; c < 3; ++c) { h_hi[c] = alloc_s((size_t)BN * HID); h_lo[c] = alloc_s((size_t)BN * HID); }
  short* rh_hi[3]; short* rh_lo[3];
  for (int c = 0; c < 3; ++c) { rh_hi[c] = alloc_s((size_t)BN * HID); rh_lo[c] = alloc_s((size_t)BN * HID); }
  short* hp_hi[3]; short* hp_lo[3];
  for (int c = 0; c < 3; ++c) { hp_hi[c] = alloc_s((size_t)BN * HID); hp_lo[c] = alloc_s((size_t)BN * HID); }
  short* gbb[3];
  for (int c = 0; c < 3; ++c) gbb[c] = alloc_s((size_t)BN * HID);

  float* out = (float*)d_out;

  PreArgs pa;
  pa.x = (const float*)d_in[0];
  pa.gk = (const float*)d_in[5];
  pa.asel = (const float*)d_in[6];
  pa.anei = (const float*)d_in[7];
  pa.hfeat = hfeat; pa.sself = sself; pa.sneigh = sneigh;

  GArgs ga;
  ga.chi = conv_hi; ga.clo = conv_lo;
  ga.h[0] = (const float*)d_in[2];
  ga.h[1] = (const float*)d_in[3];
  ga.h[2] = (const float*)d_in[4];
  for (int c = 0; c < 3; ++c) {
    pa.h[c] = ga.h[c];
    pa.hh[c] = h_hi[c]; pa.hl[c] = h_lo[c];
    const int base = 9 + c * 6;
    ga.hhi[c] = h_hi[c]; ga.hlo[c] = h_lo[c];
    ga.bu[c] = (const float*)d_in[base + 1];
    ga.br[c] = (const float*)d_in[base + 3];
    ga.bc[c] = (const float*)d_in[base + 5];
    short* wu_h = alloc_s(256 * 128); short* wu_l = alloc_s(256 * 128);
    short* wr_h = alloc_s(256 * 128); short* wr_l = alloc_s(256 * 128);
    short* wc_h = alloc_s(256 * 128); short* wc_l = alloc_s(256 * 128);
    short* rt_h = alloc_s(128 * 128); short* rt_l = alloc_s(128 * 128);
    const int pb = c * 4;
    pa.src[pb + 0] = (const float*)d_in[base + 0]; pa.whi[pb + 0] = wu_h; pa.wlo[pb + 0] = wu_l; pa.nks[pb + 0] = 8;
    pa.src[pb + 1] = (const float*)d_in[base + 2]; pa.whi[pb + 1] = wr_h; pa.wlo[pb + 1] = wr_l; pa.nks[pb + 1] = 8;
    pa.src[pb + 2] = (const float*)d_in[base + 4]; pa.whi[pb + 2] = wc_h; pa.wlo[pb + 2] = wc_l; pa.nks[pb + 2] = 8;
    pa.src[pb + 3] = (const float*)d_in[27 + c];   pa.whi[pb + 3] = rt_h; pa.wlo[pb + 3] = rt_l; pa.nks[pb + 3] = 4;
    ga.WuH[c] = wu_h; ga.WuL[c] = wu_l;
    ga.WrH[c] = wr_h; ga.WrL[c] = wr_l;
    ga.WcH[c] = wc_h; ga.WcL[c] = wc_l;
    ga.RtH[c] = rt_h; ga.RtL[c] = rt_l;
    ga.u_ws[c] = u_ws0 + (size_t)c * BN * HID;
    ga.rhh[c] = rh_hi[c]; ga.rhl[c] = rh_lo[c];
    ga.hph[c] = hp_hi[c]; ga.hpl[c] = hp_lo[c];
    ga.hout[c] = out + LOG_SZ + (size_t)c * BN * HID;
    ga.gb[c] = gbb[c];
  }

  k_pre<<<BN / 2 + 96, 256, 0, stream>>>(pa);
  k_attn<<<BN / 4, 256, 0, stream>>>(a, hfeat, sself, sneigh, bias, conv_hi, conv_lo);
  k_ur<<<dim3(BN / 64, 4, 3), 256, 0, stream>>>(ga);
  k_c<<<dim3(BN / 64, 4, 3), 256, 0, stream>>>(ga);
  k_g<<<dim3(BN / 64, 4, 3), 256, 0, stream>>>(ga);
  dim3 g2(N / 64, N / 64, B);
  k_bilinear<<<g2, 256, 0, stream>>>(gbb[0], gbb[1], gbb[2],
                                     hp_hi[0], hp_hi[1], hp_hi[2], out);
}

// Round 16
// 108.195 us; speedup vs baseline: 1.1437x; 1.0489x over previous
//
#include <hip/hip_runtime.h>
#include <hip/hip_bf16.h>

typedef __attribute__((ext_vector_type(4))) float f32x4;
typedef __attribute__((ext_vector_type(3))) float f32x3;
typedef __attribute__((ext_vector_type(8))) short bf16x8;

static constexpr int B   = 2;
static constexpr int N   = 2048;
static constexpr int F   = 64;
static constexpr int H   = 4;
static constexpr int HID = 128;
static constexpr int BN  = B * N;
static constexpr size_t LOG_SZ = (size_t)B * N * N * 3;

__device__ __forceinline__ float sigmoidf_(float x) { return 1.0f / (1.0f + __expf(-x)); }
__device__ __forceinline__ float tanhf_(float x) {
  float e = __expf(2.0f * x);
  return 1.0f - 2.0f / (e + 1.0f);      // inf-safe
}
// RNE bf16 split: v = hi + lo with ~2^-17 relative error
__device__ __forceinline__ void split_bf16(float v, short& hi, short& lo) {
  unsigned u = __float_as_uint(v);
  unsigned hr = (u + 0x7FFFu + ((u >> 16) & 1u)) >> 16;
  hi = (short)hr;
  float hv = __uint_as_float(hr << 16);
  float res = v - hv;
  unsigned u2 = __float_as_uint(res);
  lo = (short)((u2 + 0x7FFFu + ((u2 >> 16) & 1u)) >> 16);
}
__device__ __forceinline__ void stage16(const short* gp, short* lp) {
  __builtin_amdgcn_global_load_lds(
      (const __attribute__((address_space(1))) void*)gp,
      (__attribute__((address_space(3))) void*)lp, 16, 0, 0);
}

// ------------- K1: merged prep (weights->frag-order bf16x2) + feat + h-split ---
struct PreArgs {
  const float* x; const float* gk; const float* asel; const float* anei;
  float* hfeat; float* sself; float* sneigh;
  const float* h[3];
  short* hh[3]; short* hl[3];
  const float* src[12];
  short* whi[12]; short* wlo[12];
  int nks[12];
};
__global__ __launch_bounds__(256) void k_pre(PreArgs pa) {
  const int bid = blockIdx.x;
  if (bid < BN / 2) {
    const int t = threadIdx.x;
    const int r = t >> 7, tt = t & 127;
    const int bn = bid * 2 + r;
    __shared__ float xs[2][F];
    if (tt < F) xs[r][tt] = pa.x[(size_t)bn * F + tt];
    const size_t o = (size_t)bn * HID + tt;
    { short hi, lo; split_bf16(pa.h[0][o], hi, lo); pa.hh[0][o] = hi; pa.hl[0][o] = lo; }
    { short hi, lo; split_bf16(pa.h[1][o], hi, lo); pa.hh[1][o] = hi; pa.hl[1][o] = lo; }
    { short hi, lo; split_bf16(pa.h[2][o], hi, lo); pa.hh[2][o] = hi; pa.hl[2][o] = lo; }
    __syncthreads();
    float acc = 0.f;
    #pragma unroll 8
    for (int f = 0; f < F; ++f) acc += xs[r][f] * pa.gk[f * HID + tt];
    pa.hfeat[o] = acc;
    float ps = acc * pa.asel[tt];
    float pn = acc * pa.anei[tt];
    #pragma unroll
    for (int d = 16; d >= 1; d >>= 1) {
      ps += __shfl_xor(ps, d, 32);
      pn += __shfl_xor(pn, d, 32);
    }
    if ((tt & 31) == 0) {
      pa.sself [bn * H + (tt >> 5)] = ps;
      pa.sneigh[bn * H + (tt >> 5)] = pn;
    }
  } else {
    const int pb = bid - BN / 2;
    const int m = pb >> 3, cf = pb & 7;
    const int nksv = pa.nks[m];
    const int wv = threadIdx.x >> 6, lane = threadIdx.x & 63;
    const float* src = pa.src[m];
    short* ph = pa.whi[m];
    short* pl = pa.wlo[m];
    const int col = cf * 16 + (lane & 15);
    const int krow = (lane >> 4) * 8;
    for (int ks = wv; ks < nksv; ks += 4) {
      bf16x8 vh, vl;
      #pragma unroll
      for (int e = 0; e < 8; ++e) {
        const int k = ks * 32 + krow + e;
        short hi, lo; split_bf16(src[(size_t)k * HID + col], hi, lo);
        vh[e] = hi; vl[e] = lo;
      }
      const size_t o = (((size_t)cf * nksv + ks) * 64 + lane) * 8;
      *(bf16x8*)&ph[o] = vh;
      *(bf16x8*)&pl[o] = vl;
    }
  }
}

// ------------- K2: sparse GAT attention — one wave per row -------------
__global__ __launch_bounds__(256) void k_attn(
    const float* __restrict__ a, const float* __restrict__ hfeat,
    const float* __restrict__ sself, const float* __restrict__ sneigh,
    const float* __restrict__ bias,
    short* __restrict__ conv_hi, short* __restrict__ conv_lo) {
  const int wv   = threadIdx.x >> 6;
  const int lane = threadIdx.x & 63;
  const int bi   = blockIdx.x * 4 + wv;
  const int bbase = bi & ~(N - 1);
  __shared__ int   nbr[4][256];
  __shared__ float wts[4][256][4];
  int*   nb       = nbr[wv];
  float (*wt)[4]  = wts[wv];
  const float si0 = sself[bi * H + 0];
  const float si1 = sself[bi * H + 1];
  const float si2 = sself[bi * H + 2];
  const float si3 = sself[bi * H + 3];
  float den0 = 0.f, den1 = 0.f, den2 = 0.f, den3 = 0.f;
  float acc0 = 0.f, acc1 = 0.f;
  const unsigned long long lmlt = ((unsigned long long)1 << lane) - 1ull;
  const float* arow = a + (size_t)bi * N;
  const float* hb   = hfeat + (size_t)bbase * HID;
  const float* snb  = sneigh + (size_t)bbase * H;
  const int h0 = lane >> 5;
  int num = 0;
  auto flush = [&]() {
    asm volatile("s_waitcnt lgkmcnt(0)" ::: "memory");
    for (int n = lane; n < num; n += 64) {
      const int j = nb[n];
      f32x4 sn = *(const f32x4*)&snb[(size_t)j * H];
      float s0 = si0 + sn[0]; s0 = (s0 > 0.f) ? s0 : 0.2f * s0;
      float s1 = si1 + sn[1]; s1 = (s1 > 0.f) ? s1 : 0.2f * s1;
      float s2 = si2 + sn[2]; s2 = (s2 > 0.f) ? s2 : 0.2f * s2;
      float s3 = si3 + sn[3]; s3 = (s3 > 0.f) ? s3 : 0.2f * s3;
      float w0 = __expf(s0), w1 = __expf(s1), w2 = __expf(s2), w3 = __expf(s3);
      wt[n][0] = w0; wt[n][1] = w1; wt[n][2] = w2; wt[n][3] = w3;
      den0 += w0; den1 += w1; den2 += w2; den3 += w3;
    }
    asm volatile("s_waitcnt lgkmcnt(0)" ::: "memory");
    #pragma unroll 4
    for (int n = 0; n < num; ++n) {
      const int j  = nb[n];
      const float wA = wt[n][h0];
      const float wB = wt[n][h0 + 2];
      const float* hr = hb + (size_t)j * HID;
      acc0 += wA * hr[lane];
      acc1 += wB * hr[lane + 64];
    }
    asm volatile("s_waitcnt lgkmcnt(0)" ::: "memory");
    num = 0;
  };
  for (int jb = 0; jb < N; jb += 256) {
    f32x4 av = *(const f32x4*)&arow[jb + lane * 4];
    #pragma unroll
    for (int e = 0; e < 4; ++e) {
      const unsigned long long m = __ballot(av[e] > 0.5f);
      if (av[e] > 0.5f) {
        const int pos = num + __popcll(m & lmlt);
        nb[pos] = jb + lane * 4 + e;
      }
      num += __popcll(m);
      if (num > 192) flush();
    }
  }
  if (num > 0) flush();
  #pragma unroll
  for (int d = 32; d >= 1; d >>= 1) {
    den0 += __shfl_xor(den0, d, 64);
    den1 += __shfl_xor(den1, d, 64);
    den2 += __shfl_xor(den2, d, 64);
    den3 += __shfl_xor(den3, d, 64);
  }
  const float dA = h0 ? den1 : den0;
  const float dB = h0 ? den3 : den2;
  const float v0 = acc0 / dA + bias[lane];
  const float v1 = acc1 / dB + bias[64 + lane];
  { short hi, lo; split_bf16(v0, hi, lo);
    conv_hi[(size_t)bi * HID + lane] = hi; conv_lo[(size_t)bi * HID + lane] = lo; }
  { short hi, lo; split_bf16(v1, hi, lo);
    conv_hi[(size_t)bi * HID + 64 + lane] = hi; conv_lo[(size_t)bi * HID + 64 + lane] = lo; }
}

// ------------- shared arg pack -------------
struct GArgs {
  const short* chi; const short* clo;
  const float* h[3];
  const short* hhi[3]; const short* hlo[3];
  const float* bu[3]; const float* br[3]; const float* bc[3];
  const short* WuH[3]; const short* WuL[3];
  const short* WrH[3]; const short* WrL[3];
  const short* WcH[3]; const short* WcL[3];
  const short* RtH[3]; const short* RtL[3];
  float* u_ws[3];
  short* rhh[3]; short* rhl[3];
  short* hph[3]; short* hpl[3];
  float* hout[3]; short* gb[3];
};

// ------------- K3: u+r gates combined -------------
__global__ __launch_bounds__(256) void k_ur(GArgs ga) {
  const int wv = threadIdx.x >> 6, lane = threadIdx.x & 63;
  const int bx = blockIdx.x, cg2 = blockIdx.y, cell = blockIdx.z;
  const int lr = lane & 15, lg = lane >> 4, kb = lg * 8;
  const int R0 = bx * 64 + wv * 16;
  __shared__ short wlds[4][16][64][8];
  bf16x8 a_h[8], a_l[8];
  {
    const size_t ab = (size_t)(R0 + lr) * HID + kb;
    const short* hhi = ga.hhi[cell]; const short* hlo = ga.hlo[cell];
    #pragma unroll
    for (int ks = 0; ks < 4; ++ks) {
      a_h[ks]     = *(const bf16x8*)&ga.chi[ab + ks * 32];
      a_l[ks]     = *(const bf16x8*)&ga.clo[ab + ks * 32];
      a_h[4 + ks] = *(const bf16x8*)&hhi[ab + ks * 32];
      a_l[4 + ks] = *(const bf16x8*)&hlo[ab + ks * 32];
    }
  }
  {
    const short* srcs[4] = { ga.WuH[cell], ga.WuL[cell], ga.WrH[cell], ga.WrL[cell] };
    const short* sp = srcs[wv];
    #pragma unroll
    for (int f = 0; f < 16; ++f) {
      const short* gp = sp + (((size_t)((cg2 * 2 + (f >> 3)) * 8 + (f & 7))) * 64 + lane) * 8;
      stage16(gp, &wlds[wv][f][0][0]);
    }
  }
  asm volatile("s_waitcnt vmcnt(0)" ::: "memory");
  __syncthreads();
  f32x4 au[2] = {}, ar[2] = {};
  #pragma unroll
  for (int ks = 0; ks < 8; ++ks) {
    const bf16x8 ah = a_h[ks], al = a_l[ks];
    #pragma unroll
    for (int cfl = 0; cfl < 2; ++cfl) {
      const int f = cfl * 8 + ks;
      bf16x8 buh = *(const bf16x8*)&wlds[0][f][lane][0];
      bf16x8 bul = *(const bf16x8*)&wlds[1][f][lane][0];
      bf16x8 brh = *(const bf16x8*)&wlds[2][f][lane][0];
      bf16x8 brl = *(const bf16x8*)&wlds[3][f][lane][0];
      au[cfl] = __builtin_amdgcn_mfma_f32_16x16x32_bf16(ah, buh, au[cfl], 0, 0, 0);
      au[cfl] = __builtin_amdgcn_mfma_f32_16x16x32_bf16(ah, bul, au[cfl], 0, 0, 0);
      au[cfl] = __builtin_amdgcn_mfma_f32_16x16x32_bf16(al, buh, au[cfl], 0, 0, 0);
      ar[cfl] = __builtin_amdgcn_mfma_f32_16x16x32_bf16(ah, brh, ar[cfl], 0, 0, 0);
      ar[cfl] = __builtin_amdgcn_mfma_f32_16x16x32_bf16(ah, brl, ar[cfl], 0, 0, 0);
      ar[cfl] = __builtin_amdgcn_mfma_f32_16x16x32_bf16(al, brh, ar[cfl], 0, 0, 0);
    }
  }
  const float* bu = ga.bu[cell];
  const float* br = ga.br[cell];
  const float* hsrc = ga.h[cell];
  float* uws = ga.u_ws[cell];
  short* rhh = ga.rhh[cell]; short* rhl = ga.rhl[cell];
  #pragma unroll
  for (int cfl = 0; cfl < 2; ++cfl) {
    const int col = cg2 * 32 + cfl * 16 + lr;
    #pragma unroll
    for (int q = 0; q < 4; ++q) {
      const int row = R0 + lg * 4 + q;
      const int n = row & (N - 1);
      uws[(size_t)row * HID + col] = sigmoidf_(au[cfl][q] + bu[n]);
      const float rv = sigmoidf_(ar[cfl][q] + br[n]);
      const float rhv = rv * hsrc[(size_t)row * HID + col];
      short hi, lo; split_bf16(rhv, hi, lo);
      rhh[(size_t)row * HID + col] = hi;
      rhl[(size_t)row * HID + col] = lo;
    }
  }
}

// ------------- K4: c gate + h' -------------
__global__ __launch_bounds__(256) void k_c(GArgs ga) {
  const int wv = threadIdx.x >> 6, lane = threadIdx.x & 63;
  const int bx = blockIdx.x, cg2 = blockIdx.y, cell = blockIdx.z;
  const int lr = lane & 15, lg = lane >> 4, kb = lg * 8;
  const int R0 = bx * 64 + wv * 16;
  __shared__ short wlds[2][16][64][8];
  bf16x8 a_h[8], a_l[8];
  {
    const size_t ab = (size_t)(R0 + lr) * HID + kb;
    const short* rhh = ga.rhh[cell]; const short* rhl = ga.rhl[cell];
    #pragma unroll
    for (int ks = 0; ks < 4; ++ks) {
      a_h[ks]     = *(const bf16x8*)&ga.chi[ab + ks * 32];
      a_l[ks]     = *(const bf16x8*)&ga.clo[ab + ks * 32];
      a_h[4 + ks] = *(const bf16x8*)&rhh[ab + ks * 32];
      a_l[4 + ks] = *(const bf16x8*)&rhl[ab + ks * 32];
    }
  }
  {
    const short* WH = ga.WcH[cell];
    const short* WL = ga.WcL[cell];
    #pragma unroll
    for (int i = 0; i < 8; ++i) {
      const int fid = wv * 8 + i;
      const int combo = fid >> 4, f = fid & 15;
      const short* src = combo ? WL : WH;
      const short* gp = src + (((size_t)((cg2 * 2 + (f >> 3)) * 8 + (f & 7))) * 64 + lane) * 8;
      stage16(gp, &wlds[combo][f][0][0]);
    }
  }
  asm volatile("s_waitcnt vmcnt(0)" ::: "memory");
  __syncthreads();
  f32x4 acc[2] = {};
  #pragma unroll
  for (int ks = 0; ks < 8; ++ks) {
    const bf16x8 ah = a_h[ks], al = a_l[ks];
    #pragma unroll
    for (int cfl = 0; cfl < 2; ++cfl) {
      const int f = cfl * 8 + ks;
      bf16x8 bh = *(const bf16x8*)&wlds[0][f][lane][0];
      bf16x8 bl = *(const bf16x8*)&wlds[1][f][lane][0];
      acc[cfl] = __builtin_amdgcn_mfma_f32_16x16x32_bf16(ah, bh, acc[cfl], 0, 0, 0);
      acc[cfl] = __builtin_amdgcn_mfma_f32_16x16x32_bf16(ah, bl, acc[cfl], 0, 0, 0);
      acc[cfl] = __builtin_amdgcn_mfma_f32_16x16x32_bf16(al, bh, acc[cfl], 0, 0, 0);
    }
  }
  const float* bc = ga.bc[cell];
  const float* uw = ga.u_ws[cell];
  const float* hsrc = ga.h[cell];
  float* hout = ga.hout[cell];
  short* hph = ga.hph[cell]; short* hpl = ga.hpl[cell];
  #pragma unroll
  for (int cfl = 0; cfl < 2; ++cfl) {
    const int col = cg2 * 32 + cfl * 16 + lr;
    #pragma unroll
    for (int q = 0; q < 4; ++q) {
      const int row = R0 + lg * 4 + q;
      const float cv = tanhf_(acc[cfl][q] + bc[row & (N - 1)]);
      const float uv = uw[(size_t)row * HID + col];
      const float hv = hsrc[(size_t)row * HID + col];
      const float o = uv * hv + (1.f - uv) * cv;
      __builtin_nontemporal_store(o, &hout[(size_t)row * HID + col]);
      short hi, lo; split_bf16(o, hi, lo);
      hph[(size_t)row * HID + col] = hi;
      hpl[(size_t)row * HID + col] = lo;
    }
  }
}

// ------------- K5: g = h' @ R -------------
__global__ __launch_bounds__(256) void k_g(GArgs ga) {
  const int wv = threadIdx.x >> 6, lane = threadIdx.x & 63;
  const int bx = blockIdx.x, cg2 = blockIdx.y, cell = blockIdx.z;
  const int lr = lane & 15, lg = lane >> 4, kb = lg * 8;
  const int R0 = bx * 64 + wv * 16;
  __shared__ short wlds[2][8][64][8];
  bf16x8 a_h[4], a_l[4];
  {
    const size_t ab = (size_t)(R0 + lr) * HID + kb;
    const short* hph = ga.hph[cell]; const short* hpl = ga.hpl[cell];
    #pragma unroll
    for (int ks = 0; ks < 4; ++ks) {
      a_h[ks] = *(const bf16x8*)&hph[ab + ks * 32];
      a_l[ks] = *(const bf16x8*)&hpl[ab + ks * 32];
    }
  }
  {
    #pragma unroll
    for (int i = 0; i < 4; ++i) {
      const int fid = wv * 4 + i;
      const int combo = fid >> 3, f = fid & 7;
      const short* src = combo ? ga.RtL[cell] : ga.RtH[cell];
      const short* gp = src + (((size_t)((cg2 * 2 + (f >> 2)) * 4 + (f & 3))) * 64 + lane) * 8;
      stage16(gp, &wlds[combo][f][0][0]);
    }
  }
  asm volatile("s_waitcnt vmcnt(0)" ::: "memory");
  __syncthreads();
  f32x4 acc[2] = {};
  #pragma unroll
  for (int ks = 0; ks < 4; ++ks) {
    const bf16x8 ah = a_h[ks], al = a_l[ks];
    #pragma unroll
    for (int cfl = 0; cfl < 2; ++cfl) {
      const int f = cfl * 4 + ks;
      bf16x8 bh = *(const bf16x8*)&wlds[0][f][lane][0];
      bf16x8 bl = *(const bf16x8*)&wlds[1][f][lane][0];
      acc[cfl] = __builtin_amdgcn_mfma_f32_16x16x32_bf16(ah, bh, acc[cfl], 0, 0, 0);
      acc[cfl] = __builtin_amdgcn_mfma_f32_16x16x32_bf16(ah, bl, acc[cfl], 0, 0, 0);
      acc[cfl] = __builtin_amdgcn_mfma_f32_16x16x32_bf16(al, bh, acc[cfl], 0, 0, 0);
    }
  }
  short* gbo = ga.gb[cell];
  #pragma unroll
  for (int cfl = 0; cfl < 2; ++cfl) {
    const int col = cg2 * 32 + cfl * 16 + lr;
    #pragma unroll
    for (int q = 0; q < 4; ++q) {
      const int row = R0 + lg * 4 + q;
      short hi, lo; split_bf16(acc[cfl][q], hi, lo);
      gbo[(size_t)row * HID + col] = hi;
    }
  }
}

// ------------- K6: logits — 128x128 tiles, 512 thr, XCD-swizzled ---------------
// grid (N/128, N/128, B); wave = 32 rows x 64 cols; acc[3][2][4].
__global__ __launch_bounds__(512) void k_bilinear(
    const short* __restrict__ g0, const short* __restrict__ g1,
    const short* __restrict__ g2, const short* __restrict__ h0,
    const short* __restrict__ h1, const short* __restrict__ h2,
    float* __restrict__ out) {
  const int id  = blockIdx.y * 16 + blockIdx.x;      // 0..255
  const int id2 = (id & 7) * 32 + (id >> 3);         // bijective XCD swizzle
  const int ti = id2 & 15, tj = id2 >> 4;
  const int b = blockIdx.z;
  const int t = threadIdx.x;
  const int w = t >> 6, l = t & 63;
  const int wi = w >> 1, wj = w & 1;                 // 4 row-groups x 2 col-halves
  const int i_base = ti * 128 + wi * 32;
  const int j_base = tj * 128 + wj * 64;
  const short* gbs[3] = {g0, g1, g2};
  const short* hbs[3] = {h0, h1, h2};
  const int lr = l & 15;
  const int kb = (l >> 4) * 8;
  f32x4 acc[3][2][4] = {};
  for (int k0 = 0; k0 < HID; k0 += 32) {
    #pragma unroll
    for (int d = 0; d < 3; ++d) {
      bf16x8 af0 = *(const bf16x8*)&gbs[d][(size_t)(b * N + i_base + lr) * HID + k0 + kb];
      bf16x8 af1 = *(const bf16x8*)&gbs[d][(size_t)(b * N + i_base + 16 + lr) * HID + k0 + kb];
      #pragma unroll
      for (int mj = 0; mj < 4; ++mj) {
        bf16x8 bf = *(const bf16x8*)&hbs[d][(size_t)(b * N + j_base + mj * 16 + lr) * HID + k0 + kb];
        acc[d][0][mj] = __builtin_amdgcn_mfma_f32_16x16x32_bf16(af0, bf, acc[d][0][mj], 0, 0, 0);
        acc[d][1][mj] = __builtin_amdgcn_mfma_f32_16x16x32_bf16(af1, bf, acc[d][1][mj], 0, 0, 0);
      }
    }
  }
  const int orow = (l >> 4) * 4;
  const int col  = l & 15;
  #pragma unroll
  for (int mi = 0; mi < 2; ++mi)
    #pragma unroll
    for (int mj = 0; mj < 4; ++mj)
      #pragma unroll
      for (int r = 0; r < 4; ++r) {
        const int row = i_base + mi * 16 + orow + r;
        const int cc  = j_base + mj * 16 + col;
        float* p = &out[(((size_t)(b * N + row)) * N + cc) * 3];
        f32x3 v;
        v[0] = acc[0][mi][mj][r];
        v[1] = acc[1][mi][mj][r];
        v[2] = acc[2][mi][mj][r];
        *(f32x3*)p = v;
      }
}

extern "C" void kernel_launch(void* const* d_in, const int* in_sizes, int n_in,
                              void* d_out, int out_size, void* d_ws, size_t ws_size,
                              hipStream_t stream) {
  (void)in_sizes; (void)n_in; (void)out_size; (void)ws_size;
  const float* a    = (const float*)d_in[1];
  const float* bias = (const float*)d_in[8];

  float* ws      = (float*)d_ws;
  float* hfeat   = ws;
  float* sself   = hfeat + (size_t)BN * HID;
  float* sneigh  = sself + (size_t)BN * H;
  float* u_ws0   = sneigh + (size_t)BN * H;
  short* sp      = (short*)(u_ws0 + 3 * (size_t)BN * HID);
  auto alloc_s = [&](size_t n) { short* p = sp; sp += n; return p; };

  short* conv_hi = alloc_s((size_t)BN * HID);
  short* conv_lo = alloc_s((size_t)BN * HID);
  short* h_hi[3]; short* h_lo[3];
  for (int c = 0; c < 3; ++c) { h_hi[c] = alloc_s((size_t)BN * HID); h_lo[c] = alloc_s((size_t)BN * HID); }
  short* rh_hi[3]; short* rh_lo[3];
  for (int c = 0; c < 3; ++c) { rh_hi[c] = alloc_s((size_t)BN * HID); rh_lo[c] = alloc_s((size_t)BN * HID); }
  short* hp_hi[3]; short* hp_lo[3];
  for (int c = 0; c < 3; ++c) { hp_hi[c] = alloc_s((size_t)BN * HID); hp_lo[c] = alloc_s((size_t)BN * HID); }
  short* gbb[3];
  for (int c = 0; c < 3; ++c) gbb[c] = alloc_s((size_t)BN * HID);

  float* out = (float*)d_out;

  PreArgs pa;
  pa.x = (const float*)d_in[0];
  pa.gk = (const float*)d_in[5];
  pa.asel = (const float*)d_in[6];
  pa.anei = (const float*)d_in[7];
  pa.hfeat = hfeat; pa.sself = sself; pa.sneigh = sneigh;

  GArgs ga;
  ga.chi = conv_hi; ga.clo = conv_lo;
  ga.h[0] = (const float*)d_in[2];
  ga.h[1] = (const float*)d_in[3];
  ga.h[2] = (const float*)d_in[4];
  for (int c = 0; c < 3; ++c) {
    pa.h[c] = ga.h[c];
    pa.hh[c] = h_hi[c]; pa.hl[c] = h_lo[c];
    const int base = 9 + c * 6;
    ga.hhi[c] = h_hi[c]; ga.hlo[c] = h_lo[c];
    ga.bu[c] = (const float*)d_in[base + 1];
    ga.br[c] = (const float*)d_in[base + 3];
    ga.bc[c] = (const float*)d_in[base + 5];
    short* wu_h = alloc_s(256 * 128); short* wu_l = alloc_s(256 * 128);
    short* wr_h = alloc_s(256 * 128); short* wr_l = alloc_s(256 * 128);
    short* wc_h = alloc_s(256 * 128); short* wc_l = alloc_s(256 * 128);
    short* rt_h = alloc_s(128 * 128); short* rt_l = alloc_s(128 * 128);
    const int pb = c * 4;
    pa.src[pb + 0] = (const float*)d_in[base + 0]; pa.whi[pb + 0] = wu_h; pa.wlo[pb + 0] = wu_l; pa.nks[pb + 0] = 8;
    pa.src[pb + 1] = (const float*)d_in[base + 2]; pa.whi[pb + 1] = wr_h; pa.wlo[pb + 1] = wr_l; pa.nks[pb + 1] = 8;
    pa.src[pb + 2] = (const float*)d_in[base + 4]; pa.whi[pb + 2] = wc_h; pa.wlo[pb + 2] = wc_l; pa.nks[pb + 2] = 8;
    pa.src[pb + 3] = (const float*)d_in[27 + c];   pa.whi[pb + 3] = rt_h; pa.wlo[pb + 3] = rt_l; pa.nks[pb + 3] = 4;
    ga.WuH[c] = wu_h; ga.WuL[c] = wu_l;
    ga.WrH[c] = wr_h; ga.WrL[c] = wr_l;
    ga.WcH[c] = wc_h; ga.WcL[c] = wc_l;
    ga.RtH[c] = rt_h; ga.RtL[c] = rt_l;
    ga.u_ws[c] = u_ws0 + (size_t)c * BN * HID;
    ga.rhh[c] = rh_hi[c]; ga.rhl[c] = rh_lo[c];
    ga.hph[c] = hp_hi[c]; ga.hpl[c] = hp_lo[c];
    ga.hout[c] = out + LOG_SZ + (size_t)c * BN * HID;
    ga.gb[c] = gbb[c];
  }

  k_pre<<<BN / 2 + 96, 256, 0, stream>>>(pa);
  k_attn<<<BN / 4, 256, 0, stream>>>(a, hfeat, sself, sneigh, bias, conv_hi, conv_lo);
  k_ur<<<dim3(BN / 64, 4, 3), 256, 0, stream>>>(ga);
  k_c<<<dim3(BN / 64, 4, 3), 256, 0, stream>>>(ga);
  k_g<<<dim3(BN / 64, 4, 3), 256, 0, stream>>>(ga);
  dim3 g2(N / 128, N / 128, B);
  k_bilinear<<<g2, 512, 0, stream>>>(gbb[0], gbb[1], gbb[2],
                                     hp_hi[0], hp_hi[1], hp_hi[2], out);
}

// Round 17
// 108.148 us; speedup vs baseline: 1.1442x; 1.0004x over previous
//
#include <hip/hip_runtime.h>
#include <hip/hip_bf16.h>

typedef __attribute__((ext_vector_type(4))) float f32x4;
typedef __attribute__((ext_vector_type(3))) float f32x3;
typedef __attribute__((ext_vector_type(8))) short bf16x8;

static constexpr int B   = 2;
static constexpr int N   = 2048;
static constexpr int F   = 64;
static constexpr int H   = 4;
static constexpr int HID = 128;
static constexpr int BN  = B * N;
static constexpr size_t LOG_SZ = (size_t)B * N * N * 3;

__device__ __forceinline__ float sigmoidf_(float x) { return 1.0f / (1.0f + __expf(-x)); }
__device__ __forceinline__ float tanhf_(float x) {
  float e = __expf(2.0f * x);
  return 1.0f - 2.0f / (e + 1.0f);      // inf-safe
}
// RNE bf16 split: v = hi + lo with ~2^-17 relative error
__device__ __forceinline__ void split_bf16(float v, short& hi, short& lo) {
  unsigned u = __float_as_uint(v);
  unsigned hr = (u + 0x7FFFu + ((u >> 16) & 1u)) >> 16;
  hi = (short)hr;
  float hv = __uint_as_float(hr << 16);
  float res = v - hv;
  unsigned u2 = __float_as_uint(res);
  lo = (short)((u2 + 0x7FFFu + ((u2 >> 16) & 1u)) >> 16);
}
__device__ __forceinline__ void stage16(const short* gp, short* lp) {
  __builtin_amdgcn_global_load_lds(
      (const __attribute__((address_space(1))) void*)gp,
      (__attribute__((address_space(3))) void*)lp, 16, 0, 0);
}

// ------------- K1: merged prep (coalesced weight transpose) + feat + h-split ---
struct PreArgs {
  const float* x; const float* gk; const float* asel; const float* anei;
  float* hfeat; float* sself; float* sneigh;
  const float* h[3];
  short* hh[3]; short* hl[3];
  const float* src[12];
  short* whi[12]; short* wlo[12];
};
__global__ __launch_bounds__(256) void k_pre(PreArgs pa) {
  const int bid = blockIdx.x;
  __shared__ float tl[32][132];
  if (bid < BN / 2) {
    const int t = threadIdx.x;
    const int r = t >> 7, tt = t & 127;
    const int bn = bid * 2 + r;
    float* xs = &tl[r][0];              // reuse LDS: 64 floats per sub-row
    if (tt < F) xs[tt] = pa.x[(size_t)bn * F + tt];
    const size_t o = (size_t)bn * HID + tt;
    { short hi, lo; split_bf16(pa.h[0][o], hi, lo); pa.hh[0][o] = hi; pa.hl[0][o] = lo; }
    { short hi, lo; split_bf16(pa.h[1][o], hi, lo); pa.hh[1][o] = hi; pa.hl[1][o] = lo; }
    { short hi, lo; split_bf16(pa.h[2][o], hi, lo); pa.hh[2][o] = hi; pa.hl[2][o] = lo; }
    __syncthreads();
    float acc = 0.f;
    #pragma unroll 8
    for (int f = 0; f < F; ++f) acc += xs[f] * pa.gk[f * HID + tt];
    pa.hfeat[o] = acc;
    float ps = acc * pa.asel[tt];
    float pn = acc * pa.anei[tt];
    #pragma unroll
    for (int d = 16; d >= 1; d >>= 1) {
      ps += __shfl_xor(ps, d, 32);
      pn += __shfl_xor(pn, d, 32);
    }
    if ((tt & 31) == 0) {
      pa.sself [bn * H + (tt >> 5)] = ps;
      pa.sneigh[bn * H + (tt >> 5)] = pn;
    }
  } else {
    // coalesced weight prep: one block per (matrix, ks) = 32 k-rows x 128 cols
    const int pb = bid - BN / 2;         // 0..83
    int m, ks, nksv;
    if (pb < 72) { const int m9 = pb >> 3; m = (m9 / 3) * 4 + (m9 % 3); ks = pb & 7; nksv = 8; }
    else         { const int r2 = pb - 72; m = (r2 >> 2) * 4 + 3; ks = r2 & 3; nksv = 4; }
    const int t = threadIdx.x;
    const float* src = pa.src[m] + (size_t)(ks * 32) * HID;
    #pragma unroll
    for (int i = 0; i < 4; ++i) {
      const int f4 = t + i * 256;        // 0..1023 f32x4 units
      const int r2 = f4 >> 5, c = (f4 & 31) * 4;
      f32x4 v = *(const f32x4*)&src[(size_t)r2 * HID + c];
      tl[r2][c] = v[0]; tl[r2][c + 1] = v[1]; tl[r2][c + 2] = v[2]; tl[r2][c + 3] = v[3];
    }
    __syncthreads();
    short* ph = pa.whi[m];
    short* pl = pa.wlo[m];
    const int lane_out = t & 63, cgp = t >> 6;     // cgp 0..3
    const int colb = lane_out & 15, kg = lane_out >> 4;
    #pragma unroll
    for (int cc = 0; cc < 2; ++cc) {
      const int cf = cgp * 2 + cc;
      const int col = cf * 16 + colb;
      bf16x8 vh, vl;
      #pragma unroll
      for (int e = 0; e < 8; ++e) {
        short hi, lo; split_bf16(tl[kg * 8 + e][col], hi, lo);
        vh[e] = hi; vl[e] = lo;
      }
      const size_t o = (((size_t)cf * nksv + ks) * 64 + lane_out) * 8;
      *(bf16x8*)&ph[o] = vh;
      *(bf16x8*)&pl[o] = vl;
    }
  }
}

// ------------- K2: sparse GAT attention — one wave per row -------------
__global__ __launch_bounds__(256) void k_attn(
    const float* __restrict__ a, const float* __restrict__ hfeat,
    const float* __restrict__ sself, const float* __restrict__ sneigh,
    const float* __restrict__ bias,
    short* __restrict__ conv_hi, short* __restrict__ conv_lo) {
  const int wv   = threadIdx.x >> 6;
  const int lane = threadIdx.x & 63;
  const int bi   = blockIdx.x * 4 + wv;
  const int bbase = bi & ~(N - 1);
  __shared__ int   nbr[4][256];
  __shared__ float wts[4][256][4];
  int*   nb       = nbr[wv];
  float (*wt)[4]  = wts[wv];
  const float si0 = sself[bi * H + 0];
  const float si1 = sself[bi * H + 1];
  const float si2 = sself[bi * H + 2];
  const float si3 = sself[bi * H + 3];
  float den0 = 0.f, den1 = 0.f, den2 = 0.f, den3 = 0.f;
  float acc0 = 0.f, acc1 = 0.f;
  const unsigned long long lmlt = ((unsigned long long)1 << lane) - 1ull;
  const float* arow = a + (size_t)bi * N;
  const float* hb   = hfeat + (size_t)bbase * HID;
  const float* snb  = sneigh + (size_t)bbase * H;
  const int h0 = lane >> 5;
  int num = 0;
  auto flush = [&]() {
    asm volatile("s_waitcnt lgkmcnt(0)" ::: "memory");
    for (int n = lane; n < num; n += 64) {
      const int j = nb[n];
      f32x4 sn = *(const f32x4*)&snb[(size_t)j * H];
      float s0 = si0 + sn[0]; s0 = (s0 > 0.f) ? s0 : 0.2f * s0;
      float s1 = si1 + sn[1]; s1 = (s1 > 0.f) ? s1 : 0.2f * s1;
      float s2 = si2 + sn[2]; s2 = (s2 > 0.f) ? s2 : 0.2f * s2;
      float s3 = si3 + sn[3]; s3 = (s3 > 0.f) ? s3 : 0.2f * s3;
      float w0 = __expf(s0), w1 = __expf(s1), w2 = __expf(s2), w3 = __expf(s3);
      wt[n][0] = w0; wt[n][1] = w1; wt[n][2] = w2; wt[n][3] = w3;
      den0 += w0; den1 += w1; den2 += w2; den3 += w3;
    }
    asm volatile("s_waitcnt lgkmcnt(0)" ::: "memory");
    #pragma unroll 4
    for (int n = 0; n < num; ++n) {
      const int j  = nb[n];
      const float wA = wt[n][h0];
      const float wB = wt[n][h0 + 2];
      const float* hr = hb + (size_t)j * HID;
      acc0 += wA * hr[lane];
      acc1 += wB * hr[lane + 64];
    }
    asm volatile("s_waitcnt lgkmcnt(0)" ::: "memory");
    num = 0;
  };
  for (int jb = 0; jb < N; jb += 256) {
    f32x4 av = *(const f32x4*)&arow[jb + lane * 4];
    #pragma unroll
    for (int e = 0; e < 4; ++e) {
      const unsigned long long m = __ballot(av[e] > 0.5f);
      if (av[e] > 0.5f) {
        const int pos = num + __popcll(m & lmlt);
        nb[pos] = jb + lane * 4 + e;
      }
      num += __popcll(m);
      if (num > 192) flush();
    }
  }
  if (num > 0) flush();
  #pragma unroll
  for (int d = 32; d >= 1; d >>= 1) {
    den0 += __shfl_xor(den0, d, 64);
    den1 += __shfl_xor(den1, d, 64);
    den2 += __shfl_xor(den2, d, 64);
    den3 += __shfl_xor(den3, d, 64);
  }
  const float dA = h0 ? den1 : den0;
  const float dB = h0 ? den3 : den2;
  const float v0 = acc0 / dA + bias[lane];
  const float v1 = acc1 / dB + bias[64 + lane];
  { short hi, lo; split_bf16(v0, hi, lo);
    conv_hi[(size_t)bi * HID + lane] = hi; conv_lo[(size_t)bi * HID + lane] = lo; }
  { short hi, lo; split_bf16(v1, hi, lo);
    conv_hi[(size_t)bi * HID + 64 + lane] = hi; conv_lo[(size_t)bi * HID + 64 + lane] = lo; }
}

// ------------- shared arg pack -------------
struct GArgs {
  const short* chi; const short* clo;
  const float* h[3];
  const short* hhi[3]; const short* hlo[3];
  const float* bu[3]; const float* br[3]; const float* bc[3];
  const short* WuH[3]; const short* WuL[3];
  const short* WrH[3]; const short* WrL[3];
  const short* WcH[3]; const short* WcL[3];
  const short* RtH[3]; const short* RtL[3];
  float* u_ws[3];
  short* rhh[3]; short* rhl[3];
  short* hph[3]; short* hpl[3];
  float* hout[3]; short* gb[3];
};

// ------------- K3: u+r gates combined -------------
__global__ __launch_bounds__(256) void k_ur(GArgs ga) {
  const int wv = threadIdx.x >> 6, lane = threadIdx.x & 63;
  const int bx = blockIdx.x, cg2 = blockIdx.y, cell = blockIdx.z;
  const int lr = lane & 15, lg = lane >> 4, kb = lg * 8;
  const int R0 = bx * 64 + wv * 16;
  __shared__ short wlds[4][16][64][8];
  bf16x8 a_h[8], a_l[8];
  {
    const size_t ab = (size_t)(R0 + lr) * HID + kb;
    const short* hhi = ga.hhi[cell]; const short* hlo = ga.hlo[cell];
    #pragma unroll
    for (int ks = 0; ks < 4; ++ks) {
      a_h[ks]     = *(const bf16x8*)&ga.chi[ab + ks * 32];
      a_l[ks]     = *(const bf16x8*)&ga.clo[ab + ks * 32];
      a_h[4 + ks] = *(const bf16x8*)&hhi[ab + ks * 32];
      a_l[4 + ks] = *(const bf16x8*)&hlo[ab + ks * 32];
    }
  }
  {
    const short* srcs[4] = { ga.WuH[cell], ga.WuL[cell], ga.WrH[cell], ga.WrL[cell] };
    const short* sp = srcs[wv];
    #pragma unroll
    for (int f = 0; f < 16; ++f) {
      const short* gp = sp + (((size_t)((cg2 * 2 + (f >> 3)) * 8 + (f & 7))) * 64 + lane) * 8;
      stage16(gp, &wlds[wv][f][0][0]);
    }
  }
  asm volatile("s_waitcnt vmcnt(0)" ::: "memory");
  __syncthreads();
  f32x4 au[2] = {}, ar[2] = {};
  #pragma unroll
  for (int ks = 0; ks < 8; ++ks) {
    const bf16x8 ah = a_h[ks], al = a_l[ks];
    #pragma unroll
    for (int cfl = 0; cfl < 2; ++cfl) {
      const int f = cfl * 8 + ks;
      bf16x8 buh = *(const bf16x8*)&wlds[0][f][lane][0];
      bf16x8 bul = *(const bf16x8*)&wlds[1][f][lane][0];
      bf16x8 brh = *(const bf16x8*)&wlds[2][f][lane][0];
      bf16x8 brl = *(const bf16x8*)&wlds[3][f][lane][0];
      au[cfl] = __builtin_amdgcn_mfma_f32_16x16x32_bf16(ah, buh, au[cfl], 0, 0, 0);
      au[cfl] = __builtin_amdgcn_mfma_f32_16x16x32_bf16(ah, bul, au[cfl], 0, 0, 0);
      au[cfl] = __builtin_amdgcn_mfma_f32_16x16x32_bf16(al, buh, au[cfl], 0, 0, 0);
      ar[cfl] = __builtin_amdgcn_mfma_f32_16x16x32_bf16(ah, brh, ar[cfl], 0, 0, 0);
      ar[cfl] = __builtin_amdgcn_mfma_f32_16x16x32_bf16(ah, brl, ar[cfl], 0, 0, 0);
      ar[cfl] = __builtin_amdgcn_mfma_f32_16x16x32_bf16(al, brh, ar[cfl], 0, 0, 0);
    }
  }
  const float* bu = ga.bu[cell];
  const float* br = ga.br[cell];
  const float* hsrc = ga.h[cell];
  float* uws = ga.u_ws[cell];
  short* rhh = ga.rhh[cell]; short* rhl = ga.rhl[cell];
  #pragma unroll
  for (int cfl = 0; cfl < 2; ++cfl) {
    const int col = cg2 * 32 + cfl * 16 + lr;
    #pragma unroll
    for (int q = 0; q < 4; ++q) {
      const int row = R0 + lg * 4 + q;
      const int n = row & (N - 1);
      uws[(size_t)row * HID + col] = sigmoidf_(au[cfl][q] + bu[n]);
      const float rv = sigmoidf_(ar[cfl][q] + br[n]);
      const float rhv = rv * hsrc[(size_t)row * HID + col];
      short hi, lo; split_bf16(rhv, hi, lo);
      rhh[(size_t)row * HID + col] = hi;
      rhl[(size_t)row * HID + col] = lo;
    }
  }
}

// ------------- K4: c gate + h' -------------
__global__ __launch_bounds__(256) void k_c(GArgs ga) {
  const int wv = threadIdx.x >> 6, lane = threadIdx.x & 63;
  const int bx = blockIdx.x, cg2 = blockIdx.y, cell = blockIdx.z;
  const int lr = lane & 15, lg = lane >> 4, kb = lg * 8;
  const int R0 = bx * 64 + wv * 16;
  __shared__ short wlds[2][16][64][8];
  bf16x8 a_h[8], a_l[8];
  {
    const size_t ab = (size_t)(R0 + lr) * HID + kb;
    const short* rhh = ga.rhh[cell]; const short* rhl = ga.rhl[cell];
    #pragma unroll
    for (int ks = 0; ks < 4; ++ks) {
      a_h[ks]     = *(const bf16x8*)&ga.chi[ab + ks * 32];
      a_l[ks]     = *(const bf16x8*)&ga.clo[ab + ks * 32];
      a_h[4 + ks] = *(const bf16x8*)&rhh[ab + ks * 32];
      a_l[4 + ks] = *(const bf16x8*)&rhl[ab + ks * 32];
    }
  }
  {
    const short* WH = ga.WcH[cell];
    const short* WL = ga.WcL[cell];
    #pragma unroll
    for (int i = 0; i < 8; ++i) {
      const int fid = wv * 8 + i;
      const int combo = fid >> 4, f = fid & 15;
      const short* src = combo ? WL : WH;
      const short* gp = src + (((size_t)((cg2 * 2 + (f >> 3)) * 8 + (f & 7))) * 64 + lane) * 8;
      stage16(gp, &wlds[combo][f][0][0]);
    }
  }
  asm volatile("s_waitcnt vmcnt(0)" ::: "memory");
  __syncthreads();
  f32x4 acc[2] = {};
  #pragma unroll
  for (int ks = 0; ks < 8; ++ks) {
    const bf16x8 ah = a_h[ks], al = a_l[ks];
    #pragma unroll
    for (int cfl = 0; cfl < 2; ++cfl) {
      const int f = cfl * 8 + ks;
      bf16x8 bh = *(const bf16x8*)&wlds[0][f][lane][0];
      bf16x8 bl = *(const bf16x8*)&wlds[1][f][lane][0];
      acc[cfl] = __builtin_amdgcn_mfma_f32_16x16x32_bf16(ah, bh, acc[cfl], 0, 0, 0);
      acc[cfl] = __builtin_amdgcn_mfma_f32_16x16x32_bf16(ah, bl, acc[cfl], 0, 0, 0);
      acc[cfl] = __builtin_amdgcn_mfma_f32_16x16x32_bf16(al, bh, acc[cfl], 0, 0, 0);
    }
  }
  const float* bc = ga.bc[cell];
  const float* uw = ga.u_ws[cell];
  const float* hsrc = ga.h[cell];
  float* hout = ga.hout[cell];
  short* hph = ga.hph[cell]; short* hpl = ga.hpl[cell];
  #pragma unroll
  for (int cfl = 0; cfl < 2; ++cfl) {
    const int col = cg2 * 32 + cfl * 16 + lr;
    #pragma unroll
    for (int q = 0; q < 4; ++q) {
      const int row = R0 + lg * 4 + q;
      const float cv = tanhf_(acc[cfl][q] + bc[row & (N - 1)]);
      const float uv = uw[(size_t)row * HID + col];
      const float hv = hsrc[(size_t)row * HID + col];
      const float o = uv * hv + (1.f - uv) * cv;
      __builtin_nontemporal_store(o, &hout[(size_t)row * HID + col]);
      short hi, lo; split_bf16(o, hi, lo);
      hph[(size_t)row * HID + col] = hi;
      hpl[(size_t)row * HID + col] = lo;
    }
  }
}

// ------------- K5: g = h' @ R -------------
__global__ __launch_bounds__(256) void k_g(GArgs ga) {
  const int wv = threadIdx.x >> 6, lane = threadIdx.x & 63;
  const int bx = blockIdx.x, cg2 = blockIdx.y, cell = blockIdx.z;
  const int lr = lane & 15, lg = lane >> 4, kb = lg * 8;
  const int R0 = bx * 64 + wv * 16;
  __shared__ short wlds[2][8][64][8];
  bf16x8 a_h[4], a_l[4];
  {
    const size_t ab = (size_t)(R0 + lr) * HID + kb;
    const short* hph = ga.hph[cell]; const short* hpl = ga.hpl[cell];
    #pragma unroll
    for (int ks = 0; ks < 4; ++ks) {
      a_h[ks] = *(const bf16x8*)&hph[ab + ks * 32];
      a_l[ks] = *(const bf16x8*)&hpl[ab + ks * 32];
    }
  }
  {
    #pragma unroll
    for (int i = 0; i < 4; ++i) {
      const int fid = wv * 4 + i;
      const int combo = fid >> 3, f = fid & 7;
      const short* src = combo ? ga.RtL[cell] : ga.RtH[cell];
      const short* gp = src + (((size_t)((cg2 * 2 + (f >> 2)) * 4 + (f & 3))) * 64 + lane) * 8;
      stage16(gp, &wlds[combo][f][0][0]);
    }
  }
  asm volatile("s_waitcnt vmcnt(0)" ::: "memory");
  __syncthreads();
  f32x4 acc[2] = {};
  #pragma unroll
  for (int ks = 0; ks < 4; ++ks) {
    const bf16x8 ah = a_h[ks], al = a_l[ks];
    #pragma unroll
    for (int cfl = 0; cfl < 2; ++cfl) {
      const int f = cfl * 4 + ks;
      bf16x8 bh = *(const bf16x8*)&wlds[0][f][lane][0];
      bf16x8 bl = *(const bf16x8*)&wlds[1][f][lane][0];
      acc[cfl] = __builtin_amdgcn_mfma_f32_16x16x32_bf16(ah, bh, acc[cfl], 0, 0, 0);
      acc[cfl] = __builtin_amdgcn_mfma_f32_16x16x32_bf16(ah, bl, acc[cfl], 0, 0, 0);
      acc[cfl] = __builtin_amdgcn_mfma_f32_16x16x32_bf16(al, bh, acc[cfl], 0, 0, 0);
    }
  }
  short* gbo = ga.gb[cell];
  #pragma unroll
  for (int cfl = 0; cfl < 2; ++cfl) {
    const int col = cg2 * 32 + cfl * 16 + lr;
    #pragma unroll
    for (int q = 0; q < 4; ++q) {
      const int row = R0 + lg * 4 + q;
      short hi, lo; split_bf16(acc[cfl][q], hi, lo);
      gbo[(size_t)row * HID + col] = hi;
    }
  }
}

// ------------- K6: logits — 128x128 tiles, 512 thr, XCD-swizzled ---------------
__global__ __launch_bounds__(512) void k_bilinear(
    const short* __restrict__ g0, const short* __restrict__ g1,
    const short* __restrict__ g2, const short* __restrict__ h0,
    const short* __restrict__ h1, const short* __restrict__ h2,
    float* __restrict__ out) {
  const int id  = blockIdx.y * 16 + blockIdx.x;      // 0..255
  const int id2 = (id & 7) * 32 + (id >> 3);         // bijective XCD swizzle
  const int ti = id2 & 15, tj = id2 >> 4;
  const int b = blockIdx.z;
  const int t = threadIdx.x;
  const int w = t >> 6, l = t & 63;
  const int wi = w >> 1, wj = w & 1;
  const int i_base = ti * 128 + wi * 32;
  const int j_base = tj * 128 + wj * 64;
  const short* gbs[3] = {g0, g1, g2};
  const short* hbs[3] = {h0, h1, h2};
  const int lr = l & 15;
  const int kb = (l >> 4) * 8;
  f32x4 acc[3][2][4] = {};
  for (int k0 = 0; k0 < HID; k0 += 32) {
    #pragma unroll
    for (int d = 0; d < 3; ++d) {
      bf16x8 af0 = *(const bf16x8*)&gbs[d][(size_t)(b * N + i_base + lr) * HID + k0 + kb];
      bf16x8 af1 = *(const bf16x8*)&gbs[d][(size_t)(b * N + i_base + 16 + lr) * HID + k0 + kb];
      #pragma unroll
      for (int mj = 0; mj < 4; ++mj) {
        bf16x8 bf = *(const bf16x8*)&hbs[d][(size_t)(b * N + j_base + mj * 16 + lr) * HID + k0 + kb];
        acc[d][0][mj] = __builtin_amdgcn_mfma_f32_16x16x32_bf16(af0, bf, acc[d][0][mj], 0, 0, 0);
        acc[d][1][mj] = __builtin_amdgcn_mfma_f32_16x16x32_bf16(af1, bf, acc[d][1][mj], 0, 0, 0);
      }
    }
  }
  const int orow = (l >> 4) * 4;
  const int col  = l & 15;
  #pragma unroll
  for (int mi = 0; mi < 2; ++mi)
    #pragma unroll
    for (int mj = 0; mj < 4; ++mj)
      #pragma unroll
      for (int r = 0; r < 4; ++r) {
        const int row = i_base + mi * 16 + orow + r;
        const int cc  = j_base + mj * 16 + col;
        float* p = &out[(((size_t)(b * N + row)) * N + cc) * 3];
        f32x3 v;
        v[0] = acc[0][mi][mj][r];
        v[1] = acc[1][mi][mj][r];
        v[2] = acc[2][mi][mj][r];
        *(f32x3*)p = v;
      }
}

extern "C" void kernel_launch(void* const* d_in, const int* in_sizes, int n_in,
                              void* d_out, int out_size, void* d_ws, size_t ws_size,
                              hipStream_t stream) {
  (void)in_sizes; (void)n_in; (void)out_size; (void)ws_size;
  const float* a    = (const float*)d_in[1];
  const float* bias = (const float*)d_in[8];

  float* ws      = (float*)d_ws;
  float* hfeat   = ws;
  float* sself   = hfeat + (size_t)BN * HID;
  float* sneigh  = sself + (size_t)BN * H;
  float* u_ws0   = sneigh + (size_t)BN * H;
  short* sp      = (short*)(u_ws0 + 3 * (size_t)BN * HID);
  auto alloc_s = [&](size_t n) { short* p = sp; sp += n; return p; };

  short* conv_hi = alloc_s((size_t)BN * HID);
  short* conv_lo = alloc_s((size_t)BN * HID);
  short* h_hi[3]; short* h_lo[3];
  for (int c = 0; c < 3; ++c) { h_hi[c] = alloc_s((size_t)BN * HID); h_lo[c] = alloc_s((size_t)BN * HID); }
  short* rh_hi[3]; short* rh_lo[3];
  for (int c = 0; c < 3; ++c) { rh_hi[c] = alloc_s((size_t)BN * HID); rh_lo[c] = alloc_s((size_t)BN * HID); }
  short* hp_hi[3]; short* hp_lo[3];
  for (int c = 0; c < 3; ++c) { hp_hi[c] = alloc_s((size_t)BN * HID); hp_lo[c] = alloc_s((size_t)BN * HID); }
  short* gbb[3];
  for (int c = 0; c < 3; ++c) gbb[c] = alloc_s((size_t)BN * HID);

  float* out = (float*)d_out;

  PreArgs pa;
  pa.x = (const float*)d_in[0];
  pa.gk = (const float*)d_in[5];
  pa.asel = (const float*)d_in[6];
  pa.anei = (const float*)d_in[7];
  pa.hfeat = hfeat; pa.sself = sself; pa.sneigh = sneigh;

  GArgs ga;
  ga.chi = conv_hi; ga.clo = conv_lo;
  ga.h[0] = (const float*)d_in[2];
  ga.h[1] = (const float*)d_in[3];
  ga.h[2] = (const float*)d_in[4];
  for (int c = 0; c < 3; ++c) {
    pa.h[c] = ga.h[c];
    pa.hh[c] = h_hi[c]; pa.hl[c] = h_lo[c];
    const int base = 9 + c * 6;
    ga.hhi[c] = h_hi[c]; ga.hlo[c] = h_lo[c];
    ga.bu[c] = (const float*)d_in[base + 1];
    ga.br[c] = (const float*)d_in[base + 3];
    ga.bc[c] = (const float*)d_in[base + 5];
    short* wu_h = alloc_s(256 * 128); short* wu_l = alloc_s(256 * 128);
    short* wr_h = alloc_s(256 * 128); short* wr_l = alloc_s(256 * 128);
    short* wc_h = alloc_s(256 * 128); short* wc_l = alloc_s(256 * 128);
    short* rt_h = alloc_s(128 * 128); short* rt_l = alloc_s(128 * 128);
    const int pb = c * 4;
    pa.src[pb + 0] = (const float*)d_in[base + 0]; pa.whi[pb + 0] = wu_h; pa.wlo[pb + 0] = wu_l;
    pa.src[pb + 1] = (const float*)d_in[base + 2]; pa.whi[pb + 1] = wr_h; pa.wlo[pb + 1] = wr_l;
    pa.src[pb + 2] = (const float*)d_in[base + 4]; pa.whi[pb + 2] = wc_h; pa.wlo[pb + 2] = wc_l;
    pa.src[pb + 3] = (const float*)d_in[27 + c];   pa.whi[pb + 3] = rt_h; pa.wlo[pb + 3] = rt_l;
    ga.WuH[c] = wu_h; ga.WuL[c] = wu_l;
    ga.WrH[c] = wr_h; ga.WrL[c] = wr_l;
    ga.WcH[c] = wc_h; ga.WcL[c] = wc_l;
    ga.RtH[c] = rt_h; ga.RtL[c] = rt_l;
    ga.u_ws[c] = u_ws0 + (size_t)c * BN * HID;
    ga.rhh[c] = rh_hi[c]; ga.rhl[c] = rh_lo[c];
    ga.hph[c] = hp_hi[c]; ga.hpl[c] = hp_lo[c];
    ga.hout[c] = out + LOG_SZ + (size_t)c * BN * HID;
    ga.gb[c] = gbb[c];
  }

  k_pre<<<BN / 2 + 84, 256, 0, stream>>>(pa);
  k_attn<<<BN / 4, 256, 0, stream>>>(a, hfeat, sself, sneigh, bias, conv_hi, conv_lo);
  k_ur<<<dim3(BN / 64, 4, 3), 256, 0, stream>>>(ga);
  k_c<<<dim3(BN / 64, 4, 3), 256, 0, stream>>>(ga);
  k_g<<<dim3(BN / 64, 4, 3), 256, 0, stream>>>(ga);
  dim3 g2(N / 128, N / 128, B);
  k_bilinear<<<g2, 512, 0, stream>>>(gbb[0], gbb[1], gbb[2],
                                     hp_hi[0], hp_hi[1], hp_hi[2], out);
}

// Round 18
// 108.065 us; speedup vs baseline: 1.1451x; 1.0008x over previous
//
#include <hip/hip_runtime.h>
#include <hip/hip_bf16.h>
#include <hip/hip_cooperative_groups.h>

namespace cg = cooperative_groups;

typedef __attribute__((ext_vector_type(4))) float f32x4;
typedef __attribute__((ext_vector_type(3))) float f32x3;
typedef __attribute__((ext_vector_type(8))) short bf16x8;

static constexpr int B   = 2;
static constexpr int N   = 2048;
static constexpr int F   = 64;
static constexpr int H   = 4;
static constexpr int HID = 128;
static constexpr int BN  = B * N;
static constexpr size_t LOG_SZ = (size_t)B * N * N * 3;

__device__ __forceinline__ float sigmoidf_(float x) { return 1.0f / (1.0f + __expf(-x)); }
__device__ __forceinline__ float tanhf_(float x) {
  float e = __expf(2.0f * x);
  return 1.0f - 2.0f / (e + 1.0f);
}
__device__ __forceinline__ void split_bf16(float v, short& hi, short& lo) {
  unsigned u = __float_as_uint(v);
  unsigned hr = (u + 0x7FFFu + ((u >> 16) & 1u)) >> 16;
  hi = (short)hr;
  float hv = __uint_as_float(hr << 16);
  float res = v - hv;
  unsigned u2 = __float_as_uint(res);
  lo = (short)((u2 + 0x7FFFu + ((u2 >> 16) & 1u)) >> 16);
}
__device__ __forceinline__ void stage16(const short* gp, short* lp) {
  __builtin_amdgcn_global_load_lds(
      (const __attribute__((address_space(1))) void*)gp,
      (__attribute__((address_space(3))) void*)lp, 16, 0, 0);
}

// =================== shared arg pack ===================
struct MA {
  const float* x; const float* gk; const float* asel; const float* anei;
  const float* a; const float* bias;
  float* hfeat; float* sself; float* sneigh;
  const float* h[3];
  short* hh[3]; short* hl[3];
  const float* wsrc[12];
  short* whi[12]; short* wlo[12];
  short* conv_hi; short* conv_lo;
  const float* bu[3]; const float* br[3]; const float* bc[3];
  const short* WuH[3]; const short* WuL[3];
  const short* WrH[3]; const short* WrL[3];
  const short* WcH[3]; const short* WcL[3];
  const short* RtH[3]; const short* RtL[3];
  float* u_ws[3];
  short* rhh[3]; short* rhl[3];
  short* hph[3]; short* hpl[3];
  float* hout[3];
  short* gb[3];
  float* out;
};

// =================== MEGA (single cooperative dispatch) ===================
__global__ __launch_bounds__(256) void k_mega2(MA A) {
  cg::grid_group grid = cg::this_grid();
  const int blk = blockIdx.x, G = gridDim.x;
  const int t = threadIdx.x;
  const int wv = t >> 6, lane = t & 63;
  __shared__ char smem[65536];

  // ---------- P0: feat + h-split + coalesced weight prep ----------
  {
    for (int vb = blk; vb < BN / 2 + 84; vb += G) {
      if (vb < BN / 2) {
        float (*xs)[F] = (float (*)[F])smem;
        const int r = t >> 7, tt = t & 127;
        const int bn = vb * 2 + r;
        if (tt < F) xs[r][tt] = A.x[(size_t)bn * F + tt];
        const size_t o = (size_t)bn * HID + tt;
        { short hi, lo; split_bf16(A.h[0][o], hi, lo); A.hh[0][o] = hi; A.hl[0][o] = lo; }
        { short hi, lo; split_bf16(A.h[1][o], hi, lo); A.hh[1][o] = hi; A.hl[1][o] = lo; }
        { short hi, lo; split_bf16(A.h[2][o], hi, lo); A.hh[2][o] = hi; A.hl[2][o] = lo; }
        __syncthreads();
        float acc = 0.f;
        #pragma unroll 8
        for (int f = 0; f < F; ++f) acc += xs[r][f] * A.gk[f * HID + tt];
        A.hfeat[o] = acc;
        float ps = acc * A.asel[tt];
        float pn = acc * A.anei[tt];
        #pragma unroll
        for (int d = 16; d >= 1; d >>= 1) {
          ps += __shfl_xor(ps, d, 32);
          pn += __shfl_xor(pn, d, 32);
        }
        if ((tt & 31) == 0) {
          A.sself [bn * H + (tt >> 5)] = ps;
          A.sneigh[bn * H + (tt >> 5)] = pn;
        }
        __syncthreads();
      } else {
        float (*tl)[132] = (float (*)[132])smem;
        const int pb = vb - BN / 2;
        int m, ks, nksv;
        if (pb < 72) { const int m9 = pb >> 3; m = (m9 / 3) * 4 + (m9 % 3); ks = pb & 7; nksv = 8; }
        else         { const int r2 = pb - 72; m = (r2 >> 2) * 4 + 3; ks = r2 & 3; nksv = 4; }
        const float* src = A.wsrc[m] + (size_t)(ks * 32) * HID;
        #pragma unroll
        for (int i = 0; i < 4; ++i) {
          const int f4 = t + i * 256;
          const int r2 = f4 >> 5, c = (f4 & 31) * 4;
          f32x4 v = *(const f32x4*)&src[(size_t)r2 * HID + c];
          tl[r2][c] = v[0]; tl[r2][c + 1] = v[1]; tl[r2][c + 2] = v[2]; tl[r2][c + 3] = v[3];
        }
        __syncthreads();
        short* ph = A.whi[m];
        short* pl = A.wlo[m];
        const int lane_out = t & 63, cgp = t >> 6;
        const int colb = lane_out & 15, kg = lane_out >> 4;
        #pragma unroll
        for (int cc = 0; cc < 2; ++cc) {
          const int cf = cgp * 2 + cc;
          const int col = cf * 16 + colb;
          bf16x8 vh, vl;
          #pragma unroll
          for (int e = 0; e < 8; ++e) {
            short hi, lo; split_bf16(tl[kg * 8 + e][col], hi, lo);
            vh[e] = hi; vl[e] = lo;
          }
          const size_t o = (((size_t)cf * nksv + ks) * 64 + lane_out) * 8;
          *(bf16x8*)&ph[o] = vh;
          *(bf16x8*)&pl[o] = vl;
        }
        __syncthreads();
      }
    }
  }
  grid.sync();

  // ---------- P1: sparse GAT attention (wave-per-row, 4 rows/vblock) ----------
  {
    int   (*nbr)[256]    = (int (*)[256])smem;                 // 4KB
    float (*wts)[256][4] = (float (*)[256][4])(smem + 4096);   // 16KB
    const unsigned long long lmlt = ((unsigned long long)1 << lane) - 1ull;
    const int h0 = lane >> 5;
    for (int vb = blk; vb < BN / 4; vb += G) {
      const int bi = vb * 4 + wv;
      int*   nb      = nbr[wv];
      float (*wt)[4] = wts[wv];
      const int bbase = bi & ~(N - 1);
      const float si0 = A.sself[bi * H + 0];
      const float si1 = A.sself[bi * H + 1];
      const float si2 = A.sself[bi * H + 2];
      const float si3 = A.sself[bi * H + 3];
      float den0 = 0.f, den1 = 0.f, den2 = 0.f, den3 = 0.f;
      float acc0 = 0.f, acc1 = 0.f;
      const float* arow = A.a + (size_t)bi * N;
      const float* hb   = A.hfeat + (size_t)bbase * HID;
      const float* snb  = A.sneigh + (size_t)bbase * H;
      int num = 0;
      auto flush = [&]() {
        asm volatile("s_waitcnt lgkmcnt(0)" ::: "memory");
        for (int n = lane; n < num; n += 64) {
          const int j = nb[n];
          f32x4 sn = *(const f32x4*)&snb[(size_t)j * H];
          float s0 = si0 + sn[0]; s0 = (s0 > 0.f) ? s0 : 0.2f * s0;
          float s1 = si1 + sn[1]; s1 = (s1 > 0.f) ? s1 : 0.2f * s1;
          float s2 = si2 + sn[2]; s2 = (s2 > 0.f) ? s2 : 0.2f * s2;
          float s3 = si3 + sn[3]; s3 = (s3 > 0.f) ? s3 : 0.2f * s3;
          float w0 = __expf(s0), w1 = __expf(s1), w2 = __expf(s2), w3 = __expf(s3);
          wt[n][0] = w0; wt[n][1] = w1; wt[n][2] = w2; wt[n][3] = w3;
          den0 += w0; den1 += w1; den2 += w2; den3 += w3;
        }
        asm volatile("s_waitcnt lgkmcnt(0)" ::: "memory");
        #pragma unroll 4
        for (int n = 0; n < num; ++n) {
          const int j  = nb[n];
          const float wA = wt[n][h0];
          const float wB = wt[n][h0 + 2];
          const float* hr = hb + (size_t)j * HID;
          acc0 += wA * hr[lane];
          acc1 += wB * hr[lane + 64];
        }
        asm volatile("s_waitcnt lgkmcnt(0)" ::: "memory");
        num = 0;
      };
      for (int jb = 0; jb < N; jb += 256) {
        f32x4 av = *(const f32x4*)&arow[jb + lane * 4];
        #pragma unroll
        for (int e = 0; e < 4; ++e) {
          const unsigned long long m = __ballot(av[e] > 0.5f);
          if (av[e] > 0.5f) {
            const int pos = num + __popcll(m & lmlt);
            nb[pos] = jb + lane * 4 + e;
          }
          num += __popcll(m);
          if (num > 192) flush();
        }
      }
      if (num > 0) flush();
      #pragma unroll
      for (int d = 32; d >= 1; d >>= 1) {
        den0 += __shfl_xor(den0, d, 64);
        den1 += __shfl_xor(den1, d, 64);
        den2 += __shfl_xor(den2, d, 64);
        den3 += __shfl_xor(den3, d, 64);
      }
      const float dA = h0 ? den1 : den0;
      const float dB = h0 ? den3 : den2;
      const float v0 = acc0 / dA + A.bias[lane];
      const float v1 = acc1 / dB + A.bias[64 + lane];
      { short hi, lo; split_bf16(v0, hi, lo);
        A.conv_hi[(size_t)bi * HID + lane] = hi; A.conv_lo[(size_t)bi * HID + lane] = lo; }
      { short hi, lo; split_bf16(v1, hi, lo);
        A.conv_hi[(size_t)bi * HID + 64 + lane] = hi; A.conv_lo[(size_t)bi * HID + 64 + lane] = lo; }
    }
  }
  grid.sync();

  // ---------- P2: u+r gates ----------
  {
    short (*wlds)[16][64][8] = (short (*)[16][64][8])smem;   // 64KB
    const int lr = lane & 15, lg = lane >> 4, kb = lg * 8;
    for (int vb = blk; vb < 768; vb += G) {
      const int cell = vb / 256, rem = vb & 255;
      const int cg2 = rem & 3, bx = rem >> 2;
      const int R0 = bx * 64 + wv * 16;
      bf16x8 a_h[8], a_l[8];
      {
        const size_t ab = (size_t)(R0 + lr) * HID + kb;
        const short* hhi = A.hh[cell]; const short* hlo = A.hl[cell];
        #pragma unroll
        for (int ks = 0; ks < 4; ++ks) {
          a_h[ks]     = *(const bf16x8*)&A.conv_hi[ab + ks * 32];
          a_l[ks]     = *(const bf16x8*)&A.conv_lo[ab + ks * 32];
          a_h[4 + ks] = *(const bf16x8*)&hhi[ab + ks * 32];
          a_l[4 + ks] = *(const bf16x8*)&hlo[ab + ks * 32];
        }
      }
      {
        const short* srcs[4] = { A.WuH[cell], A.WuL[cell], A.WrH[cell], A.WrL[cell] };
        const short* sp = srcs[wv];
        #pragma unroll
        for (int f = 0; f < 16; ++f) {
          const short* gp = sp + (((size_t)((cg2 * 2 + (f >> 3)) * 8 + (f & 7))) * 64 + lane) * 8;
          stage16(gp, &wlds[wv][f][0][0]);
        }
      }
      asm volatile("s_waitcnt vmcnt(0)" ::: "memory");
      __syncthreads();
      f32x4 au[2] = {}, ar[2] = {};
      #pragma unroll
      for (int ks = 0; ks < 8; ++ks) {
        const bf16x8 ah = a_h[ks], al = a_l[ks];
        #pragma unroll
        for (int cfl = 0; cfl < 2; ++cfl) {
          const int f = cfl * 8 + ks;
          bf16x8 buh = *(const bf16x8*)&wlds[0][f][lane][0];
          bf16x8 bul = *(const bf16x8*)&wlds[1][f][lane][0];
          bf16x8 brh = *(const bf16x8*)&wlds[2][f][lane][0];
          bf16x8 brl = *(const bf16x8*)&wlds[3][f][lane][0];
          au[cfl] = __builtin_amdgcn_mfma_f32_16x16x32_bf16(ah, buh, au[cfl], 0, 0, 0);
          au[cfl] = __builtin_amdgcn_mfma_f32_16x16x32_bf16(ah, bul, au[cfl], 0, 0, 0);
          au[cfl] = __builtin_amdgcn_mfma_f32_16x16x32_bf16(al, buh, au[cfl], 0, 0, 0);
          ar[cfl] = __builtin_amdgcn_mfma_f32_16x16x32_bf16(ah, brh, ar[cfl], 0, 0, 0);
          ar[cfl] = __builtin_amdgcn_mfma_f32_16x16x32_bf16(ah, brl, ar[cfl], 0, 0, 0);
          ar[cfl] = __builtin_amdgcn_mfma_f32_16x16x32_bf16(al, brh, ar[cfl], 0, 0, 0);
        }
      }
      const float* bu = A.bu[cell];
      const float* br = A.br[cell];
      const float* hsrc = A.h[cell];
      float* uws = A.u_ws[cell];
      short* rhh = A.rhh[cell]; short* rhl = A.rhl[cell];
      #pragma unroll
      for (int cfl = 0; cfl < 2; ++cfl) {
        const int col = cg2 * 32 + cfl * 16 + lr;
        #pragma unroll
        for (int q = 0; q < 4; ++q) {
          const int row = R0 + lg * 4 + q;
          const int n = row & (N - 1);
          uws[(size_t)row * HID + col] = sigmoidf_(au[cfl][q] + bu[n]);
          const float rv = sigmoidf_(ar[cfl][q] + br[n]);
          const float rhv = rv * hsrc[(size_t)row * HID + col];
          short hi, lo; split_bf16(rhv, hi, lo);
          rhh[(size_t)row * HID + col] = hi;
          rhl[(size_t)row * HID + col] = lo;
        }
      }
      __syncthreads();
    }
  }
  grid.sync();

  // ---------- P3: c gate + h' ----------
  {
    short (*wlds)[16][64][8] = (short (*)[16][64][8])smem;   // 32KB used
    const int lr = lane & 15, lg = lane >> 4, kb = lg * 8;
    for (int vb = blk; vb < 768; vb += G) {
      const int cell = vb / 256, rem = vb & 255;
      const int cg2 = rem & 3, bx = rem >> 2;
      const int R0 = bx * 64 + wv * 16;
      bf16x8 a_h[8], a_l[8];
      {
        const size_t ab = (size_t)(R0 + lr) * HID + kb;
        const short* rhh = A.rhh[cell]; const short* rhl = A.rhl[cell];
        #pragma unroll
        for (int ks = 0; ks < 4; ++ks) {
          a_h[ks]     = *(const bf16x8*)&A.conv_hi[ab + ks * 32];
          a_l[ks]     = *(const bf16x8*)&A.conv_lo[ab + ks * 32];
          a_h[4 + ks] = *(const bf16x8*)&rhh[ab + ks * 32];
          a_l[4 + ks] = *(const bf16x8*)&rhl[ab + ks * 32];
        }
      }
      {
        const short* WH = A.WcH[cell];
        const short* WL = A.WcL[cell];
        #pragma unroll
        for (int i = 0; i < 8; ++i) {
          const int fid = wv * 8 + i;
          const int combo = fid >> 4, f = fid & 15;
          const short* src = combo ? WL : WH;
          const short* gp = src + (((size_t)((cg2 * 2 + (f >> 3)) * 8 + (f & 7))) * 64 + lane) * 8;
          stage16(gp, &wlds[combo][f][0][0]);
        }
      }
      asm volatile("s_waitcnt vmcnt(0)" ::: "memory");
      __syncthreads();
      f32x4 acc[2] = {};
      #pragma unroll
      for (int ks = 0; ks < 8; ++ks) {
        const bf16x8 ah = a_h[ks], al = a_l[ks];
        #pragma unroll
        for (int cfl = 0; cfl < 2; ++cfl) {
          const int f = cfl * 8 + ks;
          bf16x8 bh = *(const bf16x8*)&wlds[0][f][lane][0];
          bf16x8 bl = *(const bf16x8*)&wlds[1][f][lane][0];
          acc[cfl] = __builtin_amdgcn_mfma_f32_16x16x32_bf16(ah, bh, acc[cfl], 0, 0, 0);
          acc[cfl] = __builtin_amdgcn_mfma_f32_16x16x32_bf16(ah, bl, acc[cfl], 0, 0, 0);
          acc[cfl] = __builtin_amdgcn_mfma_f32_16x16x32_bf16(al, bh, acc[cfl], 0, 0, 0);
        }
      }
      const float* bc = A.bc[cell];
      const float* uw = A.u_ws[cell];
      const float* hsrc = A.h[cell];
      float* hout = A.hout[cell];
      short* hph = A.hph[cell]; short* hpl = A.hpl[cell];
      #pragma unroll
      for (int cfl = 0; cfl < 2; ++cfl) {
        const int col = cg2 * 32 + cfl * 16 + lr;
        #pragma unroll
        for (int q = 0; q < 4; ++q) {
          const int row = R0 + lg * 4 + q;
          const float cv = tanhf_(acc[cfl][q] + bc[row & (N - 1)]);
          const float uv = uw[(size_t)row * HID + col];
          const float hv = hsrc[(size_t)row * HID + col];
          const float o = uv * hv + (1.f - uv) * cv;
          __builtin_nontemporal_store(o, &hout[(size_t)row * HID + col]);
          short hi, lo; split_bf16(o, hi, lo);
          hph[(size_t)row * HID + col] = hi;
          hpl[(size_t)row * HID + col] = lo;
        }
      }
      __syncthreads();
    }
  }
  grid.sync();

  // ---------- P4: g = h' @ R ----------
  {
    short (*wlds)[8][64][8] = (short (*)[8][64][8])smem;   // 16KB used
    const int lr = lane & 15, lg = lane >> 4, kb = lg * 8;
    for (int vb = blk; vb < 768; vb += G) {
      const int cell = vb / 256, rem = vb & 255;
      const int cg2 = rem & 3, bx = rem >> 2;
      const int R0 = bx * 64 + wv * 16;
      bf16x8 a_h[4], a_l[4];
      {
        const size_t ab = (size_t)(R0 + lr) * HID + kb;
        const short* hph = A.hph[cell]; const short* hpl = A.hpl[cell];
        #pragma unroll
        for (int ks = 0; ks < 4; ++ks) {
          a_h[ks] = *(const bf16x8*)&hph[ab + ks * 32];
          a_l[ks] = *(const bf16x8*)&hpl[ab + ks * 32];
        }
      }
      {
        #pragma unroll
        for (int i = 0; i < 4; ++i) {
          const int fid = wv * 4 + i;
          const int combo = fid >> 3, f = fid & 7;
          const short* src = combo ? A.RtL[cell] : A.RtH[cell];
          const short* gp = src + (((size_t)((cg2 * 2 + (f >> 2)) * 4 + (f & 3))) * 64 + lane) * 8;
          stage16(gp, &wlds[combo][f][0][0]);
        }
      }
      asm volatile("s_waitcnt vmcnt(0)" ::: "memory");
      __syncthreads();
      f32x4 acc[2] = {};
      #pragma unroll
      for (int ks = 0; ks < 4; ++ks) {
        const bf16x8 ah = a_h[ks], al = a_l[ks];
        #pragma unroll
        for (int cfl = 0; cfl < 2; ++cfl) {
          const int f = cfl * 4 + ks;
          bf16x8 bh = *(const bf16x8*)&wlds[0][f][lane][0];
          bf16x8 bl = *(const bf16x8*)&wlds[1][f][lane][0];
          acc[cfl] = __builtin_amdgcn_mfma_f32_16x16x32_bf16(ah, bh, acc[cfl], 0, 0, 0);
          acc[cfl] = __builtin_amdgcn_mfma_f32_16x16x32_bf16(ah, bl, acc[cfl], 0, 0, 0);
          acc[cfl] = __builtin_amdgcn_mfma_f32_16x16x32_bf16(al, bh, acc[cfl], 0, 0, 0);
        }
      }
      short* gbo = A.gb[cell];
      #pragma unroll
      for (int cfl = 0; cfl < 2; ++cfl) {
        const int col = cg2 * 32 + cfl * 16 + lr;
        #pragma unroll
        for (int q = 0; q < 4; ++q) {
          const int row = R0 + lg * 4 + q;
          short hi, lo; split_bf16(acc[cfl][q], hi, lo);
          gbo[(size_t)row * HID + col] = hi;
        }
      }
      __syncthreads();
    }
  }
  grid.sync();

  // ---------- P5: bilinear logits (64x128 tiles, 4 waves) ----------
  {
    const int wi = wv >> 1, wj = wv & 1;
    const int lr = lane & 15;
    const int kb = (lane >> 4) * 8;
    for (int vb = blk; vb < 1024; vb += G) {
      const int b = vb >> 9, id = vb & 511;
      const int id2 = (id & 7) * 64 + (id >> 3);   // bijective XCD swizzle over 512
      const int ti = id2 & 31, tj = id2 >> 5;      // 32 row-tiles(64) x 16 col-tiles(128)
      const int i_base = ti * 64 + wi * 32;
      const int j_base = tj * 128 + wj * 64;
      f32x4 acc[3][2][4] = {};
      for (int k0 = 0; k0 < HID; k0 += 32) {
        #pragma unroll
        for (int d = 0; d < 3; ++d) {
          const short* gsrc = A.gb[d];
          const short* hsrc = A.hph[d];
          bf16x8 af0 = *(const bf16x8*)&gsrc[(size_t)(b * N + i_base + lr) * HID + k0 + kb];
          bf16x8 af1 = *(const bf16x8*)&gsrc[(size_t)(b * N + i_base + 16 + lr) * HID + k0 + kb];
          #pragma unroll
          for (int mj = 0; mj < 4; ++mj) {
            bf16x8 bf = *(const bf16x8*)&hsrc[(size_t)(b * N + j_base + mj * 16 + lr) * HID + k0 + kb];
            acc[d][0][mj] = __builtin_amdgcn_mfma_f32_16x16x32_bf16(af0, bf, acc[d][0][mj], 0, 0, 0);
            acc[d][1][mj] = __builtin_amdgcn_mfma_f32_16x16x32_bf16(af1, bf, acc[d][1][mj], 0, 0, 0);
          }
        }
      }
      const int orow = (lane >> 4) * 4;
      const int col  = lane & 15;
      #pragma unroll
      for (int mi = 0; mi < 2; ++mi)
        #pragma unroll
        for (int mj = 0; mj < 4; ++mj)
          #pragma unroll
          for (int r = 0; r < 4; ++r) {
            const int row = i_base + mi * 16 + orow + r;
            const int cc  = j_base + mj * 16 + col;
            float* p = &A.out[(((size_t)(b * N + row)) * N + cc) * 3];
            f32x3 v;
            v[0] = acc[0][mi][mj][r];
            v[1] = acc[1][mi][mj][r];
            v[2] = acc[2][mi][mj][r];
            *(f32x3*)p = v;
          }
    }
  }
}

// =================== FALLBACK: R17 six-kernel path ===================
struct PreArgs {
  const float* x; const float* gk; const float* asel; const float* anei;
  float* hfeat; float* sself; float* sneigh;
  const float* h[3];
  short* hh[3]; short* hl[3];
  const float* src[12];
  short* whi[12]; short* wlo[12];
};
__global__ __launch_bounds__(256) void k_pre(PreArgs pa) {
  const int bid = blockIdx.x;
  __shared__ float tl[32][132];
  if (bid < BN / 2) {
    const int t = threadIdx.x;
    const int r = t >> 7, tt = t & 127;
    const int bn = bid * 2 + r;
    float* xs = &tl[r][0];
    if (tt < F) xs[tt] = pa.x[(size_t)bn * F + tt];
    const size_t o = (size_t)bn * HID + tt;
    { short hi, lo; split_bf16(pa.h[0][o], hi, lo); pa.hh[0][o] = hi; pa.hl[0][o] = lo; }
    { short hi, lo; split_bf16(pa.h[1][o], hi, lo); pa.hh[1][o] = hi; pa.hl[1][o] = lo; }
    { short hi, lo; split_bf16(pa.h[2][o], hi, lo); pa.hh[2][o] = hi; pa.hl[2][o] = lo; }
    __syncthreads();
    float acc = 0.f;
    #pragma unroll 8
    for (int f = 0; f < F; ++f) acc += xs[f] * pa.gk[f * HID + tt];
    pa.hfeat[o] = acc;
    float ps = acc * pa.asel[tt];
    float pn = acc * pa.anei[tt];
    #pragma unroll
    for (int d = 16; d >= 1; d >>= 1) {
      ps += __shfl_xor(ps, d, 32);
      pn += __shfl_xor(pn, d, 32);
    }
    if ((tt & 31) == 0) {
      pa.sself [bn * H + (tt >> 5)] = ps;
      pa.sneigh[bn * H + (tt >> 5)] = pn;
    }
  } else {
    const int pb = bid - BN / 2;
    int m, ks, nksv;
    if (pb < 72) { const int m9 = pb >> 3; m = (m9 / 3) * 4 + (m9 % 3); ks = pb & 7; nksv = 8; }
    else         { const int r2 = pb - 72; m = (r2 >> 2) * 4 + 3; ks = r2 & 3; nksv = 4; }
    const int t = threadIdx.x;
    const float* src = pa.src[m] + (size_t)(ks * 32) * HID;
    #pragma unroll
    for (int i = 0; i < 4; ++i) {
      const int f4 = t + i * 256;
      const int r2 = f4 >> 5, c = (f4 & 31) * 4;
      f32x4 v = *(const f32x4*)&src[(size_t)r2 * HID + c];
      tl[r2][c] = v[0]; tl[r2][c + 1] = v[1]; tl[r2][c + 2] = v[2]; tl[r2][c + 3] = v[3];
    }
    __syncthreads();
    short* ph = pa.whi[m];
    short* pl = pa.wlo[m];
    const int lane_out = t & 63, cgp = t >> 6;
    const int colb = lane_out & 15, kg = lane_out >> 4;
    #pragma unroll
    for (int cc = 0; cc < 2; ++cc) {
      const int cf = cgp * 2 + cc;
      const int col = cf * 16 + colb;
      bf16x8 vh, vl;
      #pragma unroll
      for (int e = 0; e < 8; ++e) {
        short hi, lo; split_bf16(tl[kg * 8 + e][col], hi, lo);
        vh[e] = hi; vl[e] = lo;
      }
      const size_t o = (((size_t)cf * nksv + ks) * 64 + lane_out) * 8;
      *(bf16x8*)&ph[o] = vh;
      *(bf16x8*)&pl[o] = vl;
    }
  }
}

__global__ __launch_bounds__(256) void k_attn(
    const float* __restrict__ a, const float* __restrict__ hfeat,
    const float* __restrict__ sself, const float* __restrict__ sneigh,
    const float* __restrict__ bias,
    short* __restrict__ conv_hi, short* __restrict__ conv_lo) {
  const int wv   = threadIdx.x >> 6;
  const int lane = threadIdx.x & 63;
  const int bi   = blockIdx.x * 4 + wv;
  const int bbase = bi & ~(N - 1);
  __shared__ int   nbr[4][256];
  __shared__ float wts[4][256][4];
  int*   nb       = nbr[wv];
  float (*wt)[4]  = wts[wv];
  const float si0 = sself[bi * H + 0];
  const float si1 = sself[bi * H + 1];
  const float si2 = sself[bi * H + 2];
  const float si3 = sself[bi * H + 3];
  float den0 = 0.f, den1 = 0.f, den2 = 0.f, den3 = 0.f;
  float acc0 = 0.f, acc1 = 0.f;
  const unsigned long long lmlt = ((unsigned long long)1 << lane) - 1ull;
  const float* arow = a + (size_t)bi * N;
  const float* hb   = hfeat + (size_t)bbase * HID;
  const float* snb  = sneigh + (size_t)bbase * H;
  const int h0 = lane >> 5;
  int num = 0;
  auto flush = [&]() {
    asm volatile("s_waitcnt lgkmcnt(0)" ::: "memory");
    for (int n = lane; n < num; n += 64) {
      const int j = nb[n];
      f32x4 sn = *(const f32x4*)&snb[(size_t)j * H];
      float s0 = si0 + sn[0]; s0 = (s0 > 0.f) ? s0 : 0.2f * s0;
      float s1 = si1 + sn[1]; s1 = (s1 > 0.f) ? s1 : 0.2f * s1;
      float s2 = si2 + sn[2]; s2 = (s2 > 0.f) ? s2 : 0.2f * s2;
      float s3 = si3 + sn[3]; s3 = (s3 > 0.f) ? s3 : 0.2f * s3;
      float w0 = __expf(s0), w1 = __expf(s1), w2 = __expf(s2), w3 = __expf(s3);
      wt[n][0] = w0; wt[n][1] = w1; wt[n][2] = w2; wt[n][3] = w3;
      den0 += w0; den1 += w1; den2 += w2; den3 += w3;
    }
    asm volatile("s_waitcnt lgkmcnt(0)" ::: "memory");
    #pragma unroll 4
    for (int n = 0; n < num; ++n) {
      const int j  = nb[n];
      const float wA = wt[n][h0];
      const float wB = wt[n][h0 + 2];
      const float* hr = hb + (size_t)j * HID;
      acc0 += wA * hr[lane];
      acc1 += wB * hr[lane + 64];
    }
    asm volatile("s_waitcnt lgkmcnt(0)" ::: "memory");
    num = 0;
  };
  for (int jb = 0; jb < N; jb += 256) {
    f32x4 av = *(const f32x4*)&arow[jb + lane * 4];
    #pragma unroll
    for (int e = 0; e < 4; ++e) {
      const unsigned long long m = __ballot(av[e] > 0.5f);
      if (av[e] > 0.5f) {
        const int pos = num + __popcll(m & lmlt);
        nb[pos] = jb + lane * 4 + e;
      }
      num += __popcll(m);
      if (num > 192) flush();
    }
  }
  if (num > 0) flush();
  #pragma unroll
  for (int d = 32; d >= 1; d >>= 1) {
    den0 += __shfl_xor(den0, d, 64);
    den1 += __shfl_xor(den1, d, 64);
    den2 += __shfl_xor(den2, d, 64);
    den3 += __shfl_xor(den3, d, 64);
  }
  const float dA = h0 ? den1 : den0;
  const float dB = h0 ? den3 : den2;
  const float v0 = acc0 / dA + bias[lane];
  const float v1 = acc1 / dB + bias[64 + lane];
  { short hi, lo; split_bf16(v0, hi, lo);
    conv_hi[(size_t)bi * HID + lane] = hi; conv_lo[(size_t)bi * HID + lane] = lo; }
  { short hi, lo; split_bf16(v1, hi, lo);
    conv_hi[(size_t)bi * HID + 64 + lane] = hi; conv_lo[(size_t)bi * HID + 64 + lane] = lo; }
}

struct GArgs {
  const short* chi; const short* clo;
  const float* h[3];
  const short* hhi[3]; const short* hlo[3];
  const float* bu[3]; const float* br[3]; const float* bc[3];
  const short* WuH[3]; const short* WuL[3];
  const short* WrH[3]; const short* WrL[3];
  const short* WcH[3]; const short* WcL[3];
  const short* RtH[3]; const short* RtL[3];
  float* u_ws[3];
  short* rhh[3]; short* rhl[3];
  short* hph[3]; short* hpl[3];
  float* hout[3]; short* gb[3];
};

__global__ __launch_bounds__(256) void k_ur(GArgs ga) {
  const int wv = threadIdx.x >> 6, lane = threadIdx.x & 63;
  const int bx = blockIdx.x, cg2 = blockIdx.y, cell = blockIdx.z;
  const int lr = lane & 15, lg = lane >> 4, kb = lg * 8;
  const int R0 = bx * 64 + wv * 16;
  __shared__ short wlds[4][16][64][8];
  bf16x8 a_h[8], a_l[8];
  {
    const size_t ab = (size_t)(R0 + lr) * HID + kb;
    const short* hhi = ga.hhi[cell]; const short* hlo = ga.hlo[cell];
    #pragma unroll
    for (int ks = 0; ks < 4; ++ks) {
      a_h[ks]     = *(const bf16x8*)&ga.chi[ab + ks * 32];
      a_l[ks]     = *(const bf16x8*)&ga.clo[ab + ks * 32];
      a_h[4 + ks] = *(const bf16x8*)&hhi[ab + ks * 32];
      a_l[4 + ks] = *(const bf16x8*)&hlo[ab + ks * 32];
    }
  }
  {
    const short* srcs[4] = { ga.WuH[cell], ga.WuL[cell], ga.WrH[cell], ga.WrL[cell] };
    const short* sp = srcs[wv];
    #pragma unroll
    for (int f = 0; f < 16; ++f) {
      const short* gp = sp + (((size_t)((cg2 * 2 + (f >> 3)) * 8 + (f & 7))) * 64 + lane) * 8;
      stage16(gp, &wlds[wv][f][0][0]);
    }
  }
  asm volatile("s_waitcnt vmcnt(0)" ::: "memory");
  __syncthreads();
  f32x4 au[2] = {}, ar[2] = {};
  #pragma unroll
  for (int ks = 0; ks < 8; ++ks) {
    const bf16x8 ah = a_h[ks], al = a_l[ks];
    #pragma unroll
    for (int cfl = 0; cfl < 2; ++cfl) {
      const int f = cfl * 8 + ks;
      bf16x8 buh = *(const bf16x8*)&wlds[0][f][lane][0];
      bf16x8 bul = *(const bf16x8*)&wlds[1][f][lane][0];
      bf16x8 brh = *(const bf16x8*)&wlds[2][f][lane][0];
      bf16x8 brl = *(const bf16x8*)&wlds[3][f][lane][0];
      au[cfl] = __builtin_amdgcn_mfma_f32_16x16x32_bf16(ah, buh, au[cfl], 0, 0, 0);
      au[cfl] = __builtin_amdgcn_mfma_f32_16x16x32_bf16(ah, bul, au[cfl], 0, 0, 0);
      au[cfl] = __builtin_amdgcn_mfma_f32_16x16x32_bf16(al, buh, au[cfl], 0, 0, 0);
      ar[cfl] = __builtin_amdgcn_mfma_f32_16x16x32_bf16(ah, brh, ar[cfl], 0, 0, 0);
      ar[cfl] = __builtin_amdgcn_mfma_f32_16x16x32_bf16(ah, brl, ar[cfl], 0, 0, 0);
      ar[cfl] = __builtin_amdgcn_mfma_f32_16x16x32_bf16(al, brh, ar[cfl], 0, 0, 0);
    }
  }
  const float* bu = ga.bu[cell];
  const float* br = ga.br[cell];
  const float* hsrc = ga.h[cell];
  float* uws = ga.u_ws[cell];
  short* rhh = ga.rhh[cell]; short* rhl = ga.rhl[cell];
  #pragma unroll
  for (int cfl = 0; cfl < 2; ++cfl) {
    const int col = cg2 * 32 + cfl * 16 + lr;
    #pragma unroll
    for (int q = 0; q < 4; ++q) {
      const int row = R0 + lg * 4 + q;
      const int n = row & (N - 1);
      uws[(size_t)row * HID + col] = sigmoidf_(au[cfl][q] + bu[n]);
      const float rv = sigmoidf_(ar[cfl][q] + br[n]);
      const float rhv = rv * hsrc[(size_t)row * HID + col];
      short hi, lo; split_bf16(rhv, hi, lo);
      rhh[(size_t)row * HID + col] = hi;
      rhl[(size_t)row * HID + col] = lo;
    }
  }
}

__global__ __launch_bounds__(256) void k_c(GArgs ga) {
  const int wv = threadIdx.x >> 6, lane = threadIdx.x & 63;
  const int bx = blockIdx.x, cg2 = blockIdx.y, cell = blockIdx.z;
  const int lr = lane & 15, lg = lane >> 4, kb = lg * 8;
  const int R0 = bx * 64 + wv * 16;
  __shared__ short wlds[2][16][64][8];
  bf16x8 a_h[8], a_l[8];
  {
    const size_t ab = (size_t)(R0 + lr) * HID + kb;
    const short* rhh = ga.rhh[cell]; const short* rhl = ga.rhl[cell];
    #pragma unroll
    for (int ks = 0; ks < 4; ++ks) {
      a_h[ks]     = *(const bf16x8*)&ga.chi[ab + ks * 32];
      a_l[ks]     = *(const bf16x8*)&ga.clo[ab + ks * 32];
      a_h[4 + ks] = *(const bf16x8*)&rhh[ab + ks * 32];
      a_l[4 + ks] = *(const bf16x8*)&rhl[ab + ks * 32];
    }
  }
  {
    const short* WH = ga.WcH[cell];
    const short* WL = ga.WcL[cell];
    #pragma unroll
    for (int i = 0; i < 8; ++i) {
      const int fid = wv * 8 + i;
      const int combo = fid >> 4, f = fid & 15;
      const short* src = combo ? WL : WH;
      const short* gp = src + (((size_t)((cg2 * 2 + (f >> 3)) * 8 + (f & 7))) * 64 + lane) * 8;
      stage16(gp, &wlds[combo][f][0][0]);
    }
  }
  asm volatile("s_waitcnt vmcnt(0)" ::: "memory");
  __syncthreads();
  f32x4 acc[2] = {};
  #pragma unroll
  for (int ks = 0; ks < 8; ++ks) {
    const bf16x8 ah = a_h[ks], al = a_l[ks];
    #pragma unroll
    for (int cfl = 0; cfl < 2; ++cfl) {
      const int f = cfl * 8 + ks;
      bf16x8 bh = *(const bf16x8*)&wlds[0][f][lane][0];
      bf16x8 bl = *(const bf16x8*)&wlds[1][f][lane][0];
      acc[cfl] = __builtin_amdgcn_mfma_f32_16x16x32_bf16(ah, bh, acc[cfl], 0, 0, 0);
      acc[cfl] = __builtin_amdgcn_mfma_f32_16x16x32_bf16(ah, bl, acc[cfl], 0, 0, 0);
      acc[cfl] = __builtin_amdgcn_mfma_f32_16x16x32_bf16(al, bh, acc[cfl], 0, 0, 0);
    }
  }
  const float* bc = ga.bc[cell];
  const float* uw = ga.u_ws[cell];
  const float* hsrc = ga.h[cell];
  float* hout = ga.hout[cell];
  short* hph = ga.hph[cell]; short* hpl = ga.hpl[cell];
  #pragma unroll
  for (int cfl = 0; cfl < 2; ++cfl) {
    const int col = cg2 * 32 + cfl * 16 + lr;
    #pragma unroll
    for (int q = 0; q < 4; ++q) {
      const int row = R0 + lg * 4 + q;
      const float cv = tanhf_(acc[cfl][q] + bc[row & (N - 1)]);
      const float uv = uw[(size_t)row * HID + col];
      const float hv = hsrc[(size_t)row * HID + col];
      const float o = uv * hv + (1.f - uv) * cv;
      __builtin_nontemporal_store(o, &hout[(size_t)row * HID + col]);
      short hi, lo; split_bf16(o, hi, lo);
      hph[(size_t)row * HID + col] = hi;
      hpl[(size_t)row * HID + col] = lo;
    }
  }
}

__global__ __launch_bounds__(256) void k_g(GArgs ga) {
  const int wv = threadIdx.x >> 6, lane = threadIdx.x & 63;
  const int bx = blockIdx.x, cg2 = blockIdx.y, cell = blockIdx.z;
  const int lr = lane & 15, lg = lane >> 4, kb = lg * 8;
  const int R0 = bx * 64 + wv * 16;
  __shared__ short wlds[2][8][64][8];
  bf16x8 a_h[4], a_l[4];
  {
    const size_t ab = (size_t)(R0 + lr) * HID + kb;
    const short* hph = ga.hph[cell]; const short* hpl = ga.hpl[cell];
    #pragma unroll
    for (int ks = 0; ks < 4; ++ks) {
      a_h[ks] = *(const bf16x8*)&hph[ab + ks * 32];
      a_l[ks] = *(const bf16x8*)&hpl[ab + ks * 32];
    }
  }
  {
    #pragma unroll
    for (int i = 0; i < 4; ++i) {
      const int fid = wv * 4 + i;
      const int combo = fid >> 3, f = fid & 7;
      const short* src = combo ? ga.RtL[cell] : ga.RtH[cell];
      const short* gp = src + (((size_t)((cg2 * 2 + (f >> 2)) * 4 + (f & 3))) * 64 + lane) * 8;
      stage16(gp, &wlds[combo][f][0][0]);
    }
  }
  asm volatile("s_waitcnt vmcnt(0)" ::: "memory");
  __syncthreads();
  f32x4 acc[2] = {};
  #pragma unroll
  for (int ks = 0; ks < 4; ++ks) {
    const bf16x8 ah = a_h[ks], al = a_l[ks];
    #pragma unroll
    for (int cfl = 0; cfl < 2; ++cfl) {
      const int f = cfl * 4 + ks;
      bf16x8 bh = *(const bf16x8*)&wlds[0][f][lane][0];
      bf16x8 bl = *(const bf16x8*)&wlds[1][f][lane][0];
      acc[cfl] = __builtin_amdgcn_mfma_f32_16x16x32_bf16(ah, bh, acc[cfl], 0, 0, 0);
      acc[cfl] = __builtin_amdgcn_mfma_f32_16x16x32_bf16(ah, bl, acc[cfl], 0, 0, 0);
      acc[cfl] = __builtin_amdgcn_mfma_f32_16x16x32_bf16(al, bh, acc[cfl], 0, 0, 0);
    }
  }
  short* gbo = ga.gb[cell];
  #pragma unroll
  for (int cfl = 0; cfl < 2; ++cfl) {
    const int col = cg2 * 32 + cfl * 16 + lr;
    #pragma unroll
    for (int q = 0; q < 4; ++q) {
      const int row = R0 + lg * 4 + q;
      short hi, lo; split_bf16(acc[cfl][q], hi, lo);
      gbo[(size_t)row * HID + col] = hi;
    }
  }
}

__global__ __launch_bounds__(512) void k_bilinear(
    const short* __restrict__ g0, const short* __restrict__ g1,
    const short* __restrict__ g2, const short* __restrict__ h0,
    const short* __restrict__ h1, const short* __restrict__ h2,
    float* __restrict__ out) {
  const int id  = blockIdx.y * 16 + blockIdx.x;
  const int id2 = (id & 7) * 32 + (id >> 3);
  const int ti = id2 & 15, tj = id2 >> 4;
  const int b = blockIdx.z;
  const int t = threadIdx.x;
  const int w = t >> 6, l = t & 63;
  const int wi = w >> 1, wj = w & 1;
  const int i_base = ti * 128 + wi * 32;
  const int j_base = tj * 128 + wj * 64;
  const short* gbs[3] = {g0, g1, g2};
  const short* hbs[3] = {h0, h1, h2};
  const int lr = l & 15;
  const int kb = (l >> 4) * 8;
  f32x4 acc[3][2][4] = {};
  for (int k0 = 0; k0 < HID; k0 += 32) {
    #pragma unroll
    for (int d = 0; d < 3; ++d) {
      bf16x8 af0 = *(const bf16x8*)&gbs[d][(size_t)(b * N + i_base + lr) * HID + k0 + kb];
      bf16x8 af1 = *(const bf16x8*)&gbs[d][(size_t)(b * N + i_base + 16 + lr) * HID + k0 + kb];
      #pragma unroll
      for (int mj = 0; mj < 4; ++mj) {
        bf16x8 bf = *(const bf16x8*)&hbs[d][(size_t)(b * N + j_base + mj * 16 + lr) * HID + k0 + kb];
        acc[d][0][mj] = __builtin_amdgcn_mfma_f32_16x16x32_bf16(af0, bf, acc[d][0][mj], 0, 0, 0);
        acc[d][1][mj] = __builtin_amdgcn_mfma_f32_16x16x32_bf16(af1, bf, acc[d][1][mj], 0, 0, 0);
      }
    }
  }
  const int orow = (l >> 4) * 4;
  const int col  = l & 15;
  #pragma unroll
  for (int mi = 0; mi < 2; ++mi)
    #pragma unroll
    for (int mj = 0; mj < 4; ++mj)
      #pragma unroll
      for (int r = 0; r < 4; ++r) {
        const int row = i_base + mi * 16 + orow + r;
        const int cc  = j_base + mj * 16 + col;
        float* p = &out[(((size_t)(b * N + row)) * N + cc) * 3];
        f32x3 v;
        v[0] = acc[0][mi][mj][r];
        v[1] = acc[1][mi][mj][r];
        v[2] = acc[2][mi][mj][r];
        *(f32x3*)p = v;
      }
}

extern "C" void kernel_launch(void* const* d_in, const int* in_sizes, int n_in,
                              void* d_out, int out_size, void* d_ws, size_t ws_size,
                              hipStream_t stream) {
  (void)in_sizes; (void)n_in; (void)out_size; (void)ws_size;
  float* ws      = (float*)d_ws;
  float* hfeat   = ws;
  float* sself   = hfeat + (size_t)BN * HID;
  float* sneigh  = sself + (size_t)BN * H;
  float* u_ws0   = sneigh + (size_t)BN * H;
  short* sp      = (short*)(u_ws0 + 3 * (size_t)BN * HID);
  auto alloc_s = [&](size_t n) { short* p = sp; sp += n; return p; };

  short* conv_hi = alloc_s((size_t)BN * HID);
  short* conv_lo = alloc_s((size_t)BN * HID);
  short* h_hi[3]; short* h_lo[3];
  for (int c = 0; c < 3; ++c) { h_hi[c] = alloc_s((size_t)BN * HID); h_lo[c] = alloc_s((size_t)BN * HID); }
  short* rh_hi[3]; short* rh_lo[3];
  for (int c = 0; c < 3; ++c) { rh_hi[c] = alloc_s((size_t)BN * HID); rh_lo[c] = alloc_s((size_t)BN * HID); }
  short* hp_hi[3]; short* hp_lo[3];
  for (int c = 0; c < 3; ++c) { hp_hi[c] = alloc_s((size_t)BN * HID); hp_lo[c] = alloc_s((size_t)BN * HID); }
  short* gbb[3];
  for (int c = 0; c < 3; ++c) gbb[c] = alloc_s((size_t)BN * HID);

  float* out = (float*)d_out;

  MA ma;
  ma.x = (const float*)d_in[0];
  ma.a = (const float*)d_in[1];
  ma.gk = (const float*)d_in[5];
  ma.asel = (const float*)d_in[6];
  ma.anei = (const float*)d_in[7];
  ma.bias = (const float*)d_in[8];
  ma.hfeat = hfeat; ma.sself = sself; ma.sneigh = sneigh;
  ma.conv_hi = conv_hi; ma.conv_lo = conv_lo;
  ma.out = out;
  ma.h[0] = (const float*)d_in[2];
  ma.h[1] = (const float*)d_in[3];
  ma.h[2] = (const float*)d_in[4];
  for (int c = 0; c < 3; ++c) {
    const int base = 9 + c * 6;
    ma.hh[c] = h_hi[c]; ma.hl[c] = h_lo[c];
    ma.bu[c] = (const float*)d_in[base + 1];
    ma.br[c] = (const float*)d_in[base + 3];
    ma.bc[c] = (const float*)d_in[base + 5];
    short* wu_h = alloc_s(256 * 128); short* wu_l = alloc_s(256 * 128);
    short* wr_h = alloc_s(256 * 128); short* wr_l = alloc_s(256 * 128);
    short* wc_h = alloc_s(256 * 128); short* wc_l = alloc_s(256 * 128);
    short* rt_h = alloc_s(128 * 128); short* rt_l = alloc_s(128 * 128);
    const int pb = c * 4;
    ma.wsrc[pb + 0] = (const float*)d_in[base + 0]; ma.whi[pb + 0] = wu_h; ma.wlo[pb + 0] = wu_l;
    ma.wsrc[pb + 1] = (const float*)d_in[base + 2]; ma.whi[pb + 1] = wr_h; ma.wlo[pb + 1] = wr_l;
    ma.wsrc[pb + 2] = (const float*)d_in[base + 4]; ma.whi[pb + 2] = wc_h; ma.wlo[pb + 2] = wc_l;
    ma.wsrc[pb + 3] = (const float*)d_in[27 + c];   ma.whi[pb + 3] = rt_h; ma.wlo[pb + 3] = rt_l;
    ma.WuH[c] = wu_h; ma.WuL[c] = wu_l;
    ma.WrH[c] = wr_h; ma.WrL[c] = wr_l;
    ma.WcH[c] = wc_h; ma.WcL[c] = wc_l;
    ma.RtH[c] = rt_h; ma.RtL[c] = rt_l;
    ma.u_ws[c] = u_ws0 + (size_t)c * BN * HID;
    ma.rhh[c] = rh_hi[c]; ma.rhl[c] = rh_lo[c];
    ma.hph[c] = hp_hi[c]; ma.hpl[c] = hp_lo[c];
    ma.hout[c] = out + LOG_SZ + (size_t)c * BN * HID;
    ma.gb[c] = gbb[c];
  }

  // ---- try single cooperative dispatch (256-thr blocks, no VGPR cap) ----
  int bpc = 0;
  hipError_t oerr = hipOccupancyMaxActiveBlocksPerMultiprocessor(&bpc, k_mega2, 256, 0);
  bool done = false;
  if (oerr == hipSuccess && bpc >= 1) {
    int grid = bpc * 256;
    if (grid > 768) grid = 768;
    void* kargs[] = { (void*)&ma };
    hipError_t lerr = hipLaunchCooperativeKernel((const void*)k_mega2, dim3(grid), dim3(256),
                                                 kargs, 0, stream);
    if (lerr == hipSuccess) done = true;
  }

  if (!done) {
    PreArgs pa;
    pa.x = ma.x; pa.gk = ma.gk; pa.asel = ma.asel; pa.anei = ma.anei;
    pa.hfeat = hfeat; pa.sself = sself; pa.sneigh = sneigh;
    GArgs ga;
    ga.chi = conv_hi; ga.clo = conv_lo;
    for (int c = 0; c < 3; ++c) {
      pa.h[c] = ma.h[c]; pa.hh[c] = h_hi[c]; pa.hl[c] = h_lo[c];
      ga.h[c] = ma.h[c];
      ga.hhi[c] = h_hi[c]; ga.hlo[c] = h_lo[c];
      ga.bu[c] = ma.bu[c]; ga.br[c] = ma.br[c]; ga.bc[c] = ma.bc[c];
      ga.WuH[c] = ma.WuH[c]; ga.WuL[c] = ma.WuL[c];
      ga.WrH[c] = ma.WrH[c]; ga.WrL[c] = ma.WrL[c];
      ga.WcH[c] = ma.WcH[c]; ga.WcL[c] = ma.WcL[c];
      ga.RtH[c] = ma.RtH[c]; ga.RtL[c] = ma.RtL[c];
      ga.u_ws[c] = ma.u_ws[c];
      ga.rhh[c] = rh_hi[c]; ga.rhl[c] = rh_lo[c];
      ga.hph[c] = hp_hi[c]; ga.hpl[c] = hp_lo[c];
      ga.hout[c] = ma.hout[c];
      ga.gb[c] = gbb[c];
      const int pb = c * 4;
      pa.src[pb + 0] = ma.wsrc[pb + 0]; pa.whi[pb + 0] = ma.whi[pb + 0]; pa.wlo[pb + 0] = ma.wlo[pb + 0];
      pa.src[pb + 1] = ma.wsrc[pb + 1]; pa.whi[pb + 1] = ma.whi[pb + 1]; pa.wlo[pb + 1] = ma.wlo[pb + 1];
      pa.src[pb + 2] = ma.wsrc[pb + 2]; pa.whi[pb + 2] = ma.whi[pb + 2]; pa.wlo[pb + 2] = ma.wlo[pb + 2];
      pa.src[pb + 3] = ma.wsrc[pb + 3]; pa.whi[pb + 3] = ma.whi[pb + 3]; pa.wlo[pb + 3] = ma.wlo[pb + 3];
    }
    k_pre<<<BN / 2 + 84, 256, 0, stream>>>(pa);
    k_attn<<<BN / 4, 256, 0, stream>>>(ma.a, hfeat, sself, sneigh, ma.bias, conv_hi, conv_lo);
    k_ur<<<dim3(BN / 64, 4, 3), 256, 0, stream>>>(ga);
    k_c<<<dim3(BN / 64, 4, 3), 256, 0, stream>>>(ga);
    k_g<<<dim3(BN / 64, 4, 3), 256, 0, stream>>>(ga);
    dim3 g2(N / 128, N / 128, B);
    k_bilinear<<<g2, 512, 0, stream>>>(gbb[0], gbb[1], gbb[2],
                                       hp_hi[0], hp_hi[1], hp_hi[2], out);
  }
}

// Round 19
// 98.218 us; speedup vs baseline: 1.2599x; 1.1002x over previous
//
#include <hip/hip_runtime.h>
#include <hip/hip_bf16.h>

typedef __attribute__((ext_vector_type(4))) float f32x4;
typedef __attribute__((ext_vector_type(3))) float f32x3;
typedef __attribute__((ext_vector_type(8))) short bf16x8;

static constexpr int B   = 2;
static constexpr int N   = 2048;
static constexpr int F   = 64;
static constexpr int H   = 4;
static constexpr int HID = 128;
static constexpr int BN  = B * N;
static constexpr size_t LOG_SZ = (size_t)B * N * N * 3;

__device__ __forceinline__ float sigmoidf_(float x) { return 1.0f / (1.0f + __expf(-x)); }
__device__ __forceinline__ float tanhf_(float x) {
  float e = __expf(2.0f * x);
  return 1.0f - 2.0f / (e + 1.0f);      // inf-safe
}
// RNE bf16 split: v = hi + lo with ~2^-17 relative error
__device__ __forceinline__ void split_bf16(float v, short& hi, short& lo) {
  unsigned u = __float_as_uint(v);
  unsigned hr = (u + 0x7FFFu + ((u >> 16) & 1u)) >> 16;
  hi = (short)hr;
  float hv = __uint_as_float(hr << 16);
  float res = v - hv;
  unsigned u2 = __float_as_uint(res);
  lo = (short)((u2 + 0x7FFFu + ((u2 >> 16) & 1u)) >> 16);
}
__device__ __forceinline__ void stage16(const short* gp, short* lp) {
  __builtin_amdgcn_global_load_lds(
      (const __attribute__((address_space(1))) void*)gp,
      (__attribute__((address_space(3))) void*)lp, 16, 0, 0);
}

// ------------- K1: merged prep (coalesced weight transpose) + feat + h-split ---
struct PreArgs {
  const float* x; const float* gk; const float* asel; const float* anei;
  float* hfeat; float* sself; float* sneigh;
  const float* h[3];
  short* hh[3]; short* hl[3];
  const float* src[12];
  short* whi[12]; short* wlo[12];
};
__global__ __launch_bounds__(256) void k_pre(PreArgs pa) {
  const int bid = blockIdx.x;
  __shared__ float tl[32][132];
  if (bid < BN / 2) {
    const int t = threadIdx.x;
    const int r = t >> 7, tt = t & 127;
    const int bn = bid * 2 + r;
    float* xs = &tl[r][0];
    if (tt < F) xs[tt] = pa.x[(size_t)bn * F + tt];
    const size_t o = (size_t)bn * HID + tt;
    { short hi, lo; split_bf16(pa.h[0][o], hi, lo); pa.hh[0][o] = hi; pa.hl[0][o] = lo; }
    { short hi, lo; split_bf16(pa.h[1][o], hi, lo); pa.hh[1][o] = hi; pa.hl[1][o] = lo; }
    { short hi, lo; split_bf16(pa.h[2][o], hi, lo); pa.hh[2][o] = hi; pa.hl[2][o] = lo; }
    __syncthreads();
    float acc = 0.f;
    #pragma unroll 8
    for (int f = 0; f < F; ++f) acc += xs[f] * pa.gk[f * HID + tt];
    pa.hfeat[o] = acc;
    float ps = acc * pa.asel[tt];
    float pn = acc * pa.anei[tt];
    #pragma unroll
    for (int d = 16; d >= 1; d >>= 1) {
      ps += __shfl_xor(ps, d, 32);
      pn += __shfl_xor(pn, d, 32);
    }
    if ((tt & 31) == 0) {
      pa.sself [bn * H + (tt >> 5)] = ps;
      pa.sneigh[bn * H + (tt >> 5)] = pn;
    }
  } else {
    const int pb = bid - BN / 2;         // 0..83
    int m, ks, nksv;
    if (pb < 72) { const int m9 = pb >> 3; m = (m9 / 3) * 4 + (m9 % 3); ks = pb & 7; nksv = 8; }
    else         { const int r2 = pb - 72; m = (r2 >> 2) * 4 + 3; ks = r2 & 3; nksv = 4; }
    const int t = threadIdx.x;
    const float* src = pa.src[m] + (size_t)(ks * 32) * HID;
    #pragma unroll
    for (int i = 0; i < 4; ++i) {
      const int f4 = t + i * 256;
      const int r2 = f4 >> 5, c = (f4 & 31) * 4;
      f32x4 v = *(const f32x4*)&src[(size_t)r2 * HID + c];
      tl[r2][c] = v[0]; tl[r2][c + 1] = v[1]; tl[r2][c + 2] = v[2]; tl[r2][c + 3] = v[3];
    }
    __syncthreads();
    short* ph = pa.whi[m];
    short* pl = pa.wlo[m];
    const int lane_out = t & 63, cgp = t >> 6;
    const int colb = lane_out & 15, kg = lane_out >> 4;
    #pragma unroll
    for (int cc = 0; cc < 2; ++cc) {
      const int cf = cgp * 2 + cc;
      const int col = cf * 16 + colb;
      bf16x8 vh, vl;
      #pragma unroll
      for (int e = 0; e < 8; ++e) {
        short hi, lo; split_bf16(tl[kg * 8 + e][col], hi, lo);
        vh[e] = hi; vl[e] = lo;
      }
      const size_t o = (((size_t)cf * nksv + ks) * 64 + lane_out) * 8;
      *(bf16x8*)&ph[o] = vh;
      *(bf16x8*)&pl[o] = vl;
    }
  }
}

// ------------- K2: sparse GAT attention — one wave per row -------------
__global__ __launch_bounds__(256) void k_attn(
    const float* __restrict__ a, const float* __restrict__ hfeat,
    const float* __restrict__ sself, const float* __restrict__ sneigh,
    const float* __restrict__ bias,
    short* __restrict__ conv_hi, short* __restrict__ conv_lo) {
  const int wv   = threadIdx.x >> 6;
  const int lane = threadIdx.x & 63;
  const int bi   = blockIdx.x * 4 + wv;
  const int bbase = bi & ~(N - 1);
  __shared__ int   nbr[4][256];
  __shared__ float wts[4][256][4];
  int*   nb       = nbr[wv];
  float (*wt)[4]  = wts[wv];
  const float si0 = sself[bi * H + 0];
  const float si1 = sself[bi * H + 1];
  const float si2 = sself[bi * H + 2];
  const float si3 = sself[bi * H + 3];
  float den0 = 0.f, den1 = 0.f, den2 = 0.f, den3 = 0.f;
  float acc0 = 0.f, acc1 = 0.f;
  const unsigned long long lmlt = ((unsigned long long)1 << lane) - 1ull;
  const float* arow = a + (size_t)bi * N;
  const float* hb   = hfeat + (size_t)bbase * HID;
  const float* snb  = sneigh + (size_t)bbase * H;
  const int h0 = lane >> 5;
  int num = 0;
  auto flush = [&]() {
    asm volatile("s_waitcnt lgkmcnt(0)" ::: "memory");
    for (int n = lane; n < num; n += 64) {
      const int j = nb[n];
      f32x4 sn = *(const f32x4*)&snb[(size_t)j * H];
      float s0 = si0 + sn[0]; s0 = (s0 > 0.f) ? s0 : 0.2f * s0;
      float s1 = si1 + sn[1]; s1 = (s1 > 0.f) ? s1 : 0.2f * s1;
      float s2 = si2 + sn[2]; s2 = (s2 > 0.f) ? s2 : 0.2f * s2;
      float s3 = si3 + sn[3]; s3 = (s3 > 0.f) ? s3 : 0.2f * s3;
      float w0 = __expf(s0), w1 = __expf(s1), w2 = __expf(s2), w3 = __expf(s3);
      wt[n][0] = w0; wt[n][1] = w1; wt[n][2] = w2; wt[n][3] = w3;
      den0 += w0; den1 += w1; den2 += w2; den3 += w3;
    }
    asm volatile("s_waitcnt lgkmcnt(0)" ::: "memory");
    #pragma unroll 4
    for (int n = 0; n < num; ++n) {
      const int j  = nb[n];
      const float wA = wt[n][h0];
      const float wB = wt[n][h0 + 2];
      const float* hr = hb + (size_t)j * HID;
      acc0 += wA * hr[lane];
      acc1 += wB * hr[lane + 64];
    }
    asm volatile("s_waitcnt lgkmcnt(0)" ::: "memory");
    num = 0;
  };
  for (int jb = 0; jb < N; jb += 256) {
    f32x4 av = *(const f32x4*)&arow[jb + lane * 4];
    #pragma unroll
    for (int e = 0; e < 4; ++e) {
      const unsigned long long m = __ballot(av[e] > 0.5f);
      if (av[e] > 0.5f) {
        const int pos = num + __popcll(m & lmlt);
        nb[pos] = jb + lane * 4 + e;
      }
      num += __popcll(m);
      if (num > 192) flush();
    }
  }
  if (num > 0) flush();
  #pragma unroll
  for (int d = 32; d >= 1; d >>= 1) {
    den0 += __shfl_xor(den0, d, 64);
    den1 += __shfl_xor(den1, d, 64);
    den2 += __shfl_xor(den2, d, 64);
    den3 += __shfl_xor(den3, d, 64);
  }
  const float dA = h0 ? den1 : den0;
  const float dB = h0 ? den3 : den2;
  const float v0 = acc0 / dA + bias[lane];
  const float v1 = acc1 / dB + bias[64 + lane];
  { short hi, lo; split_bf16(v0, hi, lo);
    conv_hi[(size_t)bi * HID + lane] = hi; conv_lo[(size_t)bi * HID + lane] = lo; }
  { short hi, lo; split_bf16(v1, hi, lo);
    conv_hi[(size_t)bi * HID + 64 + lane] = hi; conv_lo[(size_t)bi * HID + 64 + lane] = lo; }
}

// ------------- shared arg pack -------------
struct GArgs {
  const short* chi; const short* clo;
  const float* h[3];
  const short* hhi[3]; const short* hlo[3];
  const float* bu[3]; const float* br[3]; const float* bc[3];
  const short* WuH[3]; const short* WuL[3];
  const short* WrH[3]; const short* WrL[3];
  const short* WcH[3]; const short* WcL[3];
  const short* RtH[3]; const short* RtL[3];
  float* u_ws[3];
  short* rhh[3]; short* rhl[3];
  short* hph[3]; short* hpl[3];
  float* hout[3]; short* gb[3];
};

// ------------- K3: u+r gates combined -------------
__global__ __launch_bounds__(256) void k_ur(GArgs ga) {
  const int wv = threadIdx.x >> 6, lane = threadIdx.x & 63;
  const int bx = blockIdx.x, cg2 = blockIdx.y, cell = blockIdx.z;
  const int lr = lane & 15, lg = lane >> 4, kb = lg * 8;
  const int R0 = bx * 64 + wv * 16;
  __shared__ short wlds[4][16][64][8];
  bf16x8 a_h[8], a_l[8];
  {
    const size_t ab = (size_t)(R0 + lr) * HID + kb;
    const short* hhi = ga.hhi[cell]; const short* hlo = ga.hlo[cell];
    #pragma unroll
    for (int ks = 0; ks < 4; ++ks) {
      a_h[ks]     = *(const bf16x8*)&ga.chi[ab + ks * 32];
      a_l[ks]     = *(const bf16x8*)&ga.clo[ab + ks * 32];
      a_h[4 + ks] = *(const bf16x8*)&hhi[ab + ks * 32];
      a_l[4 + ks] = *(const bf16x8*)&hlo[ab + ks * 32];
    }
  }
  {
    const short* srcs[4] = { ga.WuH[cell], ga.WuL[cell], ga.WrH[cell], ga.WrL[cell] };
    const short* sp = srcs[wv];
    #pragma unroll
    for (int f = 0; f < 16; ++f) {
      const short* gp = sp + (((size_t)((cg2 * 2 + (f >> 3)) * 8 + (f & 7))) * 64 + lane) * 8;
      stage16(gp, &wlds[wv][f][0][0]);
    }
  }
  asm volatile("s_waitcnt vmcnt(0)" ::: "memory");
  __syncthreads();
  f32x4 au[2] = {}, ar[2] = {};
  #pragma unroll
  for (int ks = 0; ks < 8; ++ks) {
    const bf16x8 ah = a_h[ks], al = a_l[ks];
    #pragma unroll
    for (int cfl = 0; cfl < 2; ++cfl) {
      const int f = cfl * 8 + ks;
      bf16x8 buh = *(const bf16x8*)&wlds[0][f][lane][0];
      bf16x8 bul = *(const bf16x8*)&wlds[1][f][lane][0];
      bf16x8 brh = *(const bf16x8*)&wlds[2][f][lane][0];
      bf16x8 brl = *(const bf16x8*)&wlds[3][f][lane][0];
      au[cfl] = __builtin_amdgcn_mfma_f32_16x16x32_bf16(ah, buh, au[cfl], 0, 0, 0);
      au[cfl] = __builtin_amdgcn_mfma_f32_16x16x32_bf16(ah, bul, au[cfl], 0, 0, 0);
      au[cfl] = __builtin_amdgcn_mfma_f32_16x16x32_bf16(al, buh, au[cfl], 0, 0, 0);
      ar[cfl] = __builtin_amdgcn_mfma_f32_16x16x32_bf16(ah, brh, ar[cfl], 0, 0, 0);
      ar[cfl] = __builtin_amdgcn_mfma_f32_16x16x32_bf16(ah, brl, ar[cfl], 0, 0, 0);
      ar[cfl] = __builtin_amdgcn_mfma_f32_16x16x32_bf16(al, brh, ar[cfl], 0, 0, 0);
    }
  }
  const float* bu = ga.bu[cell];
  const float* br = ga.br[cell];
  const float* hsrc = ga.h[cell];
  float* uws = ga.u_ws[cell];
  short* rhh = ga.rhh[cell]; short* rhl = ga.rhl[cell];
  #pragma unroll
  for (int cfl = 0; cfl < 2; ++cfl) {
    const int col = cg2 * 32 + cfl * 16 + lr;
    #pragma unroll
    for (int q = 0; q < 4; ++q) {
      const int row = R0 + lg * 4 + q;
      const int n = row & (N - 1);
      uws[(size_t)row * HID + col] = sigmoidf_(au[cfl][q] + bu[n]);
      const float rv = sigmoidf_(ar[cfl][q] + br[n]);
      const float rhv = rv * hsrc[(size_t)row * HID + col];
      short hi, lo; split_bf16(rhv, hi, lo);
      rhh[(size_t)row * HID + col] = hi;
      rhl[(size_t)row * HID + col] = lo;
    }
  }
}

// ------------- K4: c gate + h' -------------
__global__ __launch_bounds__(256) void k_c(GArgs ga) {
  const int wv = threadIdx.x >> 6, lane = threadIdx.x & 63;
  const int bx = blockIdx.x, cg2 = blockIdx.y, cell = blockIdx.z;
  const int lr = lane & 15, lg = lane >> 4, kb = lg * 8;
  const int R0 = bx * 64 + wv * 16;
  __shared__ short wlds[2][16][64][8];
  bf16x8 a_h[8], a_l[8];
  {
    const size_t ab = (size_t)(R0 + lr) * HID + kb;
    const short* rhh = ga.rhh[cell]; const short* rhl = ga.rhl[cell];
    #pragma unroll
    for (int ks = 0; ks < 4; ++ks) {
      a_h[ks]     = *(const bf16x8*)&ga.chi[ab + ks * 32];
      a_l[ks]     = *(const bf16x8*)&ga.clo[ab + ks * 32];
      a_h[4 + ks] = *(const bf16x8*)&rhh[ab + ks * 32];
      a_l[4 + ks] = *(const bf16x8*)&rhl[ab + ks * 32];
    }
  }
  {
    const short* WH = ga.WcH[cell];
    const short* WL = ga.WcL[cell];
    #pragma unroll
    for (int i = 0; i < 8; ++i) {
      const int fid = wv * 8 + i;
      const int combo = fid >> 4, f = fid & 15;
      const short* src = combo ? WL : WH;
      const short* gp = src + (((size_t)((cg2 * 2 + (f >> 3)) * 8 + (f & 7))) * 64 + lane) * 8;
      stage16(gp, &wlds[combo][f][0][0]);
    }
  }
  asm volatile("s_waitcnt vmcnt(0)" ::: "memory");
  __syncthreads();
  f32x4 acc[2] = {};
  #pragma unroll
  for (int ks = 0; ks < 8; ++ks) {
    const bf16x8 ah = a_h[ks], al = a_l[ks];
    #pragma unroll
    for (int cfl = 0; cfl < 2; ++cfl) {
      const int f = cfl * 8 + ks;
      bf16x8 bh = *(const bf16x8*)&wlds[0][f][lane][0];
      bf16x8 bl = *(const bf16x8*)&wlds[1][f][lane][0];
      acc[cfl] = __builtin_amdgcn_mfma_f32_16x16x32_bf16(ah, bh, acc[cfl], 0, 0, 0);
      acc[cfl] = __builtin_amdgcn_mfma_f32_16x16x32_bf16(ah, bl, acc[cfl], 0, 0, 0);
      acc[cfl] = __builtin_amdgcn_mfma_f32_16x16x32_bf16(al, bh, acc[cfl], 0, 0, 0);
    }
  }
  const float* bc = ga.bc[cell];
  const float* uw = ga.u_ws[cell];
  const float* hsrc = ga.h[cell];
  float* hout = ga.hout[cell];
  short* hph = ga.hph[cell]; short* hpl = ga.hpl[cell];
  #pragma unroll
  for (int cfl = 0; cfl < 2; ++cfl) {
    const int col = cg2 * 32 + cfl * 16 + lr;
    #pragma unroll
    for (int q = 0; q < 4; ++q) {
      const int row = R0 + lg * 4 + q;
      const float cv = tanhf_(acc[cfl][q] + bc[row & (N - 1)]);
      const float uv = uw[(size_t)row * HID + col];
      const float hv = hsrc[(size_t)row * HID + col];
      const float o = uv * hv + (1.f - uv) * cv;
      __builtin_nontemporal_store(o, &hout[(size_t)row * HID + col]);
      short hi, lo; split_bf16(o, hi, lo);
      hph[(size_t)row * HID + col] = hi;
      hpl[(size_t)row * HID + col] = lo;
    }
  }
}

// ------------- K5: g = h' @ R -------------
__global__ __launch_bounds__(256) void k_g(GArgs ga) {
  const int wv = threadIdx.x >> 6, lane = threadIdx.x & 63;
  const int bx = blockIdx.x, cg2 = blockIdx.y, cell = blockIdx.z;
  const int lr = lane & 15, lg = lane >> 4, kb = lg * 8;
  const int R0 = bx * 64 + wv * 16;
  __shared__ short wlds[2][8][64][8];
  bf16x8 a_h[4], a_l[4];
  {
    const size_t ab = (size_t)(R0 + lr) * HID + kb;
    const short* hph = ga.hph[cell]; const short* hpl = ga.hpl[cell];
    #pragma unroll
    for (int ks = 0; ks < 4; ++ks) {
      a_h[ks] = *(const bf16x8*)&hph[ab + ks * 32];
      a_l[ks] = *(const bf16x8*)&hpl[ab + ks * 32];
    }
  }
  {
    #pragma unroll
    for (int i = 0; i < 4; ++i) {
      const int fid = wv * 4 + i;
      const int combo = fid >> 3, f = fid & 7;
      const short* src = combo ? ga.RtL[cell] : ga.RtH[cell];
      const short* gp = src + (((size_t)((cg2 * 2 + (f >> 2)) * 4 + (f & 3))) * 64 + lane) * 8;
      stage16(gp, &wlds[combo][f][0][0]);
    }
  }
  asm volatile("s_waitcnt vmcnt(0)" ::: "memory");
  __syncthreads();
  f32x4 acc[2] = {};
  #pragma unroll
  for (int ks = 0; ks < 4; ++ks) {
    const bf16x8 ah = a_h[ks], al = a_l[ks];
    #pragma unroll
    for (int cfl = 0; cfl < 2; ++cfl) {
      const int f = cfl * 4 + ks;
      bf16x8 bh = *(const bf16x8*)&wlds[0][f][lane][0];
      bf16x8 bl = *(const bf16x8*)&wlds[1][f][lane][0];
      acc[cfl] = __builtin_amdgcn_mfma_f32_16x16x32_bf16(ah, bh, acc[cfl], 0, 0, 0);
      acc[cfl] = __builtin_amdgcn_mfma_f32_16x16x32_bf16(ah, bl, acc[cfl], 0, 0, 0);
      acc[cfl] = __builtin_amdgcn_mfma_f32_16x16x32_bf16(al, bh, acc[cfl], 0, 0, 0);
    }
  }
  short* gbo = ga.gb[cell];
  #pragma unroll
  for (int cfl = 0; cfl < 2; ++cfl) {
    const int col = cg2 * 32 + cfl * 16 + lr;
    #pragma unroll
    for (int q = 0; q < 4; ++q) {
      const int row = R0 + lg * 4 + q;
      short hi, lo; split_bf16(acc[cfl][q], hi, lo);
      gbo[(size_t)row * HID + col] = hi;
    }
  }
}

// ------------- K6: logits — 128x128 tiles, LDS-staged B fragments --------------
// grid (16, 16, B), 512 thr = 8 waves (4 rowgrp x 2 colhalf); per-dtype phases.
__global__ __launch_bounds__(512) void k_bilinear(
    const short* __restrict__ g0, const short* __restrict__ g1,
    const short* __restrict__ g2, const short* __restrict__ h0,
    const short* __restrict__ h1, const short* __restrict__ h2,
    float* __restrict__ out) {
  const int id  = blockIdx.y * 16 + blockIdx.x;      // 0..255
  const int id2 = (id & 7) * 32 + (id >> 3);         // bijective XCD swizzle
  const int ti = id2 & 15, tj = id2 >> 4;
  const int b = blockIdx.z;
  const int t = threadIdx.x;
  const int w = t >> 6, l = t & 63;
  const int wi = w >> 1, wj = w & 1;
  const int i_base = ti * 128 + wi * 32;
  const int j_tile = tj * 128;
  const short* gbs[3] = {g0, g1, g2};
  const short* hbs[3] = {h0, h1, h2};
  const int lr = l & 15;
  const int kb = (l >> 4) * 8;
  __shared__ short bf_lds[32][64][8];                // 32 frags x 1KB = 32KB
  f32x4 acc[3][2][4] = {};
  for (int d = 0; d < 3; ++d) {
    // stage all 32 B-fragments of h[d] (cols j_tile..+128, k 0..128), 4 per wave
    {
      const short* hsrc = hbs[d];
      #pragma unroll
      for (int i = 0; i < 4; ++i) {
        const int f = w * 4 + i;                     // 0..31 = cf*4 + ks
        const int cf = f >> 2, ks = f & 3;
        const short* gp = hsrc +
            (size_t)(b * N + j_tile + cf * 16 + lr) * HID + ks * 32 + kb;
        stage16(gp, &bf_lds[f][0][0]);
      }
    }
    // A-fragments (g) for this dtype: 2 row-frags x 4 k-steps
    bf16x8 af[2][4];
    {
      const short* gsrc = gbs[d];
      #pragma unroll
      for (int ks = 0; ks < 4; ++ks) {
        af[0][ks] = *(const bf16x8*)&gsrc[(size_t)(b * N + i_base + lr) * HID + ks * 32 + kb];
        af[1][ks] = *(const bf16x8*)&gsrc[(size_t)(b * N + i_base + 16 + lr) * HID + ks * 32 + kb];
      }
    }
    asm volatile("s_waitcnt vmcnt(0)" ::: "memory");
    __syncthreads();
    #pragma unroll
    for (int ks = 0; ks < 4; ++ks) {
      #pragma unroll
      for (int mj = 0; mj < 4; ++mj) {
        const int f = (wj * 4 + mj) * 4 + ks;
        bf16x8 bfv = *(const bf16x8*)&bf_lds[f][l][0];
        acc[d][0][mj] = __builtin_amdgcn_mfma_f32_16x16x32_bf16(af[0][ks], bfv, acc[d][0][mj], 0, 0, 0);
        acc[d][1][mj] = __builtin_amdgcn_mfma_f32_16x16x32_bf16(af[1][ks], bfv, acc[d][1][mj], 0, 0, 0);
      }
    }
    __syncthreads();                                 // LDS reads done before restage
  }
  const int orow = (l >> 4) * 4;
  const int col  = l & 15;
  const int j_base = j_tile + wj * 64;
  #pragma unroll
  for (int mi = 0; mi < 2; ++mi)
    #pragma unroll
    for (int mj = 0; mj < 4; ++mj)
      #pragma unroll
      for (int r = 0; r < 4; ++r) {
        const int row = i_base + mi * 16 + orow + r;
        const int cc  = j_base + mj * 16 + col;
        float* p = &out[(((size_t)(b * N + row)) * N + cc) * 3];
        f32x3 v;
        v[0] = acc[0][mi][mj][r];
        v[1] = acc[1][mi][mj][r];
        v[2] = acc[2][mi][mj][r];
        *(f32x3*)p = v;
      }
}

extern "C" void kernel_launch(void* const* d_in, const int* in_sizes, int n_in,
                              void* d_out, int out_size, void* d_ws, size_t ws_size,
                              hipStream_t stream) {
  (void)in_sizes; (void)n_in; (void)out_size; (void)ws_size;
  const float* a    = (const float*)d_in[1];
  const float* bias = (const float*)d_in[8];

  float* ws      = (float*)d_ws;
  float* hfeat   = ws;
  float* sself   = hfeat + (size_t)BN * HID;
  float* sneigh  = sself + (size_t)BN * H;
  float* u_ws0   = sneigh + (size_t)BN * H;
  short* sp      = (short*)(u_ws0 + 3 * (size_t)BN * HID);
  auto alloc_s = [&](size_t n) { short* p = sp; sp += n; return p; };

  short* conv_hi = alloc_s((size_t)BN * HID);
  short* conv_lo = alloc_s((size_t)BN * HID);
  short* h_hi[3]; short* h_lo[3];
  for (int c = 0; c < 3; ++c) { h_hi[c] = alloc_s((size_t)BN * HID); h_lo[c] = alloc_s((size_t)BN * HID); }
  short* rh_hi[3]; short* rh_lo[3];
  for (int c = 0; c < 3; ++c) { rh_hi[c] = alloc_s((size_t)BN * HID); rh_lo[c] = alloc_s((size_t)BN * HID); }
  short* hp_hi[3]; short* hp_lo[3];
  for (int c = 0; c < 3; ++c) { hp_hi[c] = alloc_s((size_t)BN * HID); hp_lo[c] = alloc_s((size_t)BN * HID); }
  short* gbb[3];
  for (int c = 0; c < 3; ++c) gbb[c] = alloc_s((size_t)BN * HID);

  float* out = (float*)d_out;

  PreArgs pa;
  pa.x = (const float*)d_in[0];
  pa.gk = (const float*)d_in[5];
  pa.asel = (const float*)d_in[6];
  pa.anei = (const float*)d_in[7];
  pa.hfeat = hfeat; pa.sself = sself; pa.sneigh = sneigh;

  GArgs ga;
  ga.chi = conv_hi; ga.clo = conv_lo;
  ga.h[0] = (const float*)d_in[2];
  ga.h[1] = (const float*)d_in[3];
  ga.h[2] = (const float*)d_in[4];
  for (int c = 0; c < 3; ++c) {
    pa.h[c] = ga.h[c];
    pa.hh[c] = h_hi[c]; pa.hl[c] = h_lo[c];
    const int base = 9 + c * 6;
    ga.hhi[c] = h_hi[c]; ga.hlo[c] = h_lo[c];
    ga.bu[c] = (const float*)d_in[base + 1];
    ga.br[c] = (const float*)d_in[base + 3];
    ga.bc[c] = (const float*)d_in[base + 5];
    short* wu_h = alloc_s(256 * 128); short* wu_l = alloc_s(256 * 128);
    short* wr_h = alloc_s(256 * 128); short* wr_l = alloc_s(256 * 128);
    short* wc_h = alloc_s(256 * 128); short* wc_l = alloc_s(256 * 128);
    short* rt_h = alloc_s(128 * 128); short* rt_l = alloc_s(128 * 128);
    const int pb = c * 4;
    pa.src[pb + 0] = (const float*)d_in[base + 0]; pa.whi[pb + 0] = wu_h; pa.wlo[pb + 0] = wu_l;
    pa.src[pb + 1] = (const float*)d_in[base + 2]; pa.whi[pb + 1] = wr_h; pa.wlo[pb + 1] = wr_l;
    pa.src[pb + 2] = (const float*)d_in[base + 4]; pa.whi[pb + 2] = wc_h; pa.wlo[pb + 2] = wc_l;
    pa.src[pb + 3] = (const float*)d_in[27 + c];   pa.whi[pb + 3] = rt_h; pa.wlo[pb + 3] = rt_l;
    ga.WuH[c] = wu_h; ga.WuL[c] = wu_l;
    ga.WrH[c] = wr_h; ga.WrL[c] = wr_l;
    ga.WcH[c] = wc_h; ga.WcL[c] = wc_l;
    ga.RtH[c] = rt_h; ga.RtL[c] = rt_l;
    ga.u_ws[c] = u_ws0 + (size_t)c * BN * HID;
    ga.rhh[c] = rh_hi[c]; ga.rhl[c] = rh_lo[c];
    ga.hph[c] = hp_hi[c]; ga.hpl[c] = hp_lo[c];
    ga.hout[c] = out + LOG_SZ + (size_t)c * BN * HID;
    ga.gb[c] = gbb[c];
  }

  k_pre<<<BN / 2 + 84, 256, 0, stream>>>(pa);
  k_attn<<<BN / 4, 256, 0, stream>>>(a, hfeat, sself, sneigh, bias, conv_hi, conv_lo);
  k_ur<<<dim3(BN / 64, 4, 3), 256, 0, stream>>>(ga);
  k_c<<<dim3(BN / 64, 4, 3), 256, 0, stream>>>(ga);
  k_g<<<dim3(BN / 64, 4, 3), 256, 0, stream>>>(ga);
  dim3 g2(16, 16, B);
  k_bilinear<<<g2, 512, 0, stream>>>(gbb[0], gbb[1], gbb[2],
                                     hp_hi[0], hp_hi[1], hp_hi[2], out);
}

// Round 20
// 97.711 us; speedup vs baseline: 1.2665x; 1.0052x over previous
//
#include <hip/hip_runtime.h>
#include <hip/hip_bf16.h>

typedef __attribute__((ext_vector_type(4))) float f32x4;
typedef __attribute__((ext_vector_type(3))) float f32x3;
typedef __attribute__((ext_vector_type(8))) short bf16x8;

static constexpr int B   = 2;
static constexpr int N   = 2048;
static constexpr int F   = 64;
static constexpr int H   = 4;
static constexpr int HID = 128;
static constexpr int BN  = B * N;
static constexpr size_t LOG_SZ = (size_t)B * N * N * 3;

__device__ __forceinline__ float sigmoidf_(float x) { return 1.0f / (1.0f + __expf(-x)); }
__device__ __forceinline__ float tanhf_(float x) {
  float e = __expf(2.0f * x);
  return 1.0f - 2.0f / (e + 1.0f);      // inf-safe
}
// RNE bf16 split: v = hi + lo with ~2^-17 relative error
__device__ __forceinline__ void split_bf16(float v, short& hi, short& lo) {
  unsigned u = __float_as_uint(v);
  unsigned hr = (u + 0x7FFFu + ((u >> 16) & 1u)) >> 16;
  hi = (short)hr;
  float hv = __uint_as_float(hr << 16);
  float res = v - hv;
  unsigned u2 = __float_as_uint(res);
  lo = (short)((u2 + 0x7FFFu + ((u2 >> 16) & 1u)) >> 16);
}
__device__ __forceinline__ void stage16(const short* gp, short* lp) {
  __builtin_amdgcn_global_load_lds(
      (const __attribute__((address_space(1))) void*)gp,
      (__attribute__((address_space(3))) void*)lp, 16, 0, 0);
}

// ------------- K1: merged prep (coalesced weight transpose) + feat + h-split ---
struct PreArgs {
  const float* x; const float* gk; const float* asel; const float* anei;
  float* hfeat; float* sself; float* sneigh;
  const float* h[3];
  short* hh[3]; short* hl[3];
  const float* src[12];
  short* whi[12]; short* wlo[12];
};
__global__ __launch_bounds__(256) void k_pre(PreArgs pa) {
  const int bid = blockIdx.x;
  __shared__ float tl[32][132];
  if (bid < BN / 2) {
    const int t = threadIdx.x;
    const int r = t >> 7, tt = t & 127;
    const int bn = bid * 2 + r;
    float* xs = &tl[r][0];
    if (tt < F) xs[tt] = pa.x[(size_t)bn * F + tt];
    const size_t o = (size_t)bn * HID + tt;
    { short hi, lo; split_bf16(pa.h[0][o], hi, lo); pa.hh[0][o] = hi; pa.hl[0][o] = lo; }
    { short hi, lo; split_bf16(pa.h[1][o], hi, lo); pa.hh[1][o] = hi; pa.hl[1][o] = lo; }
    { short hi, lo; split_bf16(pa.h[2][o], hi, lo); pa.hh[2][o] = hi; pa.hl[2][o] = lo; }
    __syncthreads();
    float acc = 0.f;
    #pragma unroll 8
    for (int f = 0; f < F; ++f) acc += xs[f] * pa.gk[f * HID + tt];
    pa.hfeat[o] = acc;
    float ps = acc * pa.asel[tt];
    float pn = acc * pa.anei[tt];
    #pragma unroll
    for (int d = 16; d >= 1; d >>= 1) {
      ps += __shfl_xor(ps, d, 32);
      pn += __shfl_xor(pn, d, 32);
    }
    if ((tt & 31) == 0) {
      pa.sself [bn * H + (tt >> 5)] = ps;
      pa.sneigh[bn * H + (tt >> 5)] = pn;
    }
  } else {
    const int pb = bid - BN / 2;         // 0..83
    int m, ks, nksv;
    if (pb < 72) { const int m9 = pb >> 3; m = (m9 / 3) * 4 + (m9 % 3); ks = pb & 7; nksv = 8; }
    else         { const int r2 = pb - 72; m = (r2 >> 2) * 4 + 3; ks = r2 & 3; nksv = 4; }
    const int t = threadIdx.x;
    const float* src = pa.src[m] + (size_t)(ks * 32) * HID;
    #pragma unroll
    for (int i = 0; i < 4; ++i) {
      const int f4 = t + i * 256;
      const int r2 = f4 >> 5, c = (f4 & 31) * 4;
      f32x4 v = *(const f32x4*)&src[(size_t)r2 * HID + c];
      tl[r2][c] = v[0]; tl[r2][c + 1] = v[1]; tl[r2][c + 2] = v[2]; tl[r2][c + 3] = v[3];
    }
    __syncthreads();
    short* ph = pa.whi[m];
    short* pl = pa.wlo[m];
    const int lane_out = t & 63, cgp = t >> 6;
    const int colb = lane_out & 15, kg = lane_out >> 4;
    #pragma unroll
    for (int cc = 0; cc < 2; ++cc) {
      const int cf = cgp * 2 + cc;
      const int col = cf * 16 + colb;
      bf16x8 vh, vl;
      #pragma unroll
      for (int e = 0; e < 8; ++e) {
        short hi, lo; split_bf16(tl[kg * 8 + e][col], hi, lo);
        vh[e] = hi; vl[e] = lo;
      }
      const size_t o = (((size_t)cf * nksv + ks) * 64 + lane_out) * 8;
      *(bf16x8*)&ph[o] = vh;
      *(bf16x8*)&pl[o] = vl;
    }
  }
}

// ------------- K2: sparse GAT attention — one wave per row -------------
__global__ __launch_bounds__(256) void k_attn(
    const float* __restrict__ a, const float* __restrict__ hfeat,
    const float* __restrict__ sself, const float* __restrict__ sneigh,
    const float* __restrict__ bias,
    short* __restrict__ conv_hi, short* __restrict__ conv_lo) {
  const int wv   = threadIdx.x >> 6;
  const int lane = threadIdx.x & 63;
  const int bi   = blockIdx.x * 4 + wv;
  const int bbase = bi & ~(N - 1);
  __shared__ int   nbr[4][256];
  __shared__ float wts[4][256][4];
  int*   nb       = nbr[wv];
  float (*wt)[4]  = wts[wv];
  const float si0 = sself[bi * H + 0];
  const float si1 = sself[bi * H + 1];
  const float si2 = sself[bi * H + 2];
  const float si3 = sself[bi * H + 3];
  float den0 = 0.f, den1 = 0.f, den2 = 0.f, den3 = 0.f;
  float acc0 = 0.f, acc1 = 0.f;
  const unsigned long long lmlt = ((unsigned long long)1 << lane) - 1ull;
  const float* arow = a + (size_t)bi * N;
  const float* hb   = hfeat + (size_t)bbase * HID;
  const float* snb  = sneigh + (size_t)bbase * H;
  const int h0 = lane >> 5;
  int num = 0;
  auto flush = [&]() {
    asm volatile("s_waitcnt lgkmcnt(0)" ::: "memory");
    for (int n = lane; n < num; n += 64) {
      const int j = nb[n];
      f32x4 sn = *(const f32x4*)&snb[(size_t)j * H];
      float s0 = si0 + sn[0]; s0 = (s0 > 0.f) ? s0 : 0.2f * s0;
      float s1 = si1 + sn[1]; s1 = (s1 > 0.f) ? s1 : 0.2f * s1;
      float s2 = si2 + sn[2]; s2 = (s2 > 0.f) ? s2 : 0.2f * s2;
      float s3 = si3 + sn[3]; s3 = (s3 > 0.f) ? s3 : 0.2f * s3;
      float w0 = __expf(s0), w1 = __expf(s1), w2 = __expf(s2), w3 = __expf(s3);
      wt[n][0] = w0; wt[n][1] = w1; wt[n][2] = w2; wt[n][3] = w3;
      den0 += w0; den1 += w1; den2 += w2; den3 += w3;
    }
    asm volatile("s_waitcnt lgkmcnt(0)" ::: "memory");
    #pragma unroll 4
    for (int n = 0; n < num; ++n) {
      const int j  = nb[n];
      const float wA = wt[n][h0];
      const float wB = wt[n][h0 + 2];
      const float* hr = hb + (size_t)j * HID;
      acc0 += wA * hr[lane];
      acc1 += wB * hr[lane + 64];
    }
    asm volatile("s_waitcnt lgkmcnt(0)" ::: "memory");
    num = 0;
  };
  for (int jb = 0; jb < N; jb += 256) {
    f32x4 av = *(const f32x4*)&arow[jb + lane * 4];
    #pragma unroll
    for (int e = 0; e < 4; ++e) {
      const unsigned long long m = __ballot(av[e] > 0.5f);
      if (av[e] > 0.5f) {
        const int pos = num + __popcll(m & lmlt);
        nb[pos] = jb + lane * 4 + e;
      }
      num += __popcll(m);
      if (num > 192) flush();
    }
  }
  if (num > 0) flush();
  #pragma unroll
  for (int d = 32; d >= 1; d >>= 1) {
    den0 += __shfl_xor(den0, d, 64);
    den1 += __shfl_xor(den1, d, 64);
    den2 += __shfl_xor(den2, d, 64);
    den3 += __shfl_xor(den3, d, 64);
  }
  const float dA = h0 ? den1 : den0;
  const float dB = h0 ? den3 : den2;
  const float v0 = acc0 / dA + bias[lane];
  const float v1 = acc1 / dB + bias[64 + lane];
  { short hi, lo; split_bf16(v0, hi, lo);
    conv_hi[(size_t)bi * HID + lane] = hi; conv_lo[(size_t)bi * HID + lane] = lo; }
  { short hi, lo; split_bf16(v1, hi, lo);
    conv_hi[(size_t)bi * HID + 64 + lane] = hi; conv_lo[(size_t)bi * HID + 64 + lane] = lo; }
}

// ------------- shared arg pack -------------
struct GArgs {
  const short* chi; const short* clo;
  const float* h[3];
  const short* hhi[3]; const short* hlo[3];
  const float* bu[3]; const float* br[3]; const float* bc[3];
  const short* WuH[3]; const short* WuL[3];
  const short* WrH[3]; const short* WrL[3];
  const short* WcH[3]; const short* WcL[3];
  const short* RtH[3]; const short* RtL[3];
  float* u_ws[3];
  short* rhh[3]; short* rhl[3];
  short* hph[3]; short* hpl[3];
  float* hout[3]; short* gb[3];
};

// ------------- K3: u+r gates combined -------------
__global__ __launch_bounds__(256) void k_ur(GArgs ga) {
  const int wv = threadIdx.x >> 6, lane = threadIdx.x & 63;
  const int bx = blockIdx.x, cg2 = blockIdx.y, cell = blockIdx.z;
  const int lr = lane & 15, lg = lane >> 4, kb = lg * 8;
  const int R0 = bx * 64 + wv * 16;
  __shared__ short wlds[4][16][64][8];
  bf16x8 a_h[8], a_l[8];
  {
    const size_t ab = (size_t)(R0 + lr) * HID + kb;
    const short* hhi = ga.hhi[cell]; const short* hlo = ga.hlo[cell];
    #pragma unroll
    for (int ks = 0; ks < 4; ++ks) {
      a_h[ks]     = *(const bf16x8*)&ga.chi[ab + ks * 32];
      a_l[ks]     = *(const bf16x8*)&ga.clo[ab + ks * 32];
      a_h[4 + ks] = *(const bf16x8*)&hhi[ab + ks * 32];
      a_l[4 + ks] = *(const bf16x8*)&hlo[ab + ks * 32];
    }
  }
  {
    const short* srcs[4] = { ga.WuH[cell], ga.WuL[cell], ga.WrH[cell], ga.WrL[cell] };
    const short* sp = srcs[wv];
    #pragma unroll
    for (int f = 0; f < 16; ++f) {
      const short* gp = sp + (((size_t)((cg2 * 2 + (f >> 3)) * 8 + (f & 7))) * 64 + lane) * 8;
      stage16(gp, &wlds[wv][f][0][0]);
    }
  }
  asm volatile("s_waitcnt vmcnt(0)" ::: "memory");
  __syncthreads();
  f32x4 au[2] = {}, ar[2] = {};
  #pragma unroll
  for (int ks = 0; ks < 8; ++ks) {
    const bf16x8 ah = a_h[ks], al = a_l[ks];
    #pragma unroll
    for (int cfl = 0; cfl < 2; ++cfl) {
      const int f = cfl * 8 + ks;
      bf16x8 buh = *(const bf16x8*)&wlds[0][f][lane][0];
      bf16x8 bul = *(const bf16x8*)&wlds[1][f][lane][0];
      bf16x8 brh = *(const bf16x8*)&wlds[2][f][lane][0];
      bf16x8 brl = *(const bf16x8*)&wlds[3][f][lane][0];
      au[cfl] = __builtin_amdgcn_mfma_f32_16x16x32_bf16(ah, buh, au[cfl], 0, 0, 0);
      au[cfl] = __builtin_amdgcn_mfma_f32_16x16x32_bf16(ah, bul, au[cfl], 0, 0, 0);
      au[cfl] = __builtin_amdgcn_mfma_f32_16x16x32_bf16(al, buh, au[cfl], 0, 0, 0);
      ar[cfl] = __builtin_amdgcn_mfma_f32_16x16x32_bf16(ah, brh, ar[cfl], 0, 0, 0);
      ar[cfl] = __builtin_amdgcn_mfma_f32_16x16x32_bf16(ah, brl, ar[cfl], 0, 0, 0);
      ar[cfl] = __builtin_amdgcn_mfma_f32_16x16x32_bf16(al, brh, ar[cfl], 0, 0, 0);
    }
  }
  const float* bu = ga.bu[cell];
  const float* br = ga.br[cell];
  const float* hsrc = ga.h[cell];
  float* uws = ga.u_ws[cell];
  short* rhh = ga.rhh[cell]; short* rhl = ga.rhl[cell];
  #pragma unroll
  for (int cfl = 0; cfl < 2; ++cfl) {
    const int col = cg2 * 32 + cfl * 16 + lr;
    #pragma unroll
    for (int q = 0; q < 4; ++q) {
      const int row = R0 + lg * 4 + q;
      const int n = row & (N - 1);
      uws[(size_t)row * HID + col] = sigmoidf_(au[cfl][q] + bu[n]);
      const float rv = sigmoidf_(ar[cfl][q] + br[n]);
      const float rhv = rv * hsrc[(size_t)row * HID + col];
      short hi, lo; split_bf16(rhv, hi, lo);
      rhh[(size_t)row * HID + col] = hi;
      rhl[(size_t)row * HID + col] = lo;
    }
  }
}

// ------------- K4: c gate + h' -------------
__global__ __launch_bounds__(256) void k_c(GArgs ga) {
  const int wv = threadIdx.x >> 6, lane = threadIdx.x & 63;
  const int bx = blockIdx.x, cg2 = blockIdx.y, cell = blockIdx.z;
  const int lr = lane & 15, lg = lane >> 4, kb = lg * 8;
  const int R0 = bx * 64 + wv * 16;
  __shared__ short wlds[2][16][64][8];
  bf16x8 a_h[8], a_l[8];
  {
    const size_t ab = (size_t)(R0 + lr) * HID + kb;
    const short* rhh = ga.rhh[cell]; const short* rhl = ga.rhl[cell];
    #pragma unroll
    for (int ks = 0; ks < 4; ++ks) {
      a_h[ks]     = *(const bf16x8*)&ga.chi[ab + ks * 32];
      a_l[ks]     = *(const bf16x8*)&ga.clo[ab + ks * 32];
      a_h[4 + ks] = *(const bf16x8*)&rhh[ab + ks * 32];
      a_l[4 + ks] = *(const bf16x8*)&rhl[ab + ks * 32];
    }
  }
  {
    const short* WH = ga.WcH[cell];
    const short* WL = ga.WcL[cell];
    #pragma unroll
    for (int i = 0; i < 8; ++i) {
      const int fid = wv * 8 + i;
      const int combo = fid >> 4, f = fid & 15;
      const short* src = combo ? WL : WH;
      const short* gp = src + (((size_t)((cg2 * 2 + (f >> 3)) * 8 + (f & 7))) * 64 + lane) * 8;
      stage16(gp, &wlds[combo][f][0][0]);
    }
  }
  asm volatile("s_waitcnt vmcnt(0)" ::: "memory");
  __syncthreads();
  f32x4 acc[2] = {};
  #pragma unroll
  for (int ks = 0; ks < 8; ++ks) {
    const bf16x8 ah = a_h[ks], al = a_l[ks];
    #pragma unroll
    for (int cfl = 0; cfl < 2; ++cfl) {
      const int f = cfl * 8 + ks;
      bf16x8 bh = *(const bf16x8*)&wlds[0][f][lane][0];
      bf16x8 bl = *(const bf16x8*)&wlds[1][f][lane][0];
      acc[cfl] = __builtin_amdgcn_mfma_f32_16x16x32_bf16(ah, bh, acc[cfl], 0, 0, 0);
      acc[cfl] = __builtin_amdgcn_mfma_f32_16x16x32_bf16(ah, bl, acc[cfl], 0, 0, 0);
      acc[cfl] = __builtin_amdgcn_mfma_f32_16x16x32_bf16(al, bh, acc[cfl], 0, 0, 0);
    }
  }
  const float* bc = ga.bc[cell];
  const float* uw = ga.u_ws[cell];
  const float* hsrc = ga.h[cell];
  float* hout = ga.hout[cell];
  short* hph = ga.hph[cell]; short* hpl = ga.hpl[cell];
  #pragma unroll
  for (int cfl = 0; cfl < 2; ++cfl) {
    const int col = cg2 * 32 + cfl * 16 + lr;
    #pragma unroll
    for (int q = 0; q < 4; ++q) {
      const int row = R0 + lg * 4 + q;
      const float cv = tanhf_(acc[cfl][q] + bc[row & (N - 1)]);
      const float uv = uw[(size_t)row * HID + col];
      const float hv = hsrc[(size_t)row * HID + col];
      const float o = uv * hv + (1.f - uv) * cv;
      __builtin_nontemporal_store(o, &hout[(size_t)row * HID + col]);
      short hi, lo; split_bf16(o, hi, lo);
      hph[(size_t)row * HID + col] = hi;
      hpl[(size_t)row * HID + col] = lo;
    }
  }
}

// ------------- K5: g = h' @ R -------------
__global__ __launch_bounds__(256) void k_g(GArgs ga) {
  const int wv = threadIdx.x >> 6, lane = threadIdx.x & 63;
  const int bx = blockIdx.x, cg2 = blockIdx.y, cell = blockIdx.z;
  const int lr = lane & 15, lg = lane >> 4, kb = lg * 8;
  const int R0 = bx * 64 + wv * 16;
  __shared__ short wlds[2][8][64][8];
  bf16x8 a_h[4], a_l[4];
  {
    const size_t ab = (size_t)(R0 + lr) * HID + kb;
    const short* hph = ga.hph[cell]; const short* hpl = ga.hpl[cell];
    #pragma unroll
    for (int ks = 0; ks < 4; ++ks) {
      a_h[ks] = *(const bf16x8*)&hph[ab + ks * 32];
      a_l[ks] = *(const bf16x8*)&hpl[ab + ks * 32];
    }
  }
  {
    #pragma unroll
    for (int i = 0; i < 4; ++i) {
      const int fid = wv * 4 + i;
      const int combo = fid >> 3, f = fid & 7;
      const short* src = combo ? ga.RtL[cell] : ga.RtH[cell];
      const short* gp = src + (((size_t)((cg2 * 2 + (f >> 2)) * 4 + (f & 3))) * 64 + lane) * 8;
      stage16(gp, &wlds[combo][f][0][0]);
    }
  }
  asm volatile("s_waitcnt vmcnt(0)" ::: "memory");
  __syncthreads();
  f32x4 acc[2] = {};
  #pragma unroll
  for (int ks = 0; ks < 4; ++ks) {
    const bf16x8 ah = a_h[ks], al = a_l[ks];
    #pragma unroll
    for (int cfl = 0; cfl < 2; ++cfl) {
      const int f = cfl * 4 + ks;
      bf16x8 bh = *(const bf16x8*)&wlds[0][f][lane][0];
      bf16x8 bl = *(const bf16x8*)&wlds[1][f][lane][0];
      acc[cfl] = __builtin_amdgcn_mfma_f32_16x16x32_bf16(ah, bh, acc[cfl], 0, 0, 0);
      acc[cfl] = __builtin_amdgcn_mfma_f32_16x16x32_bf16(ah, bl, acc[cfl], 0, 0, 0);
      acc[cfl] = __builtin_amdgcn_mfma_f32_16x16x32_bf16(al, bh, acc[cfl], 0, 0, 0);
    }
  }
  short* gbo = ga.gb[cell];
  #pragma unroll
  for (int cfl = 0; cfl < 2; ++cfl) {
    const int col = cg2 * 32 + cfl * 16 + lr;
    #pragma unroll
    for (int q = 0; q < 4; ++q) {
      const int row = R0 + lg * 4 + q;
      short hi, lo; split_bf16(acc[cfl][q], hi, lo);
      gbo[(size_t)row * HID + col] = hi;
    }
  }
}

// ------------- K6: logits — 128x128 tiles, double-buffered LDS-staged B --------
// grid (16, 16, B), 512 thr = 8 waves (4 rowgrp x 2 colhalf).
__global__ __launch_bounds__(512) void k_bilinear(
    const short* __restrict__ g0, const short* __restrict__ g1,
    const short* __restrict__ g2, const short* __restrict__ h0,
    const short* __restrict__ h1, const short* __restrict__ h2,
    float* __restrict__ out) {
  const int id  = blockIdx.y * 16 + blockIdx.x;      // 0..255
  const int id2 = (id & 7) * 32 + (id >> 3);         // bijective XCD swizzle
  const int ti = id2 & 15, tj = id2 >> 4;
  const int b = blockIdx.z;
  const int t = threadIdx.x;
  const int w = t >> 6, l = t & 63;
  const int wi = w >> 1, wj = w & 1;
  const int i_base = ti * 128 + wi * 32;
  const int j_tile = tj * 128;
  const short* gbs[3] = {g0, g1, g2};
  const short* hbs[3] = {h0, h1, h2};
  const int lr = l & 15;
  const int kb = (l >> 4) * 8;
  __shared__ short bf_lds[2][32][64][8];             // 2 x 32KB

  // helper lambdas (compile-time fixed literals for waits)
  auto stage_d = [&](const short* hsrc, int buf) {
    #pragma unroll
    for (int i = 0; i < 4; ++i) {
      const int f = w * 4 + i;                       // f = cf*4 + ks
      const int cf = f >> 2, ks = f & 3;
      const short* gp = hsrc +
          (size_t)(b * N + j_tile + cf * 16 + lr) * HID + ks * 32 + kb;
      stage16(gp, &bf_lds[buf][f][0][0]);
    }
  };
  auto load_af = [&](const short* gsrc, bf16x8 (&af)[2][4]) {
    #pragma unroll
    for (int ks = 0; ks < 4; ++ks) {
      af[0][ks] = *(const bf16x8*)&gsrc[(size_t)(b * N + i_base + lr) * HID + ks * 32 + kb];
      af[1][ks] = *(const bf16x8*)&gsrc[(size_t)(b * N + i_base + 16 + lr) * HID + ks * 32 + kb];
    }
  };

  f32x4 acc[3][2][4] = {};
  bf16x8 af[2][4];

  // prologue: stage d=0 into buf 0
  stage_d(hbs[0], 0);

  // ---- phase 0: compute d=0 (buf0), prefetch d=1 (buf1) ----
  load_af(gbs[0], af);
  stage_d(hbs[1], 1);
  asm volatile("s_waitcnt vmcnt(4)" ::: "memory");   // af + stage(d0) done; stage(d1) in flight
  __syncthreads();
  #pragma unroll
  for (int ks = 0; ks < 4; ++ks)
    #pragma unroll
    for (int mj = 0; mj < 4; ++mj) {
      const int f = (wj * 4 + mj) * 4 + ks;
      bf16x8 bfv = *(const bf16x8*)&bf_lds[0][f][l][0];
      acc[0][0][mj] = __builtin_amdgcn_mfma_f32_16x16x32_bf16(af[0][ks], bfv, acc[0][0][mj], 0, 0, 0);
      acc[0][1][mj] = __builtin_amdgcn_mfma_f32_16x16x32_bf16(af[1][ks], bfv, acc[0][1][mj], 0, 0, 0);
    }
  __syncthreads();

  // ---- phase 1: compute d=1 (buf1), prefetch d=2 (buf0) ----
  load_af(gbs[1], af);
  stage_d(hbs[2], 0);
  asm volatile("s_waitcnt vmcnt(4)" ::: "memory");
  __syncthreads();
  #pragma unroll
  for (int ks = 0; ks < 4; ++ks)
    #pragma unroll
    for (int mj = 0; mj < 4; ++mj) {
      const int f = (wj * 4 + mj) * 4 + ks;
      bf16x8 bfv = *(const bf16x8*)&bf_lds[1][f][l][0];
      acc[1][0][mj] = __builtin_amdgcn_mfma_f32_16x16x32_bf16(af[0][ks], bfv, acc[1][0][mj], 0, 0, 0);
      acc[1][1][mj] = __builtin_amdgcn_mfma_f32_16x16x32_bf16(af[1][ks], bfv, acc[1][1][mj], 0, 0, 0);
    }
  __syncthreads();

  // ---- phase 2: compute d=2 (buf0) ----
  load_af(gbs[2], af);
  asm volatile("s_waitcnt vmcnt(0)" ::: "memory");
  __syncthreads();
  #pragma unroll
  for (int ks = 0; ks < 4; ++ks)
    #pragma unroll
    for (int mj = 0; mj < 4; ++mj) {
      const int f = (wj * 4 + mj) * 4 + ks;
      bf16x8 bfv = *(const bf16x8*)&bf_lds[0][f][l][0];
      acc[2][0][mj] = __builtin_amdgcn_mfma_f32_16x16x32_bf16(af[0][ks], bfv, acc[2][0][mj], 0, 0, 0);
      acc[2][1][mj] = __builtin_amdgcn_mfma_f32_16x16x32_bf16(af[1][ks], bfv, acc[2][1][mj], 0, 0, 0);
    }

  const int orow = (l >> 4) * 4;
  const int col  = l & 15;
  const int j_base = j_tile + wj * 64;
  #pragma unroll
  for (int mi = 0; mi < 2; ++mi)
    #pragma unroll
    for (int mj = 0; mj < 4; ++mj)
      #pragma unroll
      for (int r = 0; r < 4; ++r) {
        const int row = i_base + mi * 16 + orow + r;
        const int cc  = j_base + mj * 16 + col;
        float* p = &out[(((size_t)(b * N + row)) * N + cc) * 3];
        f32x3 v;
        v[0] = acc[0][mi][mj][r];
        v[1] = acc[1][mi][mj][r];
        v[2] = acc[2][mi][mj][r];
        *(f32x3*)p = v;
      }
}

extern "C" void kernel_launch(void* const* d_in, const int* in_sizes, int n_in,
                              void* d_out, int out_size, void* d_ws, size_t ws_size,
                              hipStream_t stream) {
  (void)in_sizes; (void)n_in; (void)out_size; (void)ws_size;
  const float* a    = (const float*)d_in[1];
  const float* bias = (const float*)d_in[8];

  float* ws      = (float*)d_ws;
  float* hfeat   = ws;
  float* sself   = hfeat + (size_t)BN * HID;
  float* sneigh  = sself + (size_t)BN * H;
  float* u_ws0   = sneigh + (size_t)BN * H;
  short* sp      = (short*)(u_ws0 + 3 * (size_t)BN * HID);
  auto alloc_s = [&](size_t n) { short* p = sp; sp += n; return p; };

  short* conv_hi = alloc_s((size_t)BN * HID);
  short* conv_lo = alloc_s((size_t)BN * HID);
  short* h_hi[3]; short* h_lo[3];
  for (int c = 0; c < 3; ++c) { h_hi[c] = alloc_s((size_t)BN * HID); h_lo[c] = alloc_s((size_t)BN * HID); }
  short* rh_hi[3]; short* rh_lo[3];
  for (int c = 0; c < 3; ++c) { rh_hi[c] = alloc_s((size_t)BN * HID); rh_lo[c] = alloc_s((size_t)BN * HID); }
  short* hp_hi[3]; short* hp_lo[3];
  for (int c = 0; c < 3; ++c) { hp_hi[c] = alloc_s((size_t)BN * HID); hp_lo[c] = alloc_s((size_t)BN * HID); }
  short* gbb[3];
  for (int c = 0; c < 3; ++c) gbb[c] = alloc_s((size_t)BN * HID);

  float* out = (float*)d_out;

  PreArgs pa;
  pa.x = (const float*)d_in[0];
  pa.gk = (const float*)d_in[5];
  pa.asel = (const float*)d_in[6];
  pa.anei = (const float*)d_in[7];
  pa.hfeat = hfeat; pa.sself = sself; pa.sneigh = sneigh;

  GArgs ga;
  ga.chi = conv_hi; ga.clo = conv_lo;
  ga.h[0] = (const float*)d_in[2];
  ga.h[1] = (const float*)d_in[3];
  ga.h[2] = (const float*)d_in[4];
  for (int c = 0; c < 3; ++c) {
    pa.h[c] = ga.h[c];
    pa.hh[c] = h_hi[c]; pa.hl[c] = h_lo[c];
    const int base = 9 + c * 6;
    ga.hhi[c] = h_hi[c]; ga.hlo[c] = h_lo[c];
    ga.bu[c] = (const float*)d_in[base + 1];
    ga.br[c] = (const float*)d_in[base + 3];
    ga.bc[c] = (const float*)d_in[base + 5];
    short* wu_h = alloc_s(256 * 128); short* wu_l = alloc_s(256 * 128);
    short* wr_h = alloc_s(256 * 128); short* wr_l = alloc_s(256 * 128);
    short* wc_h = alloc_s(256 * 128); short* wc_l = alloc_s(256 * 128);
    short* rt_h = alloc_s(128 * 128); short* rt_l = alloc_s(128 * 128);
    const int pb = c * 4;
    pa.src[pb + 0] = (const float*)d_in[base + 0]; pa.whi[pb + 0] = wu_h; pa.wlo[pb + 0] = wu_l;
    pa.src[pb + 1] = (const float*)d_in[base + 2]; pa.whi[pb + 1] = wr_h; pa.wlo[pb + 1] = wr_l;
    pa.src[pb + 2] = (const float*)d_in[base + 4]; pa.whi[pb + 2] = wc_h; pa.wlo[pb + 2] = wc_l;
    pa.src[pb + 3] = (const float*)d_in[27 + c];   pa.whi[pb + 3] = rt_h; pa.wlo[pb + 3] = rt_l;
    ga.WuH[c] = wu_h; ga.WuL[c] = wu_l;
    ga.WrH[c] = wr_h; ga.WrL[c] = wr_l;
    ga.WcH[c] = wc_h; ga.WcL[c] = wc_l;
    ga.RtH[c] = rt_h; ga.RtL[c] = rt_l;
    ga.u_ws[c] = u_ws0 + (size_t)c * BN * HID;
    ga.rhh[c] = rh_hi[c]; ga.rhl[c] = rh_lo[c];
    ga.hph[c] = hp_hi[c]; ga.hpl[c] = hp_lo[c];
    ga.hout[c] = out + LOG_SZ + (size_t)c * BN * HID;
    ga.gb[c] = gbb[c];
  }

  k_pre<<<BN / 2 + 84, 256, 0, stream>>>(pa);
  k_attn<<<BN / 4, 256, 0, stream>>>(a, hfeat, sself, sneigh, bias, conv_hi, conv_lo);
  k_ur<<<dim3(BN / 64, 4, 3), 256, 0, stream>>>(ga);
  k_c<<<dim3(BN / 64, 4, 3), 256, 0, stream>>>(ga);
  k_g<<<dim3(BN / 64, 4, 3), 256, 0, stream>>>(ga);
  dim3 g2(16, 16, B);
  k_bilinear<<<g2, 512, 0, stream>>>(gbb[0], gbb[1], gbb[2],
                                     hp_hi[0], hp_hi[1], hp_hi[2], out);
}